// Round 8
// baseline (4617.515 us; speedup 1.0000x reference)
//
#include <hip/hip_runtime.h>
#include <stdint.h>

// SUBNET_15290083574166: encoder MLP -> 256-step recurrent f MLP -> output h MLP
// B=4096, T=256, NX=128, NU=16, NY=16, NB=NA=32, H=256
//
// Precision (VERIFIED r4-r7, absmax 0.0625 vs thr 0.24): f16 hi/lo pairs
// (2^-22) on all recurrence operands, 2-accum (hi + lo*2^-11); encoder bf16
// pairs; hnet xf-pair x f16-single. DO NOT change the numerics.
//
// r8 (numerics bit-identical; r7 post-mortem: VGPR=64 — allocator targeted
// 8 waves/EU despite LDS capping at 4 -> no reg headroom to pipeline streams):
//  - amdgpu_waves_per_eu(4,4): consistent with one 16-wave block/CU -> 128 cap
//  - W1lo persistent in regs (+20) -> G1 has no L2 stream
//  - u double-buffered in regs: next-step load issued at step top (hidden
//    under G1-G3); dead LDS u-staging deleted (r7 consumed u from regs only)
//  - streams remaining: W2lo (G2), W3lo+rWlo (G3), laundered per step

typedef __attribute__((ext_vector_type(8))) short s8v;      // 8 bf16 bits
typedef __attribute__((ext_vector_type(8))) _Float16 h8v;   // 8 f16
typedef __attribute__((ext_vector_type(4))) float f4v;

__device__ __forceinline__ f4v mfma16(s8v a, s8v b, f4v c) {
  return __builtin_amdgcn_mfma_f32_16x16x32_bf16(a, b, c, 0, 0, 0);
}
__device__ __forceinline__ f4v mfmaH(h8v a, h8v b, f4v c) {
  return __builtin_amdgcn_mfma_f32_16x16x32_f16(a, b, c, 0, 0, 0);
}
__device__ __forceinline__ f4v zero4() { return (f4v){0.f, 0.f, 0.f, 0.f}; }
__device__ __forceinline__ h8v zeroh8() {
  h8v z;
#pragma unroll
  for (int q = 0; q < 8; ++q) z[q] = (_Float16)0.f;
  return z;
}

__device__ __forceinline__ unsigned short f2b(float x) {  // f32->bf16 RNE
  unsigned int u = __builtin_bit_cast(unsigned int, x);
  u += 0x7fffu + ((u >> 16) & 1u);
  return (unsigned short)(u >> 16);
}
__device__ __forceinline__ float b2f(unsigned short h) {
  return __builtin_bit_cast(float, (unsigned int)h << 16);
}
__device__ __forceinline__ unsigned short f2h(float x) {
  return __builtin_bit_cast(unsigned short, (_Float16)x);
}
__device__ __forceinline__ float h2f(unsigned short h) {
  return (float)__builtin_bit_cast(_Float16, h);
}

__device__ __forceinline__ float tanhf_fast(float x) {
  x = fminf(15.f, fmaxf(-15.f, x));
  float e = __expf(2.f * x);
  return (e - 1.f) / (e + 1.f);
}

// ---------------- weight swizzle: fp32 [K][N] -> fragment order ---------------
// frag: idx(nt,kk,lane,j) = ((nt*KK + kk)*64 + lane)*8 + j
//   holds W[kk*32 + (lane>>4)*8 + j][nt*16 + (lane&15)]  (zero-pad k>=K)
// mode 0: bf16 hi at dst[dhi+local], bf16 lo at dst[dlo+local]
// mode 3: f16 hi at dst[dhi+local], f16((v-hi)*2048) at dst[dlo+local]
// mode 1: f16 at dst[dhi+local]
struct SwzDesc { const float* src; long woff; long dhi; long dlo; int K; int Kp; int N; int mode; };
struct SwzTable { SwzDesc d[12]; long tot_work; };

__global__ void swz_kernel(SwzTable tbl, unsigned short* __restrict__ dst) {
  long gid = (long)blockIdx.x * 256 + threadIdx.x;
  if (gid >= tbl.tot_work) return;
  int i = 11;
  while (i > 0 && gid < tbl.d[i].woff) --i;
  const SwzDesc m = tbl.d[i];
  long local = gid - m.woff;
  int j = (int)(local & 7);
  int lane = (int)((local >> 3) & 63);
  long rem = local >> 9;
  int KK = m.Kp >> 5;
  int kk = (int)(rem % KK);
  int nt = (int)(rem / KK);
  int k = kk * 32 + (lane >> 4) * 8 + j;
  int n = nt * 16 + (lane & 15);
  float v = (k < m.K) ? m.src[(long)k * m.N + n] : 0.f;
  if (m.mode == 0) {
    unsigned short hi = f2b(v);
    dst[m.dhi + local] = hi;
    dst[m.dlo + local] = f2b(v - b2f(hi));
  } else if (m.mode == 3) {
    _Float16 hi = (_Float16)v;
    dst[m.dhi + local] = __builtin_bit_cast(unsigned short, hi);
    dst[m.dlo + local] = f2h((v - (float)hi) * 2048.f);
  } else {
    dst[m.dhi + local] = f2h(v);
  }
}

// ---------------- encoder (bf16 hi/lo 3-term, one-shot) ----------------------
__global__ __launch_bounds__(512, 2)
void enc_kernel(const float* __restrict__ upast, const float* __restrict__ ypast,
                const unsigned short* __restrict__ W1h, const unsigned short* __restrict__ W1l,
                const unsigned short* __restrict__ W2h, const unsigned short* __restrict__ W2l,
                const unsigned short* __restrict__ W3h, const unsigned short* __restrict__ W3l,
                const unsigned short* __restrict__ rWh, const unsigned short* __restrict__ rWl,
                const float* __restrict__ b1, const float* __restrict__ b2,
                const float* __restrict__ b3, const float* __restrict__ rb,
                float* __restrict__ xstate) {
  __shared__ __align__(16) unsigned short h1h[16][264], h1l[16][264];
  __shared__ __align__(16) unsigned short h2h[16][264], h2l[16][264];
  const int tid = threadIdx.x;
  const int w = tid >> 6, l = tid & 63;
  const int c = l & 15, g = l >> 4;
  const int b0 = blockIdx.x << 4;
  const long zrow = (long)(b0 + c) * 512;

  f4v a0 = zero4(), a1 = zero4();
  for (int kk = 0; kk < 32; ++kk) {
    const int cb = kk * 32 + g * 8;
    const float* zp = (cb < 512) ? (upast + zrow + cb) : (ypast + zrow + (cb - 512));
    float4 z0 = *(const float4*)zp;
    float4 z1 = *(const float4*)(zp + 4);
    float zz[8] = {z0.x, z0.y, z0.z, z0.w, z1.x, z1.y, z1.z, z1.w};
    s8v ah, al;
#pragma unroll
    for (int q = 0; q < 8; ++q) {
      unsigned short hi = f2b(zz[q]);
      ah[q] = (short)hi; al[q] = (short)f2b(zz[q] - b2f(hi));
    }
#pragma unroll
    for (int ct = 0; ct < 2; ++ct) {
      s8v bh = *(const s8v*)(W1h + (((long)(2 * w + ct) * 32 + kk) * 64 + l) * 8);
      s8v bl = *(const s8v*)(W1l + (((long)(2 * w + ct) * 32 + kk) * 64 + l) * 8);
      f4v& acc = ct ? a1 : a0;
      acc = mfma16(ah, bh, acc);
      acc = mfma16(al, bh, acc);
      acc = mfma16(ah, bl, acc);
    }
  }
  {
    const float bbA = b1[(2 * w + 0) * 16 + c], bbB = b1[(2 * w + 1) * 16 + c];
#pragma unroll
    for (int j = 0; j < 4; ++j) {
      float tA = tanhf_fast(a0[j] + bbA), tB = tanhf_fast(a1[j] + bbB);
      unsigned short hA = f2b(tA), hB = f2b(tB);
      h1h[g * 4 + j][(2 * w + 0) * 16 + c] = hA;
      h1l[g * 4 + j][(2 * w + 0) * 16 + c] = f2b(tA - b2f(hA));
      h1h[g * 4 + j][(2 * w + 1) * 16 + c] = hB;
      h1l[g * 4 + j][(2 * w + 1) * 16 + c] = f2b(tB - b2f(hB));
    }
  }
  __syncthreads();
  a0 = zero4(); a1 = zero4();
#pragma unroll
  for (int kk = 0; kk < 8; ++kk) {
    s8v ah = *(const s8v*)(&h1h[c][kk * 32 + g * 8]);
    s8v al = *(const s8v*)(&h1l[c][kk * 32 + g * 8]);
#pragma unroll
    for (int ct = 0; ct < 2; ++ct) {
      s8v bh = *(const s8v*)(W2h + (((long)(2 * w + ct) * 8 + kk) * 64 + l) * 8);
      s8v bl = *(const s8v*)(W2l + (((long)(2 * w + ct) * 8 + kk) * 64 + l) * 8);
      f4v& acc = ct ? a1 : a0;
      acc = mfma16(ah, bh, acc);
      acc = mfma16(al, bh, acc);
      acc = mfma16(ah, bl, acc);
    }
  }
  {
    const float bbA = b2[(2 * w + 0) * 16 + c], bbB = b2[(2 * w + 1) * 16 + c];
#pragma unroll
    for (int j = 0; j < 4; ++j) {
      float tA = tanhf_fast(a0[j] + bbA), tB = tanhf_fast(a1[j] + bbB);
      unsigned short hA = f2b(tA), hB = f2b(tB);
      h2h[g * 4 + j][(2 * w + 0) * 16 + c] = hA;
      h2l[g * 4 + j][(2 * w + 0) * 16 + c] = f2b(tA - b2f(hA));
      h2h[g * 4 + j][(2 * w + 1) * 16 + c] = hB;
      h2l[g * 4 + j][(2 * w + 1) * 16 + c] = f2b(tB - b2f(hB));
    }
  }
  __syncthreads();
  f4v ac = zero4();
#pragma unroll
  for (int kk = 0; kk < 8; ++kk) {
    s8v ah = *(const s8v*)(&h2h[c][kk * 32 + g * 8]);
    s8v al = *(const s8v*)(&h2l[c][kk * 32 + g * 8]);
    s8v bh = *(const s8v*)(W3h + (((long)w * 8 + kk) * 64 + l) * 8);
    s8v bl = *(const s8v*)(W3l + (((long)w * 8 + kk) * 64 + l) * 8);
    ac = mfma16(ah, bh, ac);
    ac = mfma16(al, bh, ac);
    ac = mfma16(ah, bl, ac);
  }
  for (int kk = 0; kk < 32; ++kk) {
    const int cb = kk * 32 + g * 8;
    const float* zp = (cb < 512) ? (upast + zrow + cb) : (ypast + zrow + (cb - 512));
    float4 z0 = *(const float4*)zp;
    float4 z1 = *(const float4*)(zp + 4);
    float zz[8] = {z0.x, z0.y, z0.z, z0.w, z1.x, z1.y, z1.z, z1.w};
    s8v ah, al;
#pragma unroll
    for (int q = 0; q < 8; ++q) {
      unsigned short hi = f2b(zz[q]);
      ah[q] = (short)hi; al[q] = (short)f2b(zz[q] - b2f(hi));
    }
    s8v bh = *(const s8v*)(rWh + (((long)w * 32 + kk) * 64 + l) * 8);
    s8v bl = *(const s8v*)(rWl + (((long)w * 32 + kk) * 64 + l) * 8);
    ac = mfma16(ah, bh, ac);
    ac = mfma16(al, bh, ac);
    ac = mfma16(ah, bl, ac);
  }
  {
    const float bias = b3[w * 16 + c] + rb[w * 16 + c];
#pragma unroll
    for (int j = 0; j < 4; ++j)
      xstate[(long)(b0 + g * 4 + j) * 128 + w * 16 + c] = ac[j] + bias;
  }
}

// ---------------- recurrence (16 waves, 1 coltile/wave) ----------------------
__global__ __attribute__((amdgpu_flat_work_group_size(1024, 1024)))
__attribute__((amdgpu_waves_per_eu(4, 4)))
void recur_kernel(const float* __restrict__ ufut,
                  const unsigned short* __restrict__ W1h, const unsigned short* __restrict__ W1l,
                  const unsigned short* __restrict__ W2h, const unsigned short* __restrict__ W2l,
                  const unsigned short* __restrict__ W3h, const unsigned short* __restrict__ W3l,
                  const unsigned short* __restrict__ rWh, const unsigned short* __restrict__ rWl,
                  const float* __restrict__ b1, const float* __restrict__ b2,
                  const float* __restrict__ b3, const float* __restrict__ rb,
                  float* __restrict__ xstate,
                  unsigned short* __restrict__ xfh, unsigned short* __restrict__ xfl,
                  int t0, int len) {
  __shared__ __align__(16) unsigned short xu_h[16][136], xu_l[16][136];
  __shared__ __align__(16) unsigned short h1h[16][264], h1l[16][264];
  __shared__ __align__(16) unsigned short h2h[16][264], h2l[16][264];
  __shared__ __align__(16) unsigned short w3h_l[32768];  // W3 hi  (64 KB)
  __shared__ __align__(16) unsigned short rwh_l[20480];  // rW hi  (40 KB)
  __shared__ __align__(16) float part[16][136];          // rW partial (8.5 KB)
  const int tid = threadIdx.x;
  const int w = tid >> 6, l = tid & 63;
  const int c = l & 15, g = l >> 4;
  const int b0 = blockIdx.x << 4;

  // persistent regs (72 VGPR): W1 hi 20, W1 lo 20, W2 hi 32
  h8v w1h_r[5], w1l_r[5], w2h_r[8];
#pragma unroll
  for (int kk = 0; kk < 5; ++kk) {
    w1h_r[kk] = *(const h8v*)(W1h + (((long)w * 5 + kk) * 64 + l) * 8);
    w1l_r[kk] = *(const h8v*)(W1l + (((long)w * 5 + kk) * 64 + l) * 8);
  }
#pragma unroll
  for (int kk = 0; kk < 8; ++kk)
    w2h_r[kk] = *(const h8v*)(W2h + (((long)w * 8 + kk) * 64 + l) * 8);

  // LDS weights (linear copies)
  for (int i = tid; i < 4096; i += 1024) ((h8v*)w3h_l)[i] = ((const h8v*)W3h)[i];
  for (int i = tid; i < 2560; i += 1024) ((h8v*)rwh_l)[i] = ((const h8v*)rWh)[i];

  const float bb = b1[w * 16 + c];
  const float cb = b2[w * 16 + c];
  const float dB = (w < 8) ? (b3[w * 16 + c] + rb[w * 16 + c]) : 0.f;

  // seed state pair
  for (int idx = tid; idx < 2048; idx += 1024) {
    int r = idx >> 7, cc = idx & 127;
    float x = xstate[(long)(b0 + r) * 128 + cc];
    _Float16 hi = (_Float16)x;
    xu_h[r][cc] = __builtin_bit_cast(unsigned short, hi);
    xu_l[r][cc] = f2h((x - (float)hi) * 2048.f);
  }
  // u double-buffer in regs: load u(t0)
  float4 uc0, uc1;
  if (g < 2) {
    const float* up = ufut + ((long)(b0 + c) * 256 + t0) * 16 + g * 8;
    uc0 = *(const float4*)up;
    uc1 = *(const float4*)(up + 4);
  }
  __syncthreads();

  for (int tc = 0; tc < len; ++tc) {
    const int t = t0 + tc;
    // launder streamed-weight bases (blocks LICM -> per-step L2 reads)
    long lz = 0;
    asm volatile("" : "+s"(lz));
    const unsigned short* W2ls = W2l + lz;
    const unsigned short* W3ls = W3l + lz;
    const unsigned short* rWls = rWl + lz;

    // issue next-step u load early (hidden under G1-G3)
    float4 un0, un1;
    {
      const int tt = (tc + 1 < len) ? (t + 1) : t;
      if (g < 2) {
        const float* up = ufut + ((long)(b0 + c) * 256 + tt) * 16 + g * 8;
        un0 = *(const float4*)up;
        un1 = *(const float4*)(up + 4);
      }
    }
    // build u fragment (kk=4 of K=160 padded input) from current regs
    h8v ah4 = zeroh8(), al4 = zeroh8();
    if (g < 2) {
      float uu[8] = {uc0.x, uc0.y, uc0.z, uc0.w, uc1.x, uc1.y, uc1.z, uc1.w};
#pragma unroll
      for (int q = 0; q < 8; ++q) {
        _Float16 hi = (_Float16)uu[q];
        ah4[q] = hi;
        al4[q] = (_Float16)((uu[q] - (float)hi) * 2048.f);
      }
    }
    // xf store (reads current state; no xu writes this phase)
    {
      int r = tid >> 6, cc0 = (tid & 63) * 2;
      long row = ((long)(b0 + r) * len + tc) * 128 + cc0;
      *(unsigned int*)(xfh + row) =
          (unsigned int)xu_h[r][cc0] | ((unsigned int)xu_h[r][cc0 + 1] << 16);
      *(unsigned int*)(xfl + row) =
          (unsigned int)xu_l[r][cc0] | ((unsigned int)xu_l[r][cc0 + 1] << 16);
    }
    // G1: xu pair x W1 pair (all regs) -> h1 pair; coltile = w
    {
      f4v p = zero4(), q = zero4();
#pragma unroll
      for (int kk = 0; kk < 5; ++kk) {
        h8v ah, al;
        if (kk < 4) {
          ah = *(const h8v*)(&xu_h[c][kk * 32 + g * 8]);
          al = *(const h8v*)(&xu_l[c][kk * 32 + g * 8]);
        } else { ah = ah4; al = al4; }
        p = mfmaH(ah, w1h_r[kk], p);
        q = mfmaH(al, w1h_r[kk], q);
        q = mfmaH(ah, w1l_r[kk], q);
      }
#pragma unroll
      for (int j = 0; j < 4; ++j) {
        float tv = tanhf_fast(p[j] + q[j] * 0x1p-11f + bb);
        _Float16 hi = (_Float16)tv;
        h1h[g * 4 + j][w * 16 + c] = __builtin_bit_cast(unsigned short, hi);
        h1l[g * 4 + j][w * 16 + c] = f2h((tv - (float)hi) * 2048.f);
      }
    }
    __syncthreads();  // A: h1 ready
    // G2: h1 pair x W2 (hi regs, lo stream) -> h2 pair; coltile = w
    {
      f4v p = zero4(), q = zero4(), r2 = zero4();
#pragma unroll
      for (int kk = 0; kk < 8; ++kk) {
        h8v ah = *(const h8v*)(&h1h[c][kk * 32 + g * 8]);
        h8v al = *(const h8v*)(&h1l[c][kk * 32 + g * 8]);
        h8v bl = *(const h8v*)(W2ls + (((long)w * 8 + kk) * 64 + l) * 8);
        p = mfmaH(ah, w2h_r[kk], p);
        q = mfmaH(al, w2h_r[kk], q);
        r2 = mfmaH(ah, bl, r2);
      }
#pragma unroll
      for (int j = 0; j < 4; ++j) {
        float tv = tanhf_fast(p[j] + (q[j] + r2[j]) * 0x1p-11f + cb);
        _Float16 hi = (_Float16)tv;
        h2h[g * 4 + j][w * 16 + c] = __builtin_bit_cast(unsigned short, hi);
        h2l[g * 4 + j][w * 16 + c] = f2h((tv - (float)hi) * 2048.f);
      }
    }
    __syncthreads();  // B: h2 ready
    // G3 split: waves 0-7 h2@W3 (hold partials), waves 8-15 xu@rW -> LDS part
    float pv[4], qv[4];
    if (w < 8) {
      f4v p = zero4(), q = zero4(), r2 = zero4();
#pragma unroll
      for (int kk = 0; kk < 8; ++kk) {
        h8v ah = *(const h8v*)(&h2h[c][kk * 32 + g * 8]);
        h8v al = *(const h8v*)(&h2l[c][kk * 32 + g * 8]);
        h8v bh = *(const h8v*)(&w3h_l[(((long)w * 8 + kk) * 64 + l) * 8]);
        h8v bl = *(const h8v*)(W3ls + (((long)w * 8 + kk) * 64 + l) * 8);
        p = mfmaH(ah, bh, p);
        q = mfmaH(al, bh, q);
        r2 = mfmaH(ah, bl, r2);
      }
#pragma unroll
      for (int j = 0; j < 4; ++j) { pv[j] = p[j]; qv[j] = q[j] + r2[j]; }
    } else {
      const int cw = w - 8;
      f4v p = zero4(), q = zero4();
#pragma unroll
      for (int kk = 0; kk < 5; ++kk) {
        h8v ah, al;
        if (kk < 4) {
          ah = *(const h8v*)(&xu_h[c][kk * 32 + g * 8]);
          al = *(const h8v*)(&xu_l[c][kk * 32 + g * 8]);
        } else { ah = ah4; al = al4; }
        h8v bh = *(const h8v*)(&rwh_l[(((long)cw * 5 + kk) * 64 + l) * 8]);
        h8v bl = *(const h8v*)(rWls + (((long)cw * 5 + kk) * 64 + l) * 8);
        p = mfmaH(ah, bh, p);
        q = mfmaH(al, bh, q);
        q = mfmaH(ah, bl, q);
      }
#pragma unroll
      for (int j = 0; j < 4; ++j)
        part[g * 4 + j][cw * 16 + c] = p[j] + q[j] * 0x1p-11f;
    }
    __syncthreads();  // C: partials ready; all xu reads done
    // D: waves 0-7 combine + state write
    if (w < 8) {
#pragma unroll
      for (int j = 0; j < 4; ++j) {
        float xn = pv[j] + qv[j] * 0x1p-11f + part[g * 4 + j][w * 16 + c] + dB;
        _Float16 hi = (_Float16)xn;
        xu_h[g * 4 + j][w * 16 + c] = __builtin_bit_cast(unsigned short, hi);
        xu_l[g * 4 + j][w * 16 + c] = f2h((xn - (float)hi) * 2048.f);
      }
    }
    uc0 = un0; uc1 = un1;
    __syncthreads();  // D: state ready for next step
  }
  // chunk-final state writeback (fp32 = hi + lo*2^-11, exact)
  for (int idx = tid; idx < 2048; idx += 1024) {
    int r = idx >> 7, cc = idx & 127;
    xstate[(long)(b0 + r) * 128 + cc] =
        h2f(xu_h[r][cc]) + h2f(xu_l[r][cc]) * 0x1p-11f;
  }
}

// ---------------- output network h (xf pair x f16-single weights) ------------
__global__ __launch_bounds__(512, 2)
void hnet_kernel(const unsigned short* __restrict__ xfh, const unsigned short* __restrict__ xfl,
                 const unsigned short* __restrict__ W1, const unsigned short* __restrict__ W2,
                 const unsigned short* __restrict__ W3, const unsigned short* __restrict__ rW,
                 const float* __restrict__ b1, const float* __restrict__ b2,
                 const float* __restrict__ b3, const float* __restrict__ rb,
                 float* __restrict__ out, int t0, int len) {
  __shared__ __align__(16) unsigned short h1[64][264];
  __shared__ __align__(16) unsigned short h2[64][264];
  __shared__ float part[4][16][16];
  const int tid = threadIdx.x;
  const int w = tid >> 6, l = tid & 63;
  const int c = l & 15, g = l >> 4;
  const long row0 = (long)blockIdx.x * 64;

  {  // stage A: h1 = tanh(xf(pair) @ W1 + b1)
    h8v w1f[2][4];
#pragma unroll
    for (int ct = 0; ct < 2; ++ct)
#pragma unroll
      for (int kk = 0; kk < 4; ++kk)
        w1f[ct][kk] = *(const h8v*)(W1 + (((long)(2 * w + ct) * 4 + kk) * 64 + l) * 8);
    const float bbA = b1[(2 * w + 0) * 16 + c], bbB = b1[(2 * w + 1) * 16 + c];
    for (int rt = 0; rt < 4; ++rt) {
      f4v t10 = zero4(), tl0 = zero4(), t11 = zero4(), tl1 = zero4();
#pragma unroll
      for (int kk = 0; kk < 4; ++kk) {
        h8v ah = *(const h8v*)(xfh + (row0 + rt * 16 + c) * 128 + kk * 32 + g * 8);
        h8v al = *(const h8v*)(xfl + (row0 + rt * 16 + c) * 128 + kk * 32 + g * 8);
        t10 = mfmaH(ah, w1f[0][kk], t10);
        tl0 = mfmaH(al, w1f[0][kk], tl0);
        t11 = mfmaH(ah, w1f[1][kk], t11);
        tl1 = mfmaH(al, w1f[1][kk], tl1);
      }
#pragma unroll
      for (int j = 0; j < 4; ++j) {
        h1[rt * 16 + g * 4 + j][(2 * w + 0) * 16 + c] =
            f2h(tanhf_fast(t10[j] + tl0[j] * 0x1p-11f + bbA));
        h1[rt * 16 + g * 4 + j][(2 * w + 1) * 16 + c] =
            f2h(tanhf_fast(t11[j] + tl1[j] * 0x1p-11f + bbB));
      }
    }
  }
  __syncthreads();
  {  // stage B: h2 = tanh(h1 @ W2 + b2), f16 single
    h8v w2f[2][8];
#pragma unroll
    for (int ct = 0; ct < 2; ++ct)
#pragma unroll
      for (int kk = 0; kk < 8; ++kk)
        w2f[ct][kk] = *(const h8v*)(W2 + (((long)(2 * w + ct) * 8 + kk) * 64 + l) * 8);
    const float bbA = b2[(2 * w + 0) * 16 + c], bbB = b2[(2 * w + 1) * 16 + c];
    for (int rt = 0; rt < 4; ++rt) {
      f4v a0 = zero4(), a1 = zero4();
#pragma unroll
      for (int kk = 0; kk < 8; ++kk) {
        h8v a = *(const h8v*)(&h1[rt * 16 + c][kk * 32 + g * 8]);
        a0 = mfmaH(a, w2f[0][kk], a0);
        a1 = mfmaH(a, w2f[1][kk], a1);
      }
#pragma unroll
      for (int j = 0; j < 4; ++j) {
        h2[rt * 16 + g * 4 + j][(2 * w + 0) * 16 + c] = f2h(tanhf_fast(a0[j] + bbA));
        h2[rt * 16 + g * 4 + j][(2 * w + 1) * 16 + c] = f2h(tanhf_fast(a1[j] + bbB));
      }
    }
  }
  __syncthreads();
  {  // stage C: y = h2 @ W3 + xf(pair) @ rW + b3 + rb
    const int rt = w & 3, kh = w >> 2;
    f4v t1 = zero4(), tl = zero4();
#pragma unroll
    for (int kk = 0; kk < 4; ++kk) {
      const int kkg = kh * 4 + kk;
      h8v a = *(const h8v*)(&h2[rt * 16 + c][kkg * 32 + g * 8]);
      h8v b = *(const h8v*)(W3 + ((long)(kkg * 64 + l)) * 8);
      t1 = mfmaH(a, b, t1);
    }
#pragma unroll
    for (int kk = 0; kk < 2; ++kk) {
      const int kkg = kh * 2 + kk;
      h8v ah = *(const h8v*)(xfh + (row0 + rt * 16 + c) * 128 + kkg * 32 + g * 8);
      h8v al = *(const h8v*)(xfl + (row0 + rt * 16 + c) * 128 + kkg * 32 + g * 8);
      h8v b = *(const h8v*)(rW + ((long)(kkg * 64 + l)) * 8);
      t1 = mfmaH(ah, b, t1);
      tl = mfmaH(al, b, tl);
    }
    float val[4];
#pragma unroll
    for (int j = 0; j < 4; ++j) val[j] = t1[j] + tl[j] * 0x1p-11f;
    if (w >= 4) {
#pragma unroll
      for (int j = 0; j < 4; ++j) part[rt][g * 4 + j][c] = val[j];
    }
    __syncthreads();
    if (w < 4) {
      const float bias = b3[c] + rb[c];
#pragma unroll
      for (int j = 0; j < 4; ++j) {
        const long grow = row0 + rt * 16 + g * 4 + j;
        const long bq = grow / len;
        const int tq = (int)(grow - bq * len);
        out[(bq * 256 + (t0 + tq)) * 16 + c] = val[j] + part[rt][g * 4 + j][c] + bias;
      }
    }
  }
}

// ---------------- host -------------------------------------------------------
extern "C" void kernel_launch(void* const* d_in, const int* in_sizes, int n_in,
                              void* d_out, int out_size, void* d_ws, size_t ws_size,
                              hipStream_t stream) {
  (void)in_sizes; (void)n_in; (void)out_size;
  const float* upast = (const float*)d_in[0];
  const float* ypast = (const float*)d_in[1];
  const float* ufut  = (const float*)d_in[2];
  const float* e_rW = (const float*)d_in[3];
  const float* e_rb = (const float*)d_in[4];
  const float* e_W1 = (const float*)d_in[5];
  const float* e_b1 = (const float*)d_in[6];
  const float* e_W2 = (const float*)d_in[7];
  const float* e_b2 = (const float*)d_in[8];
  const float* e_W3 = (const float*)d_in[9];
  const float* e_b3 = (const float*)d_in[10];
  const float* f_rW = (const float*)d_in[11];
  const float* f_rb = (const float*)d_in[12];
  const float* f_W1 = (const float*)d_in[13];
  const float* f_b1 = (const float*)d_in[14];
  const float* f_W2 = (const float*)d_in[15];
  const float* f_b2 = (const float*)d_in[16];
  const float* f_W3 = (const float*)d_in[17];
  const float* f_b3 = (const float*)d_in[18];
  const float* h_rW = (const float*)d_in[19];
  const float* h_rb = (const float*)d_in[20];
  const float* h_W1 = (const float*)d_in[21];
  const float* h_b1 = (const float*)d_in[22];
  const float* h_W2 = (const float*)d_in[23];
  const float* h_b2 = (const float*)d_in[24];
  const float* h_W3 = (const float*)d_in[25];
  const float* h_b3 = (const float*)d_in[26];
  float* out = (float*)d_out;

  // swizzle table: e_* bf16 pair (mode0), f_* f16 pair (mode3), h_* f16 (mode1)
  const float* srcs[12] = { e_W1, e_W2, e_W3, e_rW, f_W1, f_W2, f_W3, f_rW,
                            h_W1, h_W2, h_W3, h_rW };
  const int Ks [12] = {1024, 256, 256, 1024, 144, 256, 256, 144, 128, 256, 256, 128};
  const int Kps[12] = {1024, 256, 256, 1024, 160, 256, 256, 160, 128, 256, 256, 128};
  const int Ns [12] = { 256, 256, 128,  128, 256, 256, 128, 128, 256, 256,  16,  16};
  const int modes[12] = {0,0,0,0, 3,3,3,3, 1,1,1,1};

  SwzTable tbl;
  long woff = 0, offs[12];
  for (int i = 0; i < 12; ++i) { offs[i] = woff; woff += (long)Kps[i] * Ns[i]; }
  const long EA = offs[4];              // e-region elems
  const long FB = 2 * EA;
  const long EB = offs[8] - offs[4];    // f-region elems
  const long HB = FB + 2 * EB;
  for (int i = 0; i < 12; ++i) {
    tbl.d[i].src = srcs[i]; tbl.d[i].woff = offs[i];
    tbl.d[i].K = Ks[i]; tbl.d[i].Kp = Kps[i]; tbl.d[i].N = Ns[i]; tbl.d[i].mode = modes[i];
    if (modes[i] == 0)      { tbl.d[i].dhi = offs[i];              tbl.d[i].dlo = EA + offs[i]; }
    else if (modes[i] == 3) { long lo = offs[i] - offs[4];
                              tbl.d[i].dhi = FB + lo;              tbl.d[i].dlo = FB + EB + lo; }
    else                    { long lo = offs[i] - offs[8];
                              tbl.d[i].dhi = HB + lo;              tbl.d[i].dlo = 0; }
  }
  tbl.tot_work = woff;

  unsigned short* wswz = (unsigned short*)d_ws;
  const long WSHORTS = HB + (offs[11] - offs[8]) + (long)Kps[11] * Ns[11];
  const size_t XOFF = ((size_t)WSHORTS * 2 + 4095) & ~(size_t)4095;
  float* xstate = (float*)((char*)d_ws + XOFF);
  const size_t XF0 = XOFF + (2u << 20);
  int c = 64;
  {
    long cmax = ((long)ws_size - (long)XF0) >> 21;  // 2 MB per time-step (pair)
    if (cmax < c) c = (int)cmax;
    if (c < 1) c = 1;
  }
  unsigned short* xfh = (unsigned short*)((char*)d_ws + XF0);
  unsigned short* xfl = (unsigned short*)((char*)d_ws + XF0 + (size_t)c * 1048576);

  // kernel weight pointers
  const unsigned short* eW1h = wswz + offs[0];          const unsigned short* eW1l = wswz + EA + offs[0];
  const unsigned short* eW2h = wswz + offs[1];          const unsigned short* eW2l = wswz + EA + offs[1];
  const unsigned short* eW3h = wswz + offs[2];          const unsigned short* eW3l = wswz + EA + offs[2];
  const unsigned short* erWh = wswz + offs[3];          const unsigned short* erWl = wswz + EA + offs[3];
  const unsigned short* fW1h = wswz + FB + 0;           const unsigned short* fW1l = wswz + FB + EB + 0;
  const unsigned short* fW2h = wswz + FB + 40960;       const unsigned short* fW2l = wswz + FB + EB + 40960;
  const unsigned short* fW3h = wswz + FB + 106496;      const unsigned short* fW3l = wswz + FB + EB + 106496;
  const unsigned short* frWh = wswz + FB + 139264;      const unsigned short* frWl = wswz + FB + EB + 139264;
  const unsigned short* hW1 = wswz + HB + 0;
  const unsigned short* hW2 = wswz + HB + 32768;
  const unsigned short* hW3 = wswz + HB + 98304;
  const unsigned short* hrW = wswz + HB + 102400;

  swz_kernel<<<(int)((tbl.tot_work + 255) / 256), 256, 0, stream>>>(tbl, wswz);
  enc_kernel<<<256, 512, 0, stream>>>(upast, ypast,
                                      eW1h, eW1l, eW2h, eW2l, eW3h, eW3l, erWh, erWl,
                                      e_b1, e_b2, e_b3, e_rb, xstate);
  for (int t0 = 0; t0 < 256; t0 += c) {
    int len = 256 - t0; if (len > c) len = c;
    recur_kernel<<<256, 1024, 0, stream>>>(ufut, fW1h, fW1l, fW2h, fW2l, fW3h, fW3l,
                                           frWh, frWl, f_b1, f_b2, f_b3, f_rb,
                                           xstate, xfh, xfl, t0, len);
    hnet_kernel<<<64 * len, 512, 0, stream>>>(xfh, xfl, hW1, hW2, hW3, hrW,
                                              h_b1, h_b2, h_b3, h_rb, out, t0, len);
  }
}

// Round 9
// 4570.768 us; speedup vs baseline: 1.0102x; 1.0102x over previous
//
#include <hip/hip_runtime.h>
#include <stdint.h>

// SUBNET_15290083574166: encoder MLP -> 256-step recurrent f MLP -> output h MLP
// B=4096, T=256, NX=128, NU=16, NY=16, NB=NA=32, H=256
//
// Precision (VERIFIED r4-r8, absmax 0.0625 vs thr 0.24): f16 hi/lo pairs
// (2^-22) on all recurrence operands, 2-accum (hi + lo*2^-11); encoder bf16
// pairs; hnet xf-pair x f16-single. DO NOT change the numerics.
//
// r9 (numerics bit-identical). Empirical law: arch-VGPR budget = 131072 /
// (threads*2) -> 64 at 1024 thr; attrs don't move it. But each wave at
// 4 waves/SIMD owns 128 unified regs -> 64 AGPRs sit unused. This round
// stashes the G2/G3 lo-weight streams into exactly 64 AGPRs via tied
// inline-asm class copies (accvgpr_write once; accvgpr_read per use, ~4cyc
// vs ~300cyc L2). VGPR persistent stays at r7's proven 52 (W1hi+W2hi).
// Only G1's 5-load W1lo stream remains (overlapped with xf-store).

typedef __attribute__((ext_vector_type(8))) short s8v;      // 8 bf16 bits
typedef __attribute__((ext_vector_type(8))) _Float16 h8v;   // 8 f16
typedef __attribute__((ext_vector_type(4))) float f4v;
typedef __attribute__((ext_vector_type(4))) int i4v;        // 4 dwords

__device__ __forceinline__ f4v mfma16(s8v a, s8v b, f4v c) {
  return __builtin_amdgcn_mfma_f32_16x16x32_bf16(a, b, c, 0, 0, 0);
}
__device__ __forceinline__ f4v mfmaH(h8v a, h8v b, f4v c) {
  return __builtin_amdgcn_mfma_f32_16x16x32_f16(a, b, c, 0, 0, 0);
}
__device__ __forceinline__ f4v zero4() { return (f4v){0.f, 0.f, 0.f, 0.f}; }
__device__ __forceinline__ h8v zeroh8() {
  h8v z;
#pragma unroll
  for (int q = 0; q < 8; ++q) z[q] = (_Float16)0.f;
  return z;
}

// force a 4-dword value into AGPRs (emits v_accvgpr_write x4) and back
__device__ __forceinline__ i4v to_agpr(i4v v) {
  i4v a;
  asm volatile("" : "=a"(a) : "0"(v));
  return a;
}
__device__ __forceinline__ h8v from_agpr(i4v a) {
  i4v v;
  asm volatile("" : "=v"(v) : "0"(a));
  return __builtin_bit_cast(h8v, v);
}

__device__ __forceinline__ unsigned short f2b(float x) {  // f32->bf16 RNE
  unsigned int u = __builtin_bit_cast(unsigned int, x);
  u += 0x7fffu + ((u >> 16) & 1u);
  return (unsigned short)(u >> 16);
}
__device__ __forceinline__ float b2f(unsigned short h) {
  return __builtin_bit_cast(float, (unsigned int)h << 16);
}
__device__ __forceinline__ unsigned short f2h(float x) {
  return __builtin_bit_cast(unsigned short, (_Float16)x);
}
__device__ __forceinline__ float h2f(unsigned short h) {
  return (float)__builtin_bit_cast(_Float16, h);
}

__device__ __forceinline__ float tanhf_fast(float x) {
  x = fminf(15.f, fmaxf(-15.f, x));
  float e = __expf(2.f * x);
  return (e - 1.f) / (e + 1.f);
}

// ---------------- weight swizzle: fp32 [K][N] -> fragment order ---------------
// frag: idx(nt,kk,lane,j) = ((nt*KK + kk)*64 + lane)*8 + j
//   holds W[kk*32 + (lane>>4)*8 + j][nt*16 + (lane&15)]  (zero-pad k>=K)
// mode 0: bf16 hi at dst[dhi+local], bf16 lo at dst[dlo+local]
// mode 3: f16 hi at dst[dhi+local], f16((v-hi)*2048) at dst[dlo+local]
// mode 1: f16 at dst[dhi+local]
struct SwzDesc { const float* src; long woff; long dhi; long dlo; int K; int Kp; int N; int mode; };
struct SwzTable { SwzDesc d[12]; long tot_work; };

__global__ void swz_kernel(SwzTable tbl, unsigned short* __restrict__ dst) {
  long gid = (long)blockIdx.x * 256 + threadIdx.x;
  if (gid >= tbl.tot_work) return;
  int i = 11;
  while (i > 0 && gid < tbl.d[i].woff) --i;
  const SwzDesc m = tbl.d[i];
  long local = gid - m.woff;
  int j = (int)(local & 7);
  int lane = (int)((local >> 3) & 63);
  long rem = local >> 9;
  int KK = m.Kp >> 5;
  int kk = (int)(rem % KK);
  int nt = (int)(rem / KK);
  int k = kk * 32 + (lane >> 4) * 8 + j;
  int n = nt * 16 + (lane & 15);
  float v = (k < m.K) ? m.src[(long)k * m.N + n] : 0.f;
  if (m.mode == 0) {
    unsigned short hi = f2b(v);
    dst[m.dhi + local] = hi;
    dst[m.dlo + local] = f2b(v - b2f(hi));
  } else if (m.mode == 3) {
    _Float16 hi = (_Float16)v;
    dst[m.dhi + local] = __builtin_bit_cast(unsigned short, hi);
    dst[m.dlo + local] = f2h((v - (float)hi) * 2048.f);
  } else {
    dst[m.dhi + local] = f2h(v);
  }
}

// ---------------- encoder (bf16 hi/lo 3-term, one-shot) ----------------------
__global__ __launch_bounds__(512, 2)
void enc_kernel(const float* __restrict__ upast, const float* __restrict__ ypast,
                const unsigned short* __restrict__ W1h, const unsigned short* __restrict__ W1l,
                const unsigned short* __restrict__ W2h, const unsigned short* __restrict__ W2l,
                const unsigned short* __restrict__ W3h, const unsigned short* __restrict__ W3l,
                const unsigned short* __restrict__ rWh, const unsigned short* __restrict__ rWl,
                const float* __restrict__ b1, const float* __restrict__ b2,
                const float* __restrict__ b3, const float* __restrict__ rb,
                float* __restrict__ xstate) {
  __shared__ __align__(16) unsigned short h1h[16][264], h1l[16][264];
  __shared__ __align__(16) unsigned short h2h[16][264], h2l[16][264];
  const int tid = threadIdx.x;
  const int w = tid >> 6, l = tid & 63;
  const int c = l & 15, g = l >> 4;
  const int b0 = blockIdx.x << 4;
  const long zrow = (long)(b0 + c) * 512;

  f4v a0 = zero4(), a1 = zero4();
  for (int kk = 0; kk < 32; ++kk) {
    const int cb = kk * 32 + g * 8;
    const float* zp = (cb < 512) ? (upast + zrow + cb) : (ypast + zrow + (cb - 512));
    float4 z0 = *(const float4*)zp;
    float4 z1 = *(const float4*)(zp + 4);
    float zz[8] = {z0.x, z0.y, z0.z, z0.w, z1.x, z1.y, z1.z, z1.w};
    s8v ah, al;
#pragma unroll
    for (int q = 0; q < 8; ++q) {
      unsigned short hi = f2b(zz[q]);
      ah[q] = (short)hi; al[q] = (short)f2b(zz[q] - b2f(hi));
    }
#pragma unroll
    for (int ct = 0; ct < 2; ++ct) {
      s8v bh = *(const s8v*)(W1h + (((long)(2 * w + ct) * 32 + kk) * 64 + l) * 8);
      s8v bl = *(const s8v*)(W1l + (((long)(2 * w + ct) * 32 + kk) * 64 + l) * 8);
      f4v& acc = ct ? a1 : a0;
      acc = mfma16(ah, bh, acc);
      acc = mfma16(al, bh, acc);
      acc = mfma16(ah, bl, acc);
    }
  }
  {
    const float bbA = b1[(2 * w + 0) * 16 + c], bbB = b1[(2 * w + 1) * 16 + c];
#pragma unroll
    for (int j = 0; j < 4; ++j) {
      float tA = tanhf_fast(a0[j] + bbA), tB = tanhf_fast(a1[j] + bbB);
      unsigned short hA = f2b(tA), hB = f2b(tB);
      h1h[g * 4 + j][(2 * w + 0) * 16 + c] = hA;
      h1l[g * 4 + j][(2 * w + 0) * 16 + c] = f2b(tA - b2f(hA));
      h1h[g * 4 + j][(2 * w + 1) * 16 + c] = hB;
      h1l[g * 4 + j][(2 * w + 1) * 16 + c] = f2b(tB - b2f(hB));
    }
  }
  __syncthreads();
  a0 = zero4(); a1 = zero4();
#pragma unroll
  for (int kk = 0; kk < 8; ++kk) {
    s8v ah = *(const s8v*)(&h1h[c][kk * 32 + g * 8]);
    s8v al = *(const s8v*)(&h1l[c][kk * 32 + g * 8]);
#pragma unroll
    for (int ct = 0; ct < 2; ++ct) {
      s8v bh = *(const s8v*)(W2h + (((long)(2 * w + ct) * 8 + kk) * 64 + l) * 8);
      s8v bl = *(const s8v*)(W2l + (((long)(2 * w + ct) * 8 + kk) * 64 + l) * 8);
      f4v& acc = ct ? a1 : a0;
      acc = mfma16(ah, bh, acc);
      acc = mfma16(al, bh, acc);
      acc = mfma16(ah, bl, acc);
    }
  }
  {
    const float bbA = b2[(2 * w + 0) * 16 + c], bbB = b2[(2 * w + 1) * 16 + c];
#pragma unroll
    for (int j = 0; j < 4; ++j) {
      float tA = tanhf_fast(a0[j] + bbA), tB = tanhf_fast(a1[j] + bbB);
      unsigned short hA = f2b(tA), hB = f2b(tB);
      h2h[g * 4 + j][(2 * w + 0) * 16 + c] = hA;
      h2l[g * 4 + j][(2 * w + 0) * 16 + c] = f2b(tA - b2f(hA));
      h2h[g * 4 + j][(2 * w + 1) * 16 + c] = hB;
      h2l[g * 4 + j][(2 * w + 1) * 16 + c] = f2b(tB - b2f(hB));
    }
  }
  __syncthreads();
  f4v ac = zero4();
#pragma unroll
  for (int kk = 0; kk < 8; ++kk) {
    s8v ah = *(const s8v*)(&h2h[c][kk * 32 + g * 8]);
    s8v al = *(const s8v*)(&h2l[c][kk * 32 + g * 8]);
    s8v bh = *(const s8v*)(W3h + (((long)w * 8 + kk) * 64 + l) * 8);
    s8v bl = *(const s8v*)(W3l + (((long)w * 8 + kk) * 64 + l) * 8);
    ac = mfma16(ah, bh, ac);
    ac = mfma16(al, bh, ac);
    ac = mfma16(ah, bl, ac);
  }
  for (int kk = 0; kk < 32; ++kk) {
    const int cb = kk * 32 + g * 8;
    const float* zp = (cb < 512) ? (upast + zrow + cb) : (ypast + zrow + (cb - 512));
    float4 z0 = *(const float4*)zp;
    float4 z1 = *(const float4*)(zp + 4);
    float zz[8] = {z0.x, z0.y, z0.z, z0.w, z1.x, z1.y, z1.z, z1.w};
    s8v ah, al;
#pragma unroll
    for (int q = 0; q < 8; ++q) {
      unsigned short hi = f2b(zz[q]);
      ah[q] = (short)hi; al[q] = (short)f2b(zz[q] - b2f(hi));
    }
    s8v bh = *(const s8v*)(rWh + (((long)w * 32 + kk) * 64 + l) * 8);
    s8v bl = *(const s8v*)(rWl + (((long)w * 32 + kk) * 64 + l) * 8);
    ac = mfma16(ah, bh, ac);
    ac = mfma16(al, bh, ac);
    ac = mfma16(ah, bl, ac);
  }
  {
    const float bias = b3[w * 16 + c] + rb[w * 16 + c];
#pragma unroll
    for (int j = 0; j < 4; ++j)
      xstate[(long)(b0 + g * 4 + j) * 128 + w * 16 + c] = ac[j] + bias;
  }
}

// ---------------- recurrence (16 waves, 1 coltile/wave, AGPR lo-weights) -----
__global__ __launch_bounds__(1024, 4)
void recur_kernel(const float* __restrict__ ufut,
                  const unsigned short* __restrict__ W1h, const unsigned short* __restrict__ W1l,
                  const unsigned short* __restrict__ W2h, const unsigned short* __restrict__ W2l,
                  const unsigned short* __restrict__ W3h, const unsigned short* __restrict__ W3l,
                  const unsigned short* __restrict__ rWh, const unsigned short* __restrict__ rWl,
                  const float* __restrict__ b1, const float* __restrict__ b2,
                  const float* __restrict__ b3, const float* __restrict__ rb,
                  float* __restrict__ xstate,
                  unsigned short* __restrict__ xfh, unsigned short* __restrict__ xfl,
                  int t0, int len) {
  __shared__ __align__(16) unsigned short xu_h[16][136], xu_l[16][136];
  __shared__ __align__(16) unsigned short h1h[16][264], h1l[16][264];
  __shared__ __align__(16) unsigned short h2h[16][264], h2l[16][264];
  __shared__ __align__(16) unsigned short w3h_l[32768];  // W3 hi  (64 KB)
  __shared__ __align__(16) unsigned short rwh_l[20480];  // rW hi  (40 KB)
  __shared__ __align__(16) float part[16][136];          // rW partial (8.5 KB)
  const int tid = threadIdx.x;
  const int w = tid >> 6, l = tid & 63;
  const int c = l & 15, g = l >> 4;
  const int b0 = blockIdx.x << 4;

  // persistent VGPR (52): W1 hi 20, W2 hi 32
  h8v w1h_r[5], w2h_r[8];
#pragma unroll
  for (int kk = 0; kk < 5; ++kk)
    w1h_r[kk] = *(const h8v*)(W1h + (((long)w * 5 + kk) * 64 + l) * 8);
#pragma unroll
  for (int kk = 0; kk < 8; ++kk)
    w2h_r[kk] = *(const h8v*)(W2h + (((long)w * 8 + kk) * 64 + l) * 8);

  // persistent AGPR (64): W2 lo (8 frags) + {W3 lo | rW lo} (8 frags)
  i4v w2l_a[8], g3l_a[8];
#pragma unroll
  for (int kk = 0; kk < 8; ++kk)
    w2l_a[kk] = to_agpr(*(const i4v*)(W2l + (((long)w * 8 + kk) * 64 + l) * 8));
  {
    const unsigned short* g3base = (w < 8) ? W3l : rWl;
    const long g3off = (w < 8) ? (long)w * 8 : (long)(w - 8) * 5;
    const int g3n = (w < 8) ? 8 : 5;
#pragma unroll
    for (int kk = 0; kk < 8; ++kk) {
      i4v v = (i4v){0, 0, 0, 0};
      if (kk < g3n) v = *(const i4v*)(g3base + ((g3off + kk) * 64 + l) * 8);
      g3l_a[kk] = to_agpr(v);
    }
  }

  // LDS weights (linear copies)
  for (int i = tid; i < 4096; i += 1024) ((h8v*)w3h_l)[i] = ((const h8v*)W3h)[i];
  for (int i = tid; i < 2560; i += 1024) ((h8v*)rwh_l)[i] = ((const h8v*)rWh)[i];

  const float bb = b1[w * 16 + c];
  const float cb = b2[w * 16 + c];
  const float dB = (w < 8) ? (b3[w * 16 + c] + rb[w * 16 + c]) : 0.f;

  // seed state pair
  for (int idx = tid; idx < 2048; idx += 1024) {
    int r = idx >> 7, cc = idx & 127;
    float x = xstate[(long)(b0 + r) * 128 + cc];
    _Float16 hi = (_Float16)x;
    xu_h[r][cc] = __builtin_bit_cast(unsigned short, hi);
    xu_l[r][cc] = f2h((x - (float)hi) * 2048.f);
  }
  // u double-buffer in regs: load u(t0)
  float4 uc0, uc1;
  if (g < 2) {
    const float* up = ufut + ((long)(b0 + c) * 256 + t0) * 16 + g * 8;
    uc0 = *(const float4*)up;
    uc1 = *(const float4*)(up + 4);
  }
  __syncthreads();

  for (int tc = 0; tc < len; ++tc) {
    const int t = t0 + tc;
    // launder the single remaining streamed base (blocks LICM hoist)
    long lz = 0;
    asm volatile("" : "+s"(lz));
    const unsigned short* W1ls = W1l + lz;

    // issue next-step u load early (hidden under G1-G3)
    float4 un0, un1;
    {
      const int tt = (tc + 1 < len) ? (t + 1) : t;
      if (g < 2) {
        const float* up = ufut + ((long)(b0 + c) * 256 + tt) * 16 + g * 8;
        un0 = *(const float4*)up;
        un1 = *(const float4*)(up + 4);
      }
    }
    // build u fragment (kk=4 of K=160 padded input) from current regs
    h8v ah4 = zeroh8(), al4 = zeroh8();
    if (g < 2) {
      float uu[8] = {uc0.x, uc0.y, uc0.z, uc0.w, uc1.x, uc1.y, uc1.z, uc1.w};
#pragma unroll
      for (int q = 0; q < 8; ++q) {
        _Float16 hi = (_Float16)uu[q];
        ah4[q] = hi;
        al4[q] = (_Float16)((uu[q] - (float)hi) * 2048.f);
      }
    }
    // xf store (reads current state; no xu writes this phase)
    {
      int r = tid >> 6, cc0 = (tid & 63) * 2;
      long row = ((long)(b0 + r) * len + tc) * 128 + cc0;
      *(unsigned int*)(xfh + row) =
          (unsigned int)xu_h[r][cc0] | ((unsigned int)xu_h[r][cc0 + 1] << 16);
      *(unsigned int*)(xfl + row) =
          (unsigned int)xu_l[r][cc0] | ((unsigned int)xu_l[r][cc0 + 1] << 16);
    }
    // G1: xu pair x W1 (hi regs, lo stream) -> h1 pair; coltile = w
    {
      f4v p = zero4(), q = zero4();
#pragma unroll
      for (int kk = 0; kk < 5; ++kk) {
        h8v ah, al;
        if (kk < 4) {
          ah = *(const h8v*)(&xu_h[c][kk * 32 + g * 8]);
          al = *(const h8v*)(&xu_l[c][kk * 32 + g * 8]);
        } else { ah = ah4; al = al4; }
        h8v bl = *(const h8v*)(W1ls + (((long)w * 5 + kk) * 64 + l) * 8);
        p = mfmaH(ah, w1h_r[kk], p);
        q = mfmaH(al, w1h_r[kk], q);
        q = mfmaH(ah, bl, q);
      }
#pragma unroll
      for (int j = 0; j < 4; ++j) {
        float tv = tanhf_fast(p[j] + q[j] * 0x1p-11f + bb);
        _Float16 hi = (_Float16)tv;
        h1h[g * 4 + j][w * 16 + c] = __builtin_bit_cast(unsigned short, hi);
        h1l[g * 4 + j][w * 16 + c] = f2h((tv - (float)hi) * 2048.f);
      }
    }
    __syncthreads();  // A: h1 ready
    // G2: h1 pair x W2 (hi VGPR, lo AGPR) -> h2 pair; coltile = w
    {
      f4v p = zero4(), q = zero4(), r2 = zero4();
#pragma unroll
      for (int kk = 0; kk < 8; ++kk) {
        h8v ah = *(const h8v*)(&h1h[c][kk * 32 + g * 8]);
        h8v al = *(const h8v*)(&h1l[c][kk * 32 + g * 8]);
        h8v bl = from_agpr(w2l_a[kk]);
        p = mfmaH(ah, w2h_r[kk], p);
        q = mfmaH(al, w2h_r[kk], q);
        r2 = mfmaH(ah, bl, r2);
      }
#pragma unroll
      for (int j = 0; j < 4; ++j) {
        float tv = tanhf_fast(p[j] + (q[j] + r2[j]) * 0x1p-11f + cb);
        _Float16 hi = (_Float16)tv;
        h2h[g * 4 + j][w * 16 + c] = __builtin_bit_cast(unsigned short, hi);
        h2l[g * 4 + j][w * 16 + c] = f2h((tv - (float)hi) * 2048.f);
      }
    }
    __syncthreads();  // B: h2 ready
    // G3 split: waves 0-7 h2@W3 (hi LDS, lo AGPR); waves 8-15 xu@rW (hi LDS,
    // lo AGPR) -> f32 partials in LDS
    float pv[4], qv[4];
    if (w < 8) {
      f4v p = zero4(), q = zero4(), r2 = zero4();
#pragma unroll
      for (int kk = 0; kk < 8; ++kk) {
        h8v ah = *(const h8v*)(&h2h[c][kk * 32 + g * 8]);
        h8v al = *(const h8v*)(&h2l[c][kk * 32 + g * 8]);
        h8v bh = *(const h8v*)(&w3h_l[(((long)w * 8 + kk) * 64 + l) * 8]);
        h8v bl = from_agpr(g3l_a[kk]);
        p = mfmaH(ah, bh, p);
        q = mfmaH(al, bh, q);
        r2 = mfmaH(ah, bl, r2);
      }
#pragma unroll
      for (int j = 0; j < 4; ++j) { pv[j] = p[j]; qv[j] = q[j] + r2[j]; }
    } else {
      const int cw = w - 8;
      f4v p = zero4(), q = zero4();
#pragma unroll
      for (int kk = 0; kk < 5; ++kk) {
        h8v ah, al;
        if (kk < 4) {
          ah = *(const h8v*)(&xu_h[c][kk * 32 + g * 8]);
          al = *(const h8v*)(&xu_l[c][kk * 32 + g * 8]);
        } else { ah = ah4; al = al4; }
        h8v bh = *(const h8v*)(&rwh_l[(((long)cw * 5 + kk) * 64 + l) * 8]);
        h8v bl = from_agpr(g3l_a[kk]);
        p = mfmaH(ah, bh, p);
        q = mfmaH(al, bh, q);
        q = mfmaH(ah, bl, q);
      }
#pragma unroll
      for (int j = 0; j < 4; ++j)
        part[g * 4 + j][cw * 16 + c] = p[j] + q[j] * 0x1p-11f;
    }
    __syncthreads();  // C: partials ready; all xu reads done
    // D: waves 0-7 combine + state write
    if (w < 8) {
#pragma unroll
      for (int j = 0; j < 4; ++j) {
        float xn = pv[j] + qv[j] * 0x1p-11f + part[g * 4 + j][w * 16 + c] + dB;
        _Float16 hi = (_Float16)xn;
        xu_h[g * 4 + j][w * 16 + c] = __builtin_bit_cast(unsigned short, hi);
        xu_l[g * 4 + j][w * 16 + c] = f2h((xn - (float)hi) * 2048.f);
      }
    }
    uc0 = un0; uc1 = un1;
    __syncthreads();  // D: state ready for next step
  }
  // chunk-final state writeback (fp32 = hi + lo*2^-11, exact)
  for (int idx = tid; idx < 2048; idx += 1024) {
    int r = idx >> 7, cc = idx & 127;
    xstate[(long)(b0 + r) * 128 + cc] =
        h2f(xu_h[r][cc]) + h2f(xu_l[r][cc]) * 0x1p-11f;
  }
}

// ---------------- output network h (xf pair x f16-single weights) ------------
__global__ __launch_bounds__(512, 2)
void hnet_kernel(const unsigned short* __restrict__ xfh, const unsigned short* __restrict__ xfl,
                 const unsigned short* __restrict__ W1, const unsigned short* __restrict__ W2,
                 const unsigned short* __restrict__ W3, const unsigned short* __restrict__ rW,
                 const float* __restrict__ b1, const float* __restrict__ b2,
                 const float* __restrict__ b3, const float* __restrict__ rb,
                 float* __restrict__ out, int t0, int len) {
  __shared__ __align__(16) unsigned short h1[64][264];
  __shared__ __align__(16) unsigned short h2[64][264];
  __shared__ float part[4][16][16];
  const int tid = threadIdx.x;
  const int w = tid >> 6, l = tid & 63;
  const int c = l & 15, g = l >> 4;
  const long row0 = (long)blockIdx.x * 64;

  {  // stage A: h1 = tanh(xf(pair) @ W1 + b1)
    h8v w1f[2][4];
#pragma unroll
    for (int ct = 0; ct < 2; ++ct)
#pragma unroll
      for (int kk = 0; kk < 4; ++kk)
        w1f[ct][kk] = *(const h8v*)(W1 + (((long)(2 * w + ct) * 4 + kk) * 64 + l) * 8);
    const float bbA = b1[(2 * w + 0) * 16 + c], bbB = b1[(2 * w + 1) * 16 + c];
    for (int rt = 0; rt < 4; ++rt) {
      f4v t10 = zero4(), tl0 = zero4(), t11 = zero4(), tl1 = zero4();
#pragma unroll
      for (int kk = 0; kk < 4; ++kk) {
        h8v ah = *(const h8v*)(xfh + (row0 + rt * 16 + c) * 128 + kk * 32 + g * 8);
        h8v al = *(const h8v*)(xfl + (row0 + rt * 16 + c) * 128 + kk * 32 + g * 8);
        t10 = mfmaH(ah, w1f[0][kk], t10);
        tl0 = mfmaH(al, w1f[0][kk], tl0);
        t11 = mfmaH(ah, w1f[1][kk], t11);
        tl1 = mfmaH(al, w1f[1][kk], tl1);
      }
#pragma unroll
      for (int j = 0; j < 4; ++j) {
        h1[rt * 16 + g * 4 + j][(2 * w + 0) * 16 + c] =
            f2h(tanhf_fast(t10[j] + tl0[j] * 0x1p-11f + bbA));
        h1[rt * 16 + g * 4 + j][(2 * w + 1) * 16 + c] =
            f2h(tanhf_fast(t11[j] + tl1[j] * 0x1p-11f + bbB));
      }
    }
  }
  __syncthreads();
  {  // stage B: h2 = tanh(h1 @ W2 + b2), f16 single
    h8v w2f[2][8];
#pragma unroll
    for (int ct = 0; ct < 2; ++ct)
#pragma unroll
      for (int kk = 0; kk < 8; ++kk)
        w2f[ct][kk] = *(const h8v*)(W2 + (((long)(2 * w + ct) * 8 + kk) * 64 + l) * 8);
    const float bbA = b2[(2 * w + 0) * 16 + c], bbB = b2[(2 * w + 1) * 16 + c];
    for (int rt = 0; rt < 4; ++rt) {
      f4v a0 = zero4(), a1 = zero4();
#pragma unroll
      for (int kk = 0; kk < 8; ++kk) {
        h8v a = *(const h8v*)(&h1[rt * 16 + c][kk * 32 + g * 8]);
        a0 = mfmaH(a, w2f[0][kk], a0);
        a1 = mfmaH(a, w2f[1][kk], a1);
      }
#pragma unroll
      for (int j = 0; j < 4; ++j) {
        h2[rt * 16 + g * 4 + j][(2 * w + 0) * 16 + c] = f2h(tanhf_fast(a0[j] + bbA));
        h2[rt * 16 + g * 4 + j][(2 * w + 1) * 16 + c] = f2h(tanhf_fast(a1[j] + bbB));
      }
    }
  }
  __syncthreads();
  {  // stage C: y = h2 @ W3 + xf(pair) @ rW + b3 + rb
    const int rt = w & 3, kh = w >> 2;
    f4v t1 = zero4(), tl = zero4();
#pragma unroll
    for (int kk = 0; kk < 4; ++kk) {
      const int kkg = kh * 4 + kk;
      h8v a = *(const h8v*)(&h2[rt * 16 + c][kkg * 32 + g * 8]);
      h8v b = *(const h8v*)(W3 + ((long)(kkg * 64 + l)) * 8);
      t1 = mfmaH(a, b, t1);
    }
#pragma unroll
    for (int kk = 0; kk < 2; ++kk) {
      const int kkg = kh * 2 + kk;
      h8v ah = *(const h8v*)(xfh + (row0 + rt * 16 + c) * 128 + kkg * 32 + g * 8);
      h8v al = *(const h8v*)(xfl + (row0 + rt * 16 + c) * 128 + kkg * 32 + g * 8);
      h8v b = *(const h8v*)(rW + ((long)(kkg * 64 + l)) * 8);
      t1 = mfmaH(ah, b, t1);
      tl = mfmaH(al, b, tl);
    }
    float val[4];
#pragma unroll
    for (int j = 0; j < 4; ++j) val[j] = t1[j] + tl[j] * 0x1p-11f;
    if (w >= 4) {
#pragma unroll
      for (int j = 0; j < 4; ++j) part[rt][g * 4 + j][c] = val[j];
    }
    __syncthreads();
    if (w < 4) {
      const float bias = b3[c] + rb[c];
#pragma unroll
      for (int j = 0; j < 4; ++j) {
        const long grow = row0 + rt * 16 + g * 4 + j;
        const long bq = grow / len;
        const int tq = (int)(grow - bq * len);
        out[(bq * 256 + (t0 + tq)) * 16 + c] = val[j] + part[rt][g * 4 + j][c] + bias;
      }
    }
  }
}

// ---------------- host -------------------------------------------------------
extern "C" void kernel_launch(void* const* d_in, const int* in_sizes, int n_in,
                              void* d_out, int out_size, void* d_ws, size_t ws_size,
                              hipStream_t stream) {
  (void)in_sizes; (void)n_in; (void)out_size;
  const float* upast = (const float*)d_in[0];
  const float* ypast = (const float*)d_in[1];
  const float* ufut  = (const float*)d_in[2];
  const float* e_rW = (const float*)d_in[3];
  const float* e_rb = (const float*)d_in[4];
  const float* e_W1 = (const float*)d_in[5];
  const float* e_b1 = (const float*)d_in[6];
  const float* e_W2 = (const float*)d_in[7];
  const float* e_b2 = (const float*)d_in[8];
  const float* e_W3 = (const float*)d_in[9];
  const float* e_b3 = (const float*)d_in[10];
  const float* f_rW = (const float*)d_in[11];
  const float* f_rb = (const float*)d_in[12];
  const float* f_W1 = (const float*)d_in[13];
  const float* f_b1 = (const float*)d_in[14];
  const float* f_W2 = (const float*)d_in[15];
  const float* f_b2 = (const float*)d_in[16];
  const float* f_W3 = (const float*)d_in[17];
  const float* f_b3 = (const float*)d_in[18];
  const float* h_rW = (const float*)d_in[19];
  const float* h_rb = (const float*)d_in[20];
  const float* h_W1 = (const float*)d_in[21];
  const float* h_b1 = (const float*)d_in[22];
  const float* h_W2 = (const float*)d_in[23];
  const float* h_b2 = (const float*)d_in[24];
  const float* h_W3 = (const float*)d_in[25];
  const float* h_b3 = (const float*)d_in[26];
  float* out = (float*)d_out;

  // swizzle table: e_* bf16 pair (mode0), f_* f16 pair (mode3), h_* f16 (mode1)
  const float* srcs[12] = { e_W1, e_W2, e_W3, e_rW, f_W1, f_W2, f_W3, f_rW,
                            h_W1, h_W2, h_W3, h_rW };
  const int Ks [12] = {1024, 256, 256, 1024, 144, 256, 256, 144, 128, 256, 256, 128};
  const int Kps[12] = {1024, 256, 256, 1024, 160, 256, 256, 160, 128, 256, 256, 128};
  const int Ns [12] = { 256, 256, 128,  128, 256, 256, 128, 128, 256, 256,  16,  16};
  const int modes[12] = {0,0,0,0, 3,3,3,3, 1,1,1,1};

  SwzTable tbl;
  long woff = 0, offs[12];
  for (int i = 0; i < 12; ++i) { offs[i] = woff; woff += (long)Kps[i] * Ns[i]; }
  const long EA = offs[4];              // e-region elems
  const long FB = 2 * EA;
  const long EB = offs[8] - offs[4];    // f-region elems
  const long HB = FB + 2 * EB;
  for (int i = 0; i < 12; ++i) {
    tbl.d[i].src = srcs[i]; tbl.d[i].woff = offs[i];
    tbl.d[i].K = Ks[i]; tbl.d[i].Kp = Kps[i]; tbl.d[i].N = Ns[i]; tbl.d[i].mode = modes[i];
    if (modes[i] == 0)      { tbl.d[i].dhi = offs[i];              tbl.d[i].dlo = EA + offs[i]; }
    else if (modes[i] == 3) { long lo = offs[i] - offs[4];
                              tbl.d[i].dhi = FB + lo;              tbl.d[i].dlo = FB + EB + lo; }
    else                    { long lo = offs[i] - offs[8];
                              tbl.d[i].dhi = HB + lo;              tbl.d[i].dlo = 0; }
  }
  tbl.tot_work = woff;

  unsigned short* wswz = (unsigned short*)d_ws;
  const long WSHORTS = HB + (offs[11] - offs[8]) + (long)Kps[11] * Ns[11];
  const size_t XOFF = ((size_t)WSHORTS * 2 + 4095) & ~(size_t)4095;
  float* xstate = (float*)((char*)d_ws + XOFF);
  const size_t XF0 = XOFF + (2u << 20);
  int c = 64;
  {
    long cmax = ((long)ws_size - (long)XF0) >> 21;  // 2 MB per time-step (pair)
    if (cmax < c) c = (int)cmax;
    if (c < 1) c = 1;
  }
  unsigned short* xfh = (unsigned short*)((char*)d_ws + XF0);
  unsigned short* xfl = (unsigned short*)((char*)d_ws + XF0 + (size_t)c * 1048576);

  // kernel weight pointers
  const unsigned short* eW1h = wswz + offs[0];          const unsigned short* eW1l = wswz + EA + offs[0];
  const unsigned short* eW2h = wswz + offs[1];          const unsigned short* eW2l = wswz + EA + offs[1];
  const unsigned short* eW3h = wswz + offs[2];          const unsigned short* eW3l = wswz + EA + offs[2];
  const unsigned short* erWh = wswz + offs[3];          const unsigned short* erWl = wswz + EA + offs[3];
  const unsigned short* fW1h = wswz + FB + 0;           const unsigned short* fW1l = wswz + FB + EB + 0;
  const unsigned short* fW2h = wswz + FB + 40960;       const unsigned short* fW2l = wswz + FB + EB + 40960;
  const unsigned short* fW3h = wswz + FB + 106496;      const unsigned short* fW3l = wswz + FB + EB + 106496;
  const unsigned short* frWh = wswz + FB + 139264;      const unsigned short* frWl = wswz + FB + EB + 139264;
  const unsigned short* hW1 = wswz + HB + 0;
  const unsigned short* hW2 = wswz + HB + 32768;
  const unsigned short* hW3 = wswz + HB + 98304;
  const unsigned short* hrW = wswz + HB + 102400;

  swz_kernel<<<(int)((tbl.tot_work + 255) / 256), 256, 0, stream>>>(tbl, wswz);
  enc_kernel<<<256, 512, 0, stream>>>(upast, ypast,
                                      eW1h, eW1l, eW2h, eW2l, eW3h, eW3l, erWh, erWl,
                                      e_b1, e_b2, e_b3, e_rb, xstate);
  for (int t0 = 0; t0 < 256; t0 += c) {
    int len = 256 - t0; if (len > c) len = c;
    recur_kernel<<<256, 1024, 0, stream>>>(ufut, fW1h, fW1l, fW2h, fW2l, fW3h, fW3l,
                                           frWh, frWl, f_b1, f_b2, f_b3, f_rb,
                                           xstate, xfh, xfl, t0, len);
    hnet_kernel<<<64 * len, 512, 0, stream>>>(xfh, xfl, hW1, hW2, hW3, hrW,
                                              h_b1, h_b2, h_b3, h_rb, out, t0, len);
  }
}

// Round 10
// 2973.545 us; speedup vs baseline: 1.5529x; 1.5371x over previous
//
#include <hip/hip_runtime.h>
#include <stdint.h>

// SUBNET_15290083574166: encoder MLP -> 256-step recurrent f MLP -> output h MLP
// B=4096, T=256, NX=128, NU=16, NY=16, NB=NA=32, H=256
//
// Precision (VERIFIED r4-r9, absmax 0.0625 vs thr 0.24): f16 hi/lo pairs
// (2^-22) on all recurrence operands, 2-accum (hi + lo*2^-11); encoder bf16
// pairs; hnet xf-pair x f16-single. DO NOT change the numerics.
//
// r10: consolidation round.
//  - recur/enc/swz/host: BYTE-IDENTICAL revert to the round-4 source (best
//    measured recur: 577us/dispatch, VGPR 128 + compiler AGPR-stash,
//    FETCH 152MB). r5-r9 proved every manual occupancy/AGPR intervention
//    loses to the allocator at this shape.
//  - hnet: weight-persistent rewrite. Old: 4096 blocks x 64 rows, EVERY block
//    re-reads 204KB of h-weights from L2 (~940MB/chunk, 3.4us/block L2 time
//    vs 0.3us MFMA). New: 256 blocks, weights loaded ONCE (hW1+hW2even in
//    regs, hW2odd in 64KB LDS), grid-stride 16 x 64-row tiles. 16x less
//    weight traffic; identical per-tile arithmetic (bit-identical output).

typedef __attribute__((ext_vector_type(8))) short s8v;      // 8 bf16 bits
typedef __attribute__((ext_vector_type(8))) _Float16 h8v;   // 8 f16
typedef __attribute__((ext_vector_type(4))) float f4v;

__device__ __forceinline__ f4v mfma16(s8v a, s8v b, f4v c) {
  return __builtin_amdgcn_mfma_f32_16x16x32_bf16(a, b, c, 0, 0, 0);
}
__device__ __forceinline__ f4v mfmaH(h8v a, h8v b, f4v c) {
  return __builtin_amdgcn_mfma_f32_16x16x32_f16(a, b, c, 0, 0, 0);
}
__device__ __forceinline__ f4v zero4() { return (f4v){0.f, 0.f, 0.f, 0.f}; }

__device__ __forceinline__ unsigned short f2b(float x) {  // f32->bf16 RNE
  unsigned int u = __builtin_bit_cast(unsigned int, x);
  u += 0x7fffu + ((u >> 16) & 1u);
  return (unsigned short)(u >> 16);
}
__device__ __forceinline__ float b2f(unsigned short h) {
  return __builtin_bit_cast(float, (unsigned int)h << 16);
}
__device__ __forceinline__ unsigned short f2h(float x) {
  return __builtin_bit_cast(unsigned short, (_Float16)x);
}
__device__ __forceinline__ float h2f(unsigned short h) {
  return (float)__builtin_bit_cast(_Float16, h);
}

__device__ __forceinline__ float tanhf_fast(float x) {
  x = fminf(15.f, fmaxf(-15.f, x));
  float e = __expf(2.f * x);
  return (e - 1.f) / (e + 1.f);
}

// ---------------- weight swizzle: fp32 [K][N] -> fragment order ---------------
// frag: idx(nt,kk,lane,j) = ((nt*KK + kk)*64 + lane)*8 + j
//   holds W[kk*32 + (lane>>4)*8 + j][nt*16 + (lane&15)]  (zero-pad k>=K)
// mode 0: bf16 hi at dst[dhi+local], bf16 lo at dst[dlo+local]
// mode 3: f16 hi at dst[dhi+local], f16((v-hi)*2048) at dst[dlo+local]
// mode 1: f16 at dst[dhi+local]
struct SwzDesc { const float* src; long woff; long dhi; long dlo; int K; int Kp; int N; int mode; };
struct SwzTable { SwzDesc d[12]; long tot_work; };

__global__ void swz_kernel(SwzTable tbl, unsigned short* __restrict__ dst) {
  long gid = (long)blockIdx.x * 256 + threadIdx.x;
  if (gid >= tbl.tot_work) return;
  int i = 11;
  while (i > 0 && gid < tbl.d[i].woff) --i;
  const SwzDesc m = tbl.d[i];
  long local = gid - m.woff;
  int j = (int)(local & 7);
  int lane = (int)((local >> 3) & 63);
  long rem = local >> 9;
  int KK = m.Kp >> 5;
  int kk = (int)(rem % KK);
  int nt = (int)(rem / KK);
  int k = kk * 32 + (lane >> 4) * 8 + j;
  int n = nt * 16 + (lane & 15);
  float v = (k < m.K) ? m.src[(long)k * m.N + n] : 0.f;
  if (m.mode == 0) {
    unsigned short hi = f2b(v);
    dst[m.dhi + local] = hi;
    dst[m.dlo + local] = f2b(v - b2f(hi));
  } else if (m.mode == 3) {
    _Float16 hi = (_Float16)v;
    dst[m.dhi + local] = __builtin_bit_cast(unsigned short, hi);
    dst[m.dlo + local] = f2h((v - (float)hi) * 2048.f);
  } else {
    dst[m.dhi + local] = f2h(v);
  }
}

// ---------------- encoder (bf16 hi/lo 3-term, one-shot) ----------------------
__global__ __launch_bounds__(512, 2)
void enc_kernel(const float* __restrict__ upast, const float* __restrict__ ypast,
                const unsigned short* __restrict__ W1h, const unsigned short* __restrict__ W1l,
                const unsigned short* __restrict__ W2h, const unsigned short* __restrict__ W2l,
                const unsigned short* __restrict__ W3h, const unsigned short* __restrict__ W3l,
                const unsigned short* __restrict__ rWh, const unsigned short* __restrict__ rWl,
                const float* __restrict__ b1, const float* __restrict__ b2,
                const float* __restrict__ b3, const float* __restrict__ rb,
                float* __restrict__ xstate) {
  __shared__ __align__(16) unsigned short h1h[16][264], h1l[16][264];
  __shared__ __align__(16) unsigned short h2h[16][264], h2l[16][264];
  const int tid = threadIdx.x;
  const int w = tid >> 6, l = tid & 63;
  const int c = l & 15, g = l >> 4;
  const int b0 = blockIdx.x << 4;
  const long zrow = (long)(b0 + c) * 512;

  f4v a0 = zero4(), a1 = zero4();
  for (int kk = 0; kk < 32; ++kk) {
    const int cb = kk * 32 + g * 8;
    const float* zp = (cb < 512) ? (upast + zrow + cb) : (ypast + zrow + (cb - 512));
    float4 z0 = *(const float4*)zp;
    float4 z1 = *(const float4*)(zp + 4);
    float zz[8] = {z0.x, z0.y, z0.z, z0.w, z1.x, z1.y, z1.z, z1.w};
    s8v ah, al;
#pragma unroll
    for (int q = 0; q < 8; ++q) {
      unsigned short hi = f2b(zz[q]);
      ah[q] = (short)hi; al[q] = (short)f2b(zz[q] - b2f(hi));
    }
#pragma unroll
    for (int ct = 0; ct < 2; ++ct) {
      s8v bh = *(const s8v*)(W1h + (((long)(2 * w + ct) * 32 + kk) * 64 + l) * 8);
      s8v bl = *(const s8v*)(W1l + (((long)(2 * w + ct) * 32 + kk) * 64 + l) * 8);
      f4v& acc = ct ? a1 : a0;
      acc = mfma16(ah, bh, acc);
      acc = mfma16(al, bh, acc);
      acc = mfma16(ah, bl, acc);
    }
  }
  {
    const float bbA = b1[(2 * w + 0) * 16 + c], bbB = b1[(2 * w + 1) * 16 + c];
#pragma unroll
    for (int j = 0; j < 4; ++j) {
      float tA = tanhf_fast(a0[j] + bbA), tB = tanhf_fast(a1[j] + bbB);
      unsigned short hA = f2b(tA), hB = f2b(tB);
      h1h[g * 4 + j][(2 * w + 0) * 16 + c] = hA;
      h1l[g * 4 + j][(2 * w + 0) * 16 + c] = f2b(tA - b2f(hA));
      h1h[g * 4 + j][(2 * w + 1) * 16 + c] = hB;
      h1l[g * 4 + j][(2 * w + 1) * 16 + c] = f2b(tB - b2f(hB));
    }
  }
  __syncthreads();
  a0 = zero4(); a1 = zero4();
#pragma unroll
  for (int kk = 0; kk < 8; ++kk) {
    s8v ah = *(const s8v*)(&h1h[c][kk * 32 + g * 8]);
    s8v al = *(const s8v*)(&h1l[c][kk * 32 + g * 8]);
#pragma unroll
    for (int ct = 0; ct < 2; ++ct) {
      s8v bh = *(const s8v*)(W2h + (((long)(2 * w + ct) * 8 + kk) * 64 + l) * 8);
      s8v bl = *(const s8v*)(W2l + (((long)(2 * w + ct) * 8 + kk) * 64 + l) * 8);
      f4v& acc = ct ? a1 : a0;
      acc = mfma16(ah, bh, acc);
      acc = mfma16(al, bh, acc);
      acc = mfma16(ah, bl, acc);
    }
  }
  {
    const float bbA = b2[(2 * w + 0) * 16 + c], bbB = b2[(2 * w + 1) * 16 + c];
#pragma unroll
    for (int j = 0; j < 4; ++j) {
      float tA = tanhf_fast(a0[j] + bbA), tB = tanhf_fast(a1[j] + bbB);
      unsigned short hA = f2b(tA), hB = f2b(tB);
      h2h[g * 4 + j][(2 * w + 0) * 16 + c] = hA;
      h2l[g * 4 + j][(2 * w + 0) * 16 + c] = f2b(tA - b2f(hA));
      h2h[g * 4 + j][(2 * w + 1) * 16 + c] = hB;
      h2l[g * 4 + j][(2 * w + 1) * 16 + c] = f2b(tB - b2f(hB));
    }
  }
  __syncthreads();
  f4v ac = zero4();
#pragma unroll
  for (int kk = 0; kk < 8; ++kk) {
    s8v ah = *(const s8v*)(&h2h[c][kk * 32 + g * 8]);
    s8v al = *(const s8v*)(&h2l[c][kk * 32 + g * 8]);
    s8v bh = *(const s8v*)(W3h + (((long)w * 8 + kk) * 64 + l) * 8);
    s8v bl = *(const s8v*)(W3l + (((long)w * 8 + kk) * 64 + l) * 8);
    ac = mfma16(ah, bh, ac);
    ac = mfma16(al, bh, ac);
    ac = mfma16(ah, bl, ac);
  }
  for (int kk = 0; kk < 32; ++kk) {
    const int cb = kk * 32 + g * 8;
    const float* zp = (cb < 512) ? (upast + zrow + cb) : (ypast + zrow + (cb - 512));
    float4 z0 = *(const float4*)zp;
    float4 z1 = *(const float4*)(zp + 4);
    float zz[8] = {z0.x, z0.y, z0.z, z0.w, z1.x, z1.y, z1.z, z1.w};
    s8v ah, al;
#pragma unroll
    for (int q = 0; q < 8; ++q) {
      unsigned short hi = f2b(zz[q]);
      ah[q] = (short)hi; al[q] = (short)f2b(zz[q] - b2f(hi));
    }
    s8v bh = *(const s8v*)(rWh + (((long)w * 32 + kk) * 64 + l) * 8);
    s8v bl = *(const s8v*)(rWl + (((long)w * 32 + kk) * 64 + l) * 8);
    ac = mfma16(ah, bh, ac);
    ac = mfma16(al, bh, ac);
    ac = mfma16(ah, bl, ac);
  }
  {
    const float bias = b3[w * 16 + c] + rb[w * 16 + c];
#pragma unroll
    for (int j = 0; j < 4; ++j)
      xstate[(long)(b0 + g * 4 + j) * 128 + w * 16 + c] = ac[j] + bias;
  }
}

// ---------------- recurrence (f16 pairs everywhere) --------------------------
// regs persistent (184): W1 pair 80, W2hi 64, rW pair 40. LDS: W3 pair 128KB +
// activations ~27KB. W2lo streamed from L2 via rolling 8-frag window.
__global__ __launch_bounds__(512, 2)
void recur_kernel(const float* __restrict__ ufut,
                  const unsigned short* __restrict__ W1h, const unsigned short* __restrict__ W1l,
                  const unsigned short* __restrict__ W2h, const unsigned short* __restrict__ W2l,
                  const unsigned short* __restrict__ W3h, const unsigned short* __restrict__ W3l,
                  const unsigned short* __restrict__ rWh, const unsigned short* __restrict__ rWl,
                  const float* __restrict__ b1, const float* __restrict__ b2,
                  const float* __restrict__ b3, const float* __restrict__ rb,
                  float* __restrict__ xstate,
                  unsigned short* __restrict__ xfh, unsigned short* __restrict__ xfl,
                  int t0, int len) {
  __shared__ __align__(16) unsigned short xu_h[16][168], xu_l[16][168];
  __shared__ __align__(16) unsigned short hh[16][264], hl[16][264];
  __shared__ __align__(16) unsigned short w3h_l[32768];   // W3 hi, full
  __shared__ __align__(16) unsigned short w3l_l[32768];   // W3 lo, full
  const int tid = threadIdx.x;
  const int w = tid >> 6, l = tid & 63;
  const int c = l & 15, g = l >> 4;
  const int b0 = blockIdx.x << 4;

  // persistent register fragments (f16)
  h8v w1h_r[2][5], w1l_r[2][5], w2h_r[2][8], rwh_r[5], rwl_r[5];
#pragma unroll
  for (int ct = 0; ct < 2; ++ct) {
#pragma unroll
    for (int kk = 0; kk < 5; ++kk) {
      w1h_r[ct][kk] = *(const h8v*)(W1h + (((long)(2 * w + ct) * 5 + kk) * 64 + l) * 8);
      w1l_r[ct][kk] = *(const h8v*)(W1l + (((long)(2 * w + ct) * 5 + kk) * 64 + l) * 8);
    }
#pragma unroll
    for (int kk = 0; kk < 8; ++kk)
      w2h_r[ct][kk] = *(const h8v*)(W2h + (((long)(2 * w + ct) * 8 + kk) * 64 + l) * 8);
  }
#pragma unroll
  for (int kk = 0; kk < 5; ++kk) {
    rwh_r[kk] = *(const h8v*)(rWh + (((long)w * 5 + kk) * 64 + l) * 8);
    rwl_r[kk] = *(const h8v*)(rWl + (((long)w * 5 + kk) * 64 + l) * 8);
  }
  // LDS: W3 pair (linear copy)
  for (int i = tid; i < 4096; i += 512) {
    ((h8v*)w3h_l)[i] = ((const h8v*)W3h)[i];
    ((h8v*)w3l_l)[i] = ((const h8v*)W3l)[i];
  }

  const float bbA = b1[(2 * w + 0) * 16 + c], bbB = b1[(2 * w + 1) * 16 + c];
  const float cbA = b2[(2 * w + 0) * 16 + c], cbB = b2[(2 * w + 1) * 16 + c];
  const float dB  = b3[w * 16 + c] + rb[w * 16 + c];

  // seed state f16 pair; zero k-pad cols 144..167
  for (int idx = tid; idx < 2048; idx += 512) {
    int r = idx >> 7, cc = idx & 127;
    float x = xstate[(long)(b0 + r) * 128 + cc];
    _Float16 hi = (_Float16)x;
    xu_h[r][cc] = __builtin_bit_cast(unsigned short, hi);
    xu_l[r][cc] = f2h((x - (float)hi) * 2048.f);
  }
  for (int idx = tid; idx < 16 * 24; idx += 512) {
    int r = idx / 24, cc = 144 + (idx % 24);
    xu_h[r][cc] = 0; xu_l[r][cc] = 0;
  }
  __syncthreads();

  for (int tc = 0; tc < len; ++tc) {
    const int t = t0 + tc;
    // rolling W2lo window: preload ct0
    h8v w2s[8];
#pragma unroll
    for (int kk = 0; kk < 8; ++kk)
      w2s[kk] = *(const h8v*)(W2l + (((long)(2 * w + 0) * 8 + kk) * 64 + l) * 8);
    // phase 0: u_t pair into cols 128..143; xf store (pair) from cols 0..127
    if (tid < 256) {
      int r = tid >> 4, cc = tid & 15;
      float uv = ufut[((long)(b0 + r) * 256 + t) * 16 + cc];
      _Float16 hi = (_Float16)uv;
      xu_h[r][128 + cc] = __builtin_bit_cast(unsigned short, hi);
      xu_l[r][128 + cc] = f2h((uv - (float)hi) * 2048.f);
    }
    {
      int r = tid >> 5, cc0 = (tid & 31) * 4;
      long row = ((long)(b0 + r) * len + tc) * 128 + cc0;
      unsigned long long ph =
            (unsigned long long)xu_h[r][cc0 + 0]
          | ((unsigned long long)xu_h[r][cc0 + 1] << 16)
          | ((unsigned long long)xu_h[r][cc0 + 2] << 32)
          | ((unsigned long long)xu_h[r][cc0 + 3] << 48);
      unsigned long long pl =
            (unsigned long long)xu_l[r][cc0 + 0]
          | ((unsigned long long)xu_l[r][cc0 + 1] << 16)
          | ((unsigned long long)xu_l[r][cc0 + 2] << 32)
          | ((unsigned long long)xu_l[r][cc0 + 3] << 48);
      *(unsigned long long*)(xfh + row) = ph;
      *(unsigned long long*)(xfl + row) = pl;
    }
    __syncthreads();
    // GEMM1: xu pair x W1 pair -> h1 pair
    float v1s[2][4];
#pragma unroll
    for (int ct = 0; ct < 2; ++ct) {
      f4v t1 = zero4(), tl = zero4();
#pragma unroll
      for (int kk = 0; kk < 5; ++kk) {
        h8v ah = *(const h8v*)(&xu_h[c][kk * 32 + g * 8]);
        h8v al = *(const h8v*)(&xu_l[c][kk * 32 + g * 8]);
        t1 = mfmaH(ah, w1h_r[ct][kk], t1);
        tl = mfmaH(al, w1h_r[ct][kk], tl);
        tl = mfmaH(ah, w1l_r[ct][kk], tl);
      }
      const float bb = ct ? bbB : bbA;
#pragma unroll
      for (int j = 0; j < 4; ++j) v1s[ct][j] = t1[j] + tl[j] * 0x1p-11f + bb;
    }
#pragma unroll
    for (int ct = 0; ct < 2; ++ct)
#pragma unroll
      for (int j = 0; j < 4; ++j) {
        float tv = tanhf_fast(v1s[ct][j]);
        _Float16 hi = (_Float16)tv;
        hh[g * 4 + j][(2 * w + ct) * 16 + c] = __builtin_bit_cast(unsigned short, hi);
        hl[g * 4 + j][(2 * w + ct) * 16 + c] = f2h((tv - (float)hi) * 2048.f);
      }
    __syncthreads();
    // GEMM2: h1 pair x W2 pair (hi regs, lo streamed) -> h2 pair
    float v2s[2][4];
#pragma unroll
    for (int ct = 0; ct < 2; ++ct) {
      f4v t1 = zero4(), tl = zero4();
#pragma unroll
      for (int kk = 0; kk < 8; ++kk) {
        h8v ah = *(const h8v*)(&hh[c][kk * 32 + g * 8]);
        h8v al = *(const h8v*)(&hl[c][kk * 32 + g * 8]);
        t1 = mfmaH(ah, w2h_r[ct][kk], t1);
        tl = mfmaH(al, w2h_r[ct][kk], tl);
        tl = mfmaH(ah, w2s[kk], tl);
        if (ct == 0)
          w2s[kk] = *(const h8v*)(W2l + (((long)(2 * w + 1) * 8 + kk) * 64 + l) * 8);
      }
      const float cb = ct ? cbB : cbA;
#pragma unroll
      for (int j = 0; j < 4; ++j) v2s[ct][j] = t1[j] + tl[j] * 0x1p-11f + cb;
    }
    __syncthreads();  // drain h1 reads before overwriting hh/hl with h2
#pragma unroll
    for (int ct = 0; ct < 2; ++ct)
#pragma unroll
      for (int j = 0; j < 4; ++j) {
        float tv = tanhf_fast(v2s[ct][j]);
        _Float16 hi = (_Float16)tv;
        hh[g * 4 + j][(2 * w + ct) * 16 + c] = __builtin_bit_cast(unsigned short, hi);
        hl[g * 4 + j][(2 * w + ct) * 16 + c] = f2h((tv - (float)hi) * 2048.f);
      }
    __syncthreads();
    // GEMM3: h2 pair x W3 pair (LDS) + xu pair x rW pair (regs)
    {
      f4v t1 = zero4(), tl = zero4();
#pragma unroll
      for (int kk = 0; kk < 8; ++kk) {
        h8v ah = *(const h8v*)(&hh[c][kk * 32 + g * 8]);
        h8v al = *(const h8v*)(&hl[c][kk * 32 + g * 8]);
        h8v bh = *(const h8v*)(&w3h_l[((w * 8 + kk) * 64 + l) * 8]);
        h8v bl = *(const h8v*)(&w3l_l[((w * 8 + kk) * 64 + l) * 8]);
        t1 = mfmaH(ah, bh, t1);
        tl = mfmaH(al, bh, tl);
        tl = mfmaH(ah, bl, tl);
      }
#pragma unroll
      for (int kk = 0; kk < 5; ++kk) {
        h8v ah = *(const h8v*)(&xu_h[c][kk * 32 + g * 8]);
        h8v al = *(const h8v*)(&xu_l[c][kk * 32 + g * 8]);
        t1 = mfmaH(ah, rwh_r[kk], t1);
        tl = mfmaH(al, rwh_r[kk], tl);
        tl = mfmaH(ah, rwl_r[kk], tl);
      }
      __syncthreads();  // drain xu/hh reads before state overwrite
#pragma unroll
      for (int j = 0; j < 4; ++j) {
        float xn = t1[j] + tl[j] * 0x1p-11f + dB;
        _Float16 hi = (_Float16)xn;
        xu_h[g * 4 + j][w * 16 + c] = __builtin_bit_cast(unsigned short, hi);
        xu_l[g * 4 + j][w * 16 + c] = f2h((xn - (float)hi) * 2048.f);
      }
    }
    __syncthreads();
  }
  // chunk-final state writeback (fp32 = hi + lo*2^-11, exact)
  for (int idx = tid; idx < 2048; idx += 512) {
    int r = idx >> 7, cc = idx & 127;
    xstate[(long)(b0 + r) * 128 + cc] = h2f(xu_h[r][cc]) + h2f(xu_l[r][cc]) * 0x1p-11f;
  }
}

// ---------------- output network h (weight-persistent, grid-stride) ----------
__global__ __launch_bounds__(512, 2)
void hnet_kernel(const unsigned short* __restrict__ xfh, const unsigned short* __restrict__ xfl,
                 const unsigned short* __restrict__ W1, const unsigned short* __restrict__ W2,
                 const unsigned short* __restrict__ W3, const unsigned short* __restrict__ rW,
                 const float* __restrict__ b1, const float* __restrict__ b2,
                 const float* __restrict__ b3, const float* __restrict__ rb,
                 float* __restrict__ out, int t0, int len) {
  __shared__ __align__(16) unsigned short h1[64][264];
  __shared__ __align__(16) unsigned short h2[64][264];
  __shared__ __align__(16) unsigned short w2odd[32768];   // hW2 odd coltiles (64KB)
  __shared__ float part[4][16][16];
  const int tid = threadIdx.x;
  const int w = tid >> 6, l = tid & 63;
  const int c = l & 15, g = l >> 4;

  // persistent weights: hW1 both coltiles (regs), hW2 even ct (regs), odd ct (LDS)
  h8v w1f[2][4], w2f0[8];
#pragma unroll
  for (int ct = 0; ct < 2; ++ct)
#pragma unroll
    for (int kk = 0; kk < 4; ++kk)
      w1f[ct][kk] = *(const h8v*)(W1 + (((long)(2 * w + ct) * 4 + kk) * 64 + l) * 8);
#pragma unroll
  for (int kk = 0; kk < 8; ++kk)
    w2f0[kk] = *(const h8v*)(W2 + (((long)(2 * w + 0) * 8 + kk) * 64 + l) * 8);
  for (int i = tid; i < 4096; i += 512) {
    int wq = i >> 9, rem = i & 511, kk = rem >> 6, ll = rem & 63;
    ((h8v*)w2odd)[i] = *(const h8v*)(W2 + (((long)(2 * wq + 1) * 8 + kk) * 64 + ll) * 8);
  }
  const float bbA1 = b1[(2 * w + 0) * 16 + c], bbB1 = b1[(2 * w + 1) * 16 + c];
  const float bbA2 = b2[(2 * w + 0) * 16 + c], bbB2 = b2[(2 * w + 1) * 16 + c];
  __syncthreads();

  const int ntiles = 64 * len;  // (4096*len rows) / 64
  for (int tile = blockIdx.x; tile < ntiles; tile += 256) {
    const long row0 = (long)tile * 64;
    {  // stage A: h1 = tanh(xf(pair) @ W1 + b1)
      for (int rt = 0; rt < 4; ++rt) {
        f4v t10 = zero4(), tl0 = zero4(), t11 = zero4(), tl1 = zero4();
#pragma unroll
        for (int kk = 0; kk < 4; ++kk) {
          h8v ah = *(const h8v*)(xfh + (row0 + rt * 16 + c) * 128 + kk * 32 + g * 8);
          h8v al = *(const h8v*)(xfl + (row0 + rt * 16 + c) * 128 + kk * 32 + g * 8);
          t10 = mfmaH(ah, w1f[0][kk], t10);
          tl0 = mfmaH(al, w1f[0][kk], tl0);
          t11 = mfmaH(ah, w1f[1][kk], t11);
          tl1 = mfmaH(al, w1f[1][kk], tl1);
        }
#pragma unroll
        for (int j = 0; j < 4; ++j) {
          h1[rt * 16 + g * 4 + j][(2 * w + 0) * 16 + c] =
              f2h(tanhf_fast(t10[j] + tl0[j] * 0x1p-11f + bbA1));
          h1[rt * 16 + g * 4 + j][(2 * w + 1) * 16 + c] =
              f2h(tanhf_fast(t11[j] + tl1[j] * 0x1p-11f + bbB1));
        }
      }
    }
    __syncthreads();
    {  // stage B: h2 = tanh(h1 @ W2 + b2), f16 single (even ct regs, odd ct LDS)
      for (int rt = 0; rt < 4; ++rt) {
        f4v a0 = zero4(), a1 = zero4();
#pragma unroll
        for (int kk = 0; kk < 8; ++kk) {
          h8v a = *(const h8v*)(&h1[rt * 16 + c][kk * 32 + g * 8]);
          h8v b1f = *(const h8v*)(&w2odd[(((long)w * 8 + kk) * 64 + l) * 8]);
          a0 = mfmaH(a, w2f0[kk], a0);
          a1 = mfmaH(a, b1f, a1);
        }
#pragma unroll
        for (int j = 0; j < 4; ++j) {
          h2[rt * 16 + g * 4 + j][(2 * w + 0) * 16 + c] = f2h(tanhf_fast(a0[j] + bbA2));
          h2[rt * 16 + g * 4 + j][(2 * w + 1) * 16 + c] = f2h(tanhf_fast(a1[j] + bbB2));
        }
      }
    }
    __syncthreads();
    {  // stage C: y = h2 @ W3 + xf(pair) @ rW + b3 + rb
      const int rt = w & 3, kh = w >> 2;
      f4v t1 = zero4(), tl = zero4();
#pragma unroll
      for (int kk = 0; kk < 4; ++kk) {
        const int kkg = kh * 4 + kk;
        h8v a = *(const h8v*)(&h2[rt * 16 + c][kkg * 32 + g * 8]);
        h8v b = *(const h8v*)(W3 + ((long)(kkg * 64 + l)) * 8);
        t1 = mfmaH(a, b, t1);
      }
#pragma unroll
      for (int kk = 0; kk < 2; ++kk) {
        const int kkg = kh * 2 + kk;
        h8v ah = *(const h8v*)(xfh + (row0 + rt * 16 + c) * 128 + kkg * 32 + g * 8);
        h8v al = *(const h8v*)(xfl + (row0 + rt * 16 + c) * 128 + kkg * 32 + g * 8);
        h8v b = *(const h8v*)(rW + ((long)(kkg * 64 + l)) * 8);
        t1 = mfmaH(ah, b, t1);
        tl = mfmaH(al, b, tl);
      }
      float val[4];
#pragma unroll
      for (int j = 0; j < 4; ++j) val[j] = t1[j] + tl[j] * 0x1p-11f;
      if (w >= 4) {
#pragma unroll
        for (int j = 0; j < 4; ++j) part[rt][g * 4 + j][c] = val[j];
      }
      __syncthreads();
      if (w < 4) {
        const float bias = b3[c] + rb[c];
#pragma unroll
        for (int j = 0; j < 4; ++j) {
          const long grow = row0 + rt * 16 + g * 4 + j;
          const long bq = grow / len;
          const int tq = (int)(grow - bq * len);
          out[(bq * 256 + (t0 + tq)) * 16 + c] = val[j] + part[rt][g * 4 + j][c] + bias;
        }
      }
    }
  }
}

// ---------------- host -------------------------------------------------------
extern "C" void kernel_launch(void* const* d_in, const int* in_sizes, int n_in,
                              void* d_out, int out_size, void* d_ws, size_t ws_size,
                              hipStream_t stream) {
  (void)in_sizes; (void)n_in; (void)out_size;
  const float* upast = (const float*)d_in[0];
  const float* ypast = (const float*)d_in[1];
  const float* ufut  = (const float*)d_in[2];
  const float* e_rW = (const float*)d_in[3];
  const float* e_rb = (const float*)d_in[4];
  const float* e_W1 = (const float*)d_in[5];
  const float* e_b1 = (const float*)d_in[6];
  const float* e_W2 = (const float*)d_in[7];
  const float* e_b2 = (const float*)d_in[8];
  const float* e_W3 = (const float*)d_in[9];
  const float* e_b3 = (const float*)d_in[10];
  const float* f_rW = (const float*)d_in[11];
  const float* f_rb = (const float*)d_in[12];
  const float* f_W1 = (const float*)d_in[13];
  const float* f_b1 = (const float*)d_in[14];
  const float* f_W2 = (const float*)d_in[15];
  const float* f_b2 = (const float*)d_in[16];
  const float* f_W3 = (const float*)d_in[17];
  const float* f_b3 = (const float*)d_in[18];
  const float* h_rW = (const float*)d_in[19];
  const float* h_rb = (const float*)d_in[20];
  const float* h_W1 = (const float*)d_in[21];
  const float* h_b1 = (const float*)d_in[22];
  const float* h_W2 = (const float*)d_in[23];
  const float* h_b2 = (const float*)d_in[24];
  const float* h_W3 = (const float*)d_in[25];
  const float* h_b3 = (const float*)d_in[26];
  float* out = (float*)d_out;

  // swizzle table: e_* bf16 pair (mode0), f_* f16 pair (mode3), h_* f16 (mode1)
  const float* srcs[12] = { e_W1, e_W2, e_W3, e_rW, f_W1, f_W2, f_W3, f_rW,
                            h_W1, h_W2, h_W3, h_rW };
  const int Ks [12] = {1024, 256, 256, 1024, 144, 256, 256, 144, 128, 256, 256, 128};
  const int Kps[12] = {1024, 256, 256, 1024, 160, 256, 256, 160, 128, 256, 256, 128};
  const int Ns [12] = { 256, 256, 128,  128, 256, 256, 128, 128, 256, 256,  16,  16};
  const int modes[12] = {0,0,0,0, 3,3,3,3, 1,1,1,1};

  SwzTable tbl;
  long woff = 0, offs[12];
  for (int i = 0; i < 12; ++i) { offs[i] = woff; woff += (long)Kps[i] * Ns[i]; }
  const long EA = offs[4];              // e-region elems
  const long FB = 2 * EA;
  const long EB = offs[8] - offs[4];    // f-region elems
  const long HB = FB + 2 * EB;
  for (int i = 0; i < 12; ++i) {
    tbl.d[i].src = srcs[i]; tbl.d[i].woff = offs[i];
    tbl.d[i].K = Ks[i]; tbl.d[i].Kp = Kps[i]; tbl.d[i].N = Ns[i]; tbl.d[i].mode = modes[i];
    if (modes[i] == 0)      { tbl.d[i].dhi = offs[i];              tbl.d[i].dlo = EA + offs[i]; }
    else if (modes[i] == 3) { long lo = offs[i] - offs[4];
                              tbl.d[i].dhi = FB + lo;              tbl.d[i].dlo = FB + EB + lo; }
    else                    { long lo = offs[i] - offs[8];
                              tbl.d[i].dhi = HB + lo;              tbl.d[i].dlo = 0; }
  }
  tbl.tot_work = woff;

  unsigned short* wswz = (unsigned short*)d_ws;
  const long WSHORTS = HB + (offs[11] - offs[8]) + (long)Kps[11] * Ns[11];
  const size_t XOFF = ((size_t)WSHORTS * 2 + 4095) & ~(size_t)4095;
  float* xstate = (float*)((char*)d_ws + XOFF);
  const size_t XF0 = XOFF + (2u << 20);
  int c = 64;
  {
    long cmax = ((long)ws_size - (long)XF0) >> 21;  // 2 MB per time-step (pair)
    if (cmax < c) c = (int)cmax;
    if (c < 1) c = 1;
  }
  unsigned short* xfh = (unsigned short*)((char*)d_ws + XF0);
  unsigned short* xfl = (unsigned short*)((char*)d_ws + XF0 + (size_t)c * 1048576);

  // kernel weight pointers
  const unsigned short* eW1h = wswz + offs[0];          const unsigned short* eW1l = wswz + EA + offs[0];
  const unsigned short* eW2h = wswz + offs[1];          const unsigned short* eW2l = wswz + EA + offs[1];
  const unsigned short* eW3h = wswz + offs[2];          const unsigned short* eW3l = wswz + EA + offs[2];
  const unsigned short* erWh = wswz + offs[3];          const unsigned short* erWl = wswz + EA + offs[3];
  const unsigned short* fW1h = wswz + FB + 0;           const unsigned short* fW1l = wswz + FB + EB + 0;
  const unsigned short* fW2h = wswz + FB + 40960;       const unsigned short* fW2l = wswz + FB + EB + 40960;
  const unsigned short* fW3h = wswz + FB + 106496;      const unsigned short* fW3l = wswz + FB + EB + 106496;
  const unsigned short* frWh = wswz + FB + 139264;      const unsigned short* frWl = wswz + FB + EB + 139264;
  const unsigned short* hW1 = wswz + HB + 0;
  const unsigned short* hW2 = wswz + HB + 32768;
  const unsigned short* hW3 = wswz + HB + 98304;
  const unsigned short* hrW = wswz + HB + 102400;

  swz_kernel<<<(int)((tbl.tot_work + 255) / 256), 256, 0, stream>>>(tbl, wswz);
  enc_kernel<<<256, 512, 0, stream>>>(upast, ypast,
                                      eW1h, eW1l, eW2h, eW2l, eW3h, eW3l, erWh, erWl,
                                      e_b1, e_b2, e_b3, e_rb, xstate);
  for (int t0 = 0; t0 < 256; t0 += c) {
    int len = 256 - t0; if (len > c) len = c;
    recur_kernel<<<256, 512, 0, stream>>>(ufut, fW1h, fW1l, fW2h, fW2l, fW3h, fW3l,
                                          frWh, frWl, f_b1, f_b2, f_b3, f_rb,
                                          xstate, xfh, xfl, t0, len);
    hnet_kernel<<<256, 512, 0, stream>>>(xfh, xfl, hW1, hW2, hW3, hrW,
                                         h_b1, h_b2, h_b3, h_rb, out, t0, len);
  }
}

// Round 11
// 2920.385 us; speedup vs baseline: 1.5811x; 1.0182x over previous
//
#include <hip/hip_runtime.h>
#include <stdint.h>

// SUBNET_15290083574166: encoder MLP -> 256-step recurrent f MLP -> output h MLP
// B=4096, T=256, NX=128, NU=16, NY=16, NB=NA=32, H=256
//
// Precision (VERIFIED r4-r10, absmax 0.0625 vs thr 0.24): f16 hi/lo pairs
// (2^-22) on all recurrence operands, 2-accum (hi + lo*2^-11); encoder bf16
// pairs; hnet xf-pair x f16-single. DO NOT change the numerics.
//
// r11 (numerics bit-identical):
//  - recur: ct-INTERLEAVED kk-loops in G1/G2 — each A-fragment ds_read_b128
//    once instead of once per coltile (A-reads 20->10 G1, 32->16 G2; ~33% of
//    the 624 wave-wide LDS reads/step/CU). ct1's W2lo stream issued right
//    after the G1 MFMA loop (hidden under tanh+writes+barrier). Accumulator
//    chains receive identical contribution order -> bit-identical.
//  - hnet: reverted to r4's 4096-block version (r10's weight-persistent
//    variant measured neutral-negative: xf reads dominate, not weights).
//  - everything else byte-identical to the proven r4/r10 structure.

typedef __attribute__((ext_vector_type(8))) short s8v;      // 8 bf16 bits
typedef __attribute__((ext_vector_type(8))) _Float16 h8v;   // 8 f16
typedef __attribute__((ext_vector_type(4))) float f4v;

__device__ __forceinline__ f4v mfma16(s8v a, s8v b, f4v c) {
  return __builtin_amdgcn_mfma_f32_16x16x32_bf16(a, b, c, 0, 0, 0);
}
__device__ __forceinline__ f4v mfmaH(h8v a, h8v b, f4v c) {
  return __builtin_amdgcn_mfma_f32_16x16x32_f16(a, b, c, 0, 0, 0);
}
__device__ __forceinline__ f4v zero4() { return (f4v){0.f, 0.f, 0.f, 0.f}; }

__device__ __forceinline__ unsigned short f2b(float x) {  // f32->bf16 RNE
  unsigned int u = __builtin_bit_cast(unsigned int, x);
  u += 0x7fffu + ((u >> 16) & 1u);
  return (unsigned short)(u >> 16);
}
__device__ __forceinline__ float b2f(unsigned short h) {
  return __builtin_bit_cast(float, (unsigned int)h << 16);
}
__device__ __forceinline__ unsigned short f2h(float x) {
  return __builtin_bit_cast(unsigned short, (_Float16)x);
}
__device__ __forceinline__ float h2f(unsigned short h) {
  return (float)__builtin_bit_cast(_Float16, h);
}

__device__ __forceinline__ float tanhf_fast(float x) {
  x = fminf(15.f, fmaxf(-15.f, x));
  float e = __expf(2.f * x);
  return (e - 1.f) / (e + 1.f);
}

// ---------------- weight swizzle: fp32 [K][N] -> fragment order ---------------
// frag: idx(nt,kk,lane,j) = ((nt*KK + kk)*64 + lane)*8 + j
//   holds W[kk*32 + (lane>>4)*8 + j][nt*16 + (lane&15)]  (zero-pad k>=K)
// mode 0: bf16 hi at dst[dhi+local], bf16 lo at dst[dlo+local]
// mode 3: f16 hi at dst[dhi+local], f16((v-hi)*2048) at dst[dlo+local]
// mode 1: f16 at dst[dhi+local]
struct SwzDesc { const float* src; long woff; long dhi; long dlo; int K; int Kp; int N; int mode; };
struct SwzTable { SwzDesc d[12]; long tot_work; };

__global__ void swz_kernel(SwzTable tbl, unsigned short* __restrict__ dst) {
  long gid = (long)blockIdx.x * 256 + threadIdx.x;
  if (gid >= tbl.tot_work) return;
  int i = 11;
  while (i > 0 && gid < tbl.d[i].woff) --i;
  const SwzDesc m = tbl.d[i];
  long local = gid - m.woff;
  int j = (int)(local & 7);
  int lane = (int)((local >> 3) & 63);
  long rem = local >> 9;
  int KK = m.Kp >> 5;
  int kk = (int)(rem % KK);
  int nt = (int)(rem / KK);
  int k = kk * 32 + (lane >> 4) * 8 + j;
  int n = nt * 16 + (lane & 15);
  float v = (k < m.K) ? m.src[(long)k * m.N + n] : 0.f;
  if (m.mode == 0) {
    unsigned short hi = f2b(v);
    dst[m.dhi + local] = hi;
    dst[m.dlo + local] = f2b(v - b2f(hi));
  } else if (m.mode == 3) {
    _Float16 hi = (_Float16)v;
    dst[m.dhi + local] = __builtin_bit_cast(unsigned short, hi);
    dst[m.dlo + local] = f2h((v - (float)hi) * 2048.f);
  } else {
    dst[m.dhi + local] = f2h(v);
  }
}

// ---------------- encoder (bf16 hi/lo 3-term, one-shot) ----------------------
__global__ __launch_bounds__(512, 2)
void enc_kernel(const float* __restrict__ upast, const float* __restrict__ ypast,
                const unsigned short* __restrict__ W1h, const unsigned short* __restrict__ W1l,
                const unsigned short* __restrict__ W2h, const unsigned short* __restrict__ W2l,
                const unsigned short* __restrict__ W3h, const unsigned short* __restrict__ W3l,
                const unsigned short* __restrict__ rWh, const unsigned short* __restrict__ rWl,
                const float* __restrict__ b1, const float* __restrict__ b2,
                const float* __restrict__ b3, const float* __restrict__ rb,
                float* __restrict__ xstate) {
  __shared__ __align__(16) unsigned short h1h[16][264], h1l[16][264];
  __shared__ __align__(16) unsigned short h2h[16][264], h2l[16][264];
  const int tid = threadIdx.x;
  const int w = tid >> 6, l = tid & 63;
  const int c = l & 15, g = l >> 4;
  const int b0 = blockIdx.x << 4;
  const long zrow = (long)(b0 + c) * 512;

  f4v a0 = zero4(), a1 = zero4();
  for (int kk = 0; kk < 32; ++kk) {
    const int cb = kk * 32 + g * 8;
    const float* zp = (cb < 512) ? (upast + zrow + cb) : (ypast + zrow + (cb - 512));
    float4 z0 = *(const float4*)zp;
    float4 z1 = *(const float4*)(zp + 4);
    float zz[8] = {z0.x, z0.y, z0.z, z0.w, z1.x, z1.y, z1.z, z1.w};
    s8v ah, al;
#pragma unroll
    for (int q = 0; q < 8; ++q) {
      unsigned short hi = f2b(zz[q]);
      ah[q] = (short)hi; al[q] = (short)f2b(zz[q] - b2f(hi));
    }
#pragma unroll
    for (int ct = 0; ct < 2; ++ct) {
      s8v bh = *(const s8v*)(W1h + (((long)(2 * w + ct) * 32 + kk) * 64 + l) * 8);
      s8v bl = *(const s8v*)(W1l + (((long)(2 * w + ct) * 32 + kk) * 64 + l) * 8);
      f4v& acc = ct ? a1 : a0;
      acc = mfma16(ah, bh, acc);
      acc = mfma16(al, bh, acc);
      acc = mfma16(ah, bl, acc);
    }
  }
  {
    const float bbA = b1[(2 * w + 0) * 16 + c], bbB = b1[(2 * w + 1) * 16 + c];
#pragma unroll
    for (int j = 0; j < 4; ++j) {
      float tA = tanhf_fast(a0[j] + bbA), tB = tanhf_fast(a1[j] + bbB);
      unsigned short hA = f2b(tA), hB = f2b(tB);
      h1h[g * 4 + j][(2 * w + 0) * 16 + c] = hA;
      h1l[g * 4 + j][(2 * w + 0) * 16 + c] = f2b(tA - b2f(hA));
      h1h[g * 4 + j][(2 * w + 1) * 16 + c] = hB;
      h1l[g * 4 + j][(2 * w + 1) * 16 + c] = f2b(tB - b2f(hB));
    }
  }
  __syncthreads();
  a0 = zero4(); a1 = zero4();
#pragma unroll
  for (int kk = 0; kk < 8; ++kk) {
    s8v ah = *(const s8v*)(&h1h[c][kk * 32 + g * 8]);
    s8v al = *(const s8v*)(&h1l[c][kk * 32 + g * 8]);
#pragma unroll
    for (int ct = 0; ct < 2; ++ct) {
      s8v bh = *(const s8v*)(W2h + (((long)(2 * w + ct) * 8 + kk) * 64 + l) * 8);
      s8v bl = *(const s8v*)(W2l + (((long)(2 * w + ct) * 8 + kk) * 64 + l) * 8);
      f4v& acc = ct ? a1 : a0;
      acc = mfma16(ah, bh, acc);
      acc = mfma16(al, bh, acc);
      acc = mfma16(ah, bl, acc);
    }
  }
  {
    const float bbA = b2[(2 * w + 0) * 16 + c], bbB = b2[(2 * w + 1) * 16 + c];
#pragma unroll
    for (int j = 0; j < 4; ++j) {
      float tA = tanhf_fast(a0[j] + bbA), tB = tanhf_fast(a1[j] + bbB);
      unsigned short hA = f2b(tA), hB = f2b(tB);
      h2h[g * 4 + j][(2 * w + 0) * 16 + c] = hA;
      h2l[g * 4 + j][(2 * w + 0) * 16 + c] = f2b(tA - b2f(hA));
      h2h[g * 4 + j][(2 * w + 1) * 16 + c] = hB;
      h2l[g * 4 + j][(2 * w + 1) * 16 + c] = f2b(tB - b2f(hB));
    }
  }
  __syncthreads();
  f4v ac = zero4();
#pragma unroll
  for (int kk = 0; kk < 8; ++kk) {
    s8v ah = *(const s8v*)(&h2h[c][kk * 32 + g * 8]);
    s8v al = *(const s8v*)(&h2l[c][kk * 32 + g * 8]);
    s8v bh = *(const s8v*)(W3h + (((long)w * 8 + kk) * 64 + l) * 8);
    s8v bl = *(const s8v*)(W3l + (((long)w * 8 + kk) * 64 + l) * 8);
    ac = mfma16(ah, bh, ac);
    ac = mfma16(al, bh, ac);
    ac = mfma16(ah, bl, ac);
  }
  for (int kk = 0; kk < 32; ++kk) {
    const int cb = kk * 32 + g * 8;
    const float* zp = (cb < 512) ? (upast + zrow + cb) : (ypast + zrow + (cb - 512));
    float4 z0 = *(const float4*)zp;
    float4 z1 = *(const float4*)(zp + 4);
    float zz[8] = {z0.x, z0.y, z0.z, z0.w, z1.x, z1.y, z1.z, z1.w};
    s8v ah, al;
#pragma unroll
    for (int q = 0; q < 8; ++q) {
      unsigned short hi = f2b(zz[q]);
      ah[q] = (short)hi; al[q] = (short)f2b(zz[q] - b2f(hi));
    }
    s8v bh = *(const s8v*)(rWh + (((long)w * 32 + kk) * 64 + l) * 8);
    s8v bl = *(const s8v*)(rWl + (((long)w * 32 + kk) * 64 + l) * 8);
    ac = mfma16(ah, bh, ac);
    ac = mfma16(al, bh, ac);
    ac = mfma16(ah, bl, ac);
  }
  {
    const float bias = b3[w * 16 + c] + rb[w * 16 + c];
#pragma unroll
    for (int j = 0; j < 4; ++j)
      xstate[(long)(b0 + g * 4 + j) * 128 + w * 16 + c] = ac[j] + bias;
  }
}

// ---------------- recurrence (f16 pairs, ct-interleaved kk loops) ------------
// regs persistent (184): W1 pair 80, W2hi 64, rW pair 40. LDS: W3 pair 128KB +
// activations ~27KB. W2lo streamed from L2 (ct0 preloaded, ct1 issued in G1 tail).
__global__ __launch_bounds__(512, 2)
void recur_kernel(const float* __restrict__ ufut,
                  const unsigned short* __restrict__ W1h, const unsigned short* __restrict__ W1l,
                  const unsigned short* __restrict__ W2h, const unsigned short* __restrict__ W2l,
                  const unsigned short* __restrict__ W3h, const unsigned short* __restrict__ W3l,
                  const unsigned short* __restrict__ rWh, const unsigned short* __restrict__ rWl,
                  const float* __restrict__ b1, const float* __restrict__ b2,
                  const float* __restrict__ b3, const float* __restrict__ rb,
                  float* __restrict__ xstate,
                  unsigned short* __restrict__ xfh, unsigned short* __restrict__ xfl,
                  int t0, int len) {
  __shared__ __align__(16) unsigned short xu_h[16][168], xu_l[16][168];
  __shared__ __align__(16) unsigned short hh[16][264], hl[16][264];
  __shared__ __align__(16) unsigned short w3h_l[32768];   // W3 hi, full
  __shared__ __align__(16) unsigned short w3l_l[32768];   // W3 lo, full
  const int tid = threadIdx.x;
  const int w = tid >> 6, l = tid & 63;
  const int c = l & 15, g = l >> 4;
  const int b0 = blockIdx.x << 4;

  // persistent register fragments (f16)
  h8v w1h_r[2][5], w1l_r[2][5], w2h_r[2][8], rwh_r[5], rwl_r[5];
#pragma unroll
  for (int ct = 0; ct < 2; ++ct) {
#pragma unroll
    for (int kk = 0; kk < 5; ++kk) {
      w1h_r[ct][kk] = *(const h8v*)(W1h + (((long)(2 * w + ct) * 5 + kk) * 64 + l) * 8);
      w1l_r[ct][kk] = *(const h8v*)(W1l + (((long)(2 * w + ct) * 5 + kk) * 64 + l) * 8);
    }
#pragma unroll
    for (int kk = 0; kk < 8; ++kk)
      w2h_r[ct][kk] = *(const h8v*)(W2h + (((long)(2 * w + ct) * 8 + kk) * 64 + l) * 8);
  }
#pragma unroll
  for (int kk = 0; kk < 5; ++kk) {
    rwh_r[kk] = *(const h8v*)(rWh + (((long)w * 5 + kk) * 64 + l) * 8);
    rwl_r[kk] = *(const h8v*)(rWl + (((long)w * 5 + kk) * 64 + l) * 8);
  }
  // LDS: W3 pair (linear copy)
  for (int i = tid; i < 4096; i += 512) {
    ((h8v*)w3h_l)[i] = ((const h8v*)W3h)[i];
    ((h8v*)w3l_l)[i] = ((const h8v*)W3l)[i];
  }

  const float bbA = b1[(2 * w + 0) * 16 + c], bbB = b1[(2 * w + 1) * 16 + c];
  const float cbA = b2[(2 * w + 0) * 16 + c], cbB = b2[(2 * w + 1) * 16 + c];
  const float dB  = b3[w * 16 + c] + rb[w * 16 + c];

  // seed state f16 pair; zero k-pad cols 144..167
  for (int idx = tid; idx < 2048; idx += 512) {
    int r = idx >> 7, cc = idx & 127;
    float x = xstate[(long)(b0 + r) * 128 + cc];
    _Float16 hi = (_Float16)x;
    xu_h[r][cc] = __builtin_bit_cast(unsigned short, hi);
    xu_l[r][cc] = f2h((x - (float)hi) * 2048.f);
  }
  for (int idx = tid; idx < 16 * 24; idx += 512) {
    int r = idx / 24, cc = 144 + (idx % 24);
    xu_h[r][cc] = 0; xu_l[r][cc] = 0;
  }
  __syncthreads();

  for (int tc = 0; tc < len; ++tc) {
    const int t = t0 + tc;
    // rolling W2lo: preload ct0
    h8v w2s[8];
#pragma unroll
    for (int kk = 0; kk < 8; ++kk)
      w2s[kk] = *(const h8v*)(W2l + (((long)(2 * w + 0) * 8 + kk) * 64 + l) * 8);
    // phase 0: u_t pair into cols 128..143; xf store (pair) from cols 0..127
    if (tid < 256) {
      int r = tid >> 4, cc = tid & 15;
      float uv = ufut[((long)(b0 + r) * 256 + t) * 16 + cc];
      _Float16 hi = (_Float16)uv;
      xu_h[r][128 + cc] = __builtin_bit_cast(unsigned short, hi);
      xu_l[r][128 + cc] = f2h((uv - (float)hi) * 2048.f);
    }
    {
      int r = tid >> 5, cc0 = (tid & 31) * 4;
      long row = ((long)(b0 + r) * len + tc) * 128 + cc0;
      unsigned long long ph =
            (unsigned long long)xu_h[r][cc0 + 0]
          | ((unsigned long long)xu_h[r][cc0 + 1] << 16)
          | ((unsigned long long)xu_h[r][cc0 + 2] << 32)
          | ((unsigned long long)xu_h[r][cc0 + 3] << 48);
      unsigned long long pl =
            (unsigned long long)xu_l[r][cc0 + 0]
          | ((unsigned long long)xu_l[r][cc0 + 1] << 16)
          | ((unsigned long long)xu_l[r][cc0 + 2] << 32)
          | ((unsigned long long)xu_l[r][cc0 + 3] << 48);
      *(unsigned long long*)(xfh + row) = ph;
      *(unsigned long long*)(xfl + row) = pl;
    }
    __syncthreads();
    // GEMM1: xu pair x W1 pair -> h1 pair (ct-interleaved, A-frags read ONCE)
    float v1s[2][4];
    {
      f4v t10 = zero4(), tl0 = zero4(), t11 = zero4(), tl1 = zero4();
#pragma unroll
      for (int kk = 0; kk < 5; ++kk) {
        h8v ah = *(const h8v*)(&xu_h[c][kk * 32 + g * 8]);
        h8v al = *(const h8v*)(&xu_l[c][kk * 32 + g * 8]);
        t10 = mfmaH(ah, w1h_r[0][kk], t10);
        tl0 = mfmaH(al, w1h_r[0][kk], tl0);
        tl0 = mfmaH(ah, w1l_r[0][kk], tl0);
        t11 = mfmaH(ah, w1h_r[1][kk], t11);
        tl1 = mfmaH(al, w1h_r[1][kk], tl1);
        tl1 = mfmaH(ah, w1l_r[1][kk], tl1);
      }
#pragma unroll
      for (int j = 0; j < 4; ++j) {
        v1s[0][j] = t10[j] + tl0[j] * 0x1p-11f + bbA;
        v1s[1][j] = t11[j] + tl1[j] * 0x1p-11f + bbB;
      }
    }
    // issue ct1's W2lo stream now (hidden under tanh + writes + barrier)
    h8v w2s1[8];
#pragma unroll
    for (int kk = 0; kk < 8; ++kk)
      w2s1[kk] = *(const h8v*)(W2l + (((long)(2 * w + 1) * 8 + kk) * 64 + l) * 8);
#pragma unroll
    for (int ct = 0; ct < 2; ++ct)
#pragma unroll
      for (int j = 0; j < 4; ++j) {
        float tv = tanhf_fast(v1s[ct][j]);
        _Float16 hi = (_Float16)tv;
        hh[g * 4 + j][(2 * w + ct) * 16 + c] = __builtin_bit_cast(unsigned short, hi);
        hl[g * 4 + j][(2 * w + ct) * 16 + c] = f2h((tv - (float)hi) * 2048.f);
      }
    __syncthreads();
    // GEMM2: h1 pair x W2 pair (ct-interleaved, A-frags read ONCE)
    float v2s[2][4];
    {
      f4v t10 = zero4(), tl0 = zero4(), t11 = zero4(), tl1 = zero4();
#pragma unroll
      for (int kk = 0; kk < 8; ++kk) {
        h8v ah = *(const h8v*)(&hh[c][kk * 32 + g * 8]);
        h8v al = *(const h8v*)(&hl[c][kk * 32 + g * 8]);
        t10 = mfmaH(ah, w2h_r[0][kk], t10);
        tl0 = mfmaH(al, w2h_r[0][kk], tl0);
        tl0 = mfmaH(ah, w2s[kk], tl0);
        t11 = mfmaH(ah, w2h_r[1][kk], t11);
        tl1 = mfmaH(al, w2h_r[1][kk], tl1);
        tl1 = mfmaH(ah, w2s1[kk], tl1);
      }
#pragma unroll
      for (int j = 0; j < 4; ++j) {
        v2s[0][j] = t10[j] + tl0[j] * 0x1p-11f + cbA;
        v2s[1][j] = t11[j] + tl1[j] * 0x1p-11f + cbB;
      }
    }
    __syncthreads();  // drain h1 reads before overwriting hh/hl with h2
#pragma unroll
    for (int ct = 0; ct < 2; ++ct)
#pragma unroll
      for (int j = 0; j < 4; ++j) {
        float tv = tanhf_fast(v2s[ct][j]);
        _Float16 hi = (_Float16)tv;
        hh[g * 4 + j][(2 * w + ct) * 16 + c] = __builtin_bit_cast(unsigned short, hi);
        hl[g * 4 + j][(2 * w + ct) * 16 + c] = f2h((tv - (float)hi) * 2048.f);
      }
    __syncthreads();
    // GEMM3: h2 pair x W3 pair (LDS) + xu pair x rW pair (regs)
    {
      f4v t1 = zero4(), tl = zero4();
#pragma unroll
      for (int kk = 0; kk < 8; ++kk) {
        h8v ah = *(const h8v*)(&hh[c][kk * 32 + g * 8]);
        h8v al = *(const h8v*)(&hl[c][kk * 32 + g * 8]);
        h8v bh = *(const h8v*)(&w3h_l[((w * 8 + kk) * 64 + l) * 8]);
        h8v bl = *(const h8v*)(&w3l_l[((w * 8 + kk) * 64 + l) * 8]);
        t1 = mfmaH(ah, bh, t1);
        tl = mfmaH(al, bh, tl);
        tl = mfmaH(ah, bl, tl);
      }
#pragma unroll
      for (int kk = 0; kk < 5; ++kk) {
        h8v ah = *(const h8v*)(&xu_h[c][kk * 32 + g * 8]);
        h8v al = *(const h8v*)(&xu_l[c][kk * 32 + g * 8]);
        t1 = mfmaH(ah, rwh_r[kk], t1);
        tl = mfmaH(al, rwh_r[kk], tl);
        tl = mfmaH(ah, rwl_r[kk], tl);
      }
      __syncthreads();  // drain xu/hh reads before state overwrite
#pragma unroll
      for (int j = 0; j < 4; ++j) {
        float xn = t1[j] + tl[j] * 0x1p-11f + dB;
        _Float16 hi = (_Float16)xn;
        xu_h[g * 4 + j][w * 16 + c] = __builtin_bit_cast(unsigned short, hi);
        xu_l[g * 4 + j][w * 16 + c] = f2h((xn - (float)hi) * 2048.f);
      }
    }
    __syncthreads();
  }
  // chunk-final state writeback (fp32 = hi + lo*2^-11, exact)
  for (int idx = tid; idx < 2048; idx += 512) {
    int r = idx >> 7, cc = idx & 127;
    xstate[(long)(b0 + r) * 128 + cc] = h2f(xu_h[r][cc]) + h2f(xu_l[r][cc]) * 0x1p-11f;
  }
}

// ---------------- output network h (xf pair x f16-single weights, r4 ver) ----
__global__ __launch_bounds__(512, 2)
void hnet_kernel(const unsigned short* __restrict__ xfh, const unsigned short* __restrict__ xfl,
                 const unsigned short* __restrict__ W1, const unsigned short* __restrict__ W2,
                 const unsigned short* __restrict__ W3, const unsigned short* __restrict__ rW,
                 const float* __restrict__ b1, const float* __restrict__ b2,
                 const float* __restrict__ b3, const float* __restrict__ rb,
                 float* __restrict__ out, int t0, int len) {
  __shared__ __align__(16) unsigned short h1[64][264];
  __shared__ __align__(16) unsigned short h2[64][264];
  __shared__ float part[4][16][16];
  const int tid = threadIdx.x;
  const int w = tid >> 6, l = tid & 63;
  const int c = l & 15, g = l >> 4;
  const long row0 = (long)blockIdx.x * 64;

  {  // stage A: h1 = tanh(xf(pair) @ W1 + b1)
    h8v w1f[2][4];
#pragma unroll
    for (int ct = 0; ct < 2; ++ct)
#pragma unroll
      for (int kk = 0; kk < 4; ++kk)
        w1f[ct][kk] = *(const h8v*)(W1 + (((long)(2 * w + ct) * 4 + kk) * 64 + l) * 8);
    const float bbA = b1[(2 * w + 0) * 16 + c], bbB = b1[(2 * w + 1) * 16 + c];
    for (int rt = 0; rt < 4; ++rt) {
      f4v t10 = zero4(), tl0 = zero4(), t11 = zero4(), tl1 = zero4();
#pragma unroll
      for (int kk = 0; kk < 4; ++kk) {
        h8v ah = *(const h8v*)(xfh + (row0 + rt * 16 + c) * 128 + kk * 32 + g * 8);
        h8v al = *(const h8v*)(xfl + (row0 + rt * 16 + c) * 128 + kk * 32 + g * 8);
        t10 = mfmaH(ah, w1f[0][kk], t10);
        tl0 = mfmaH(al, w1f[0][kk], tl0);
        t11 = mfmaH(ah, w1f[1][kk], t11);
        tl1 = mfmaH(al, w1f[1][kk], tl1);
      }
#pragma unroll
      for (int j = 0; j < 4; ++j) {
        h1[rt * 16 + g * 4 + j][(2 * w + 0) * 16 + c] =
            f2h(tanhf_fast(t10[j] + tl0[j] * 0x1p-11f + bbA));
        h1[rt * 16 + g * 4 + j][(2 * w + 1) * 16 + c] =
            f2h(tanhf_fast(t11[j] + tl1[j] * 0x1p-11f + bbB));
      }
    }
  }
  __syncthreads();
  {  // stage B: h2 = tanh(h1 @ W2 + b2), f16 single
    h8v w2f[2][8];
#pragma unroll
    for (int ct = 0; ct < 2; ++ct)
#pragma unroll
      for (int kk = 0; kk < 8; ++kk)
        w2f[ct][kk] = *(const h8v*)(W2 + (((long)(2 * w + ct) * 8 + kk) * 64 + l) * 8);
    const float bbA = b2[(2 * w + 0) * 16 + c], bbB = b2[(2 * w + 1) * 16 + c];
    for (int rt = 0; rt < 4; ++rt) {
      f4v a0 = zero4(), a1 = zero4();
#pragma unroll
      for (int kk = 0; kk < 8; ++kk) {
        h8v a = *(const h8v*)(&h1[rt * 16 + c][kk * 32 + g * 8]);
        a0 = mfmaH(a, w2f[0][kk], a0);
        a1 = mfmaH(a, w2f[1][kk], a1);
      }
#pragma unroll
      for (int j = 0; j < 4; ++j) {
        h2[rt * 16 + g * 4 + j][(2 * w + 0) * 16 + c] = f2h(tanhf_fast(a0[j] + bbA));
        h2[rt * 16 + g * 4 + j][(2 * w + 1) * 16 + c] = f2h(tanhf_fast(a1[j] + bbB));
      }
    }
  }
  __syncthreads();
  {  // stage C: y = h2 @ W3 + xf(pair) @ rW + b3 + rb
    const int rt = w & 3, kh = w >> 2;
    f4v t1 = zero4(), tl = zero4();
#pragma unroll
    for (int kk = 0; kk < 4; ++kk) {
      const int kkg = kh * 4 + kk;
      h8v a = *(const h8v*)(&h2[rt * 16 + c][kkg * 32 + g * 8]);
      h8v b = *(const h8v*)(W3 + ((long)(kkg * 64 + l)) * 8);
      t1 = mfmaH(a, b, t1);
    }
#pragma unroll
    for (int kk = 0; kk < 2; ++kk) {
      const int kkg = kh * 2 + kk;
      h8v ah = *(const h8v*)(xfh + (row0 + rt * 16 + c) * 128 + kkg * 32 + g * 8);
      h8v al = *(const h8v*)(xfl + (row0 + rt * 16 + c) * 128 + kkg * 32 + g * 8);
      h8v b = *(const h8v*)(rW + ((long)(kkg * 64 + l)) * 8);
      t1 = mfmaH(ah, b, t1);
      tl = mfmaH(al, b, tl);
    }
    float val[4];
#pragma unroll
    for (int j = 0; j < 4; ++j) val[j] = t1[j] + tl[j] * 0x1p-11f;
    if (w >= 4) {
#pragma unroll
      for (int j = 0; j < 4; ++j) part[rt][g * 4 + j][c] = val[j];
    }
    __syncthreads();
    if (w < 4) {
      const float bias = b3[c] + rb[c];
#pragma unroll
      for (int j = 0; j < 4; ++j) {
        const long grow = row0 + rt * 16 + g * 4 + j;
        const long bq = grow / len;
        const int tq = (int)(grow - bq * len);
        out[(bq * 256 + (t0 + tq)) * 16 + c] = val[j] + part[rt][g * 4 + j][c] + bias;
      }
    }
  }
}

// ---------------- host -------------------------------------------------------
extern "C" void kernel_launch(void* const* d_in, const int* in_sizes, int n_in,
                              void* d_out, int out_size, void* d_ws, size_t ws_size,
                              hipStream_t stream) {
  (void)in_sizes; (void)n_in; (void)out_size;
  const float* upast = (const float*)d_in[0];
  const float* ypast = (const float*)d_in[1];
  const float* ufut  = (const float*)d_in[2];
  const float* e_rW = (const float*)d_in[3];
  const float* e_rb = (const float*)d_in[4];
  const float* e_W1 = (const float*)d_in[5];
  const float* e_b1 = (const float*)d_in[6];
  const float* e_W2 = (const float*)d_in[7];
  const float* e_b2 = (const float*)d_in[8];
  const float* e_W3 = (const float*)d_in[9];
  const float* e_b3 = (const float*)d_in[10];
  const float* f_rW = (const float*)d_in[11];
  const float* f_rb = (const float*)d_in[12];
  const float* f_W1 = (const float*)d_in[13];
  const float* f_b1 = (const float*)d_in[14];
  const float* f_W2 = (const float*)d_in[15];
  const float* f_b2 = (const float*)d_in[16];
  const float* f_W3 = (const float*)d_in[17];
  const float* f_b3 = (const float*)d_in[18];
  const float* h_rW = (const float*)d_in[19];
  const float* h_rb = (const float*)d_in[20];
  const float* h_W1 = (const float*)d_in[21];
  const float* h_b1 = (const float*)d_in[22];
  const float* h_W2 = (const float*)d_in[23];
  const float* h_b2 = (const float*)d_in[24];
  const float* h_W3 = (const float*)d_in[25];
  const float* h_b3 = (const float*)d_in[26];
  float* out = (float*)d_out;

  // swizzle table: e_* bf16 pair (mode0), f_* f16 pair (mode3), h_* f16 (mode1)
  const float* srcs[12] = { e_W1, e_W2, e_W3, e_rW, f_W1, f_W2, f_W3, f_rW,
                            h_W1, h_W2, h_W3, h_rW };
  const int Ks [12] = {1024, 256, 256, 1024, 144, 256, 256, 144, 128, 256, 256, 128};
  const int Kps[12] = {1024, 256, 256, 1024, 160, 256, 256, 160, 128, 256, 256, 128};
  const int Ns [12] = { 256, 256, 128,  128, 256, 256, 128, 128, 256, 256,  16,  16};
  const int modes[12] = {0,0,0,0, 3,3,3,3, 1,1,1,1};

  SwzTable tbl;
  long woff = 0, offs[12];
  for (int i = 0; i < 12; ++i) { offs[i] = woff; woff += (long)Kps[i] * Ns[i]; }
  const long EA = offs[4];              // e-region elems
  const long FB = 2 * EA;
  const long EB = offs[8] - offs[4];    // f-region elems
  const long HB = FB + 2 * EB;
  for (int i = 0; i < 12; ++i) {
    tbl.d[i].src = srcs[i]; tbl.d[i].woff = offs[i];
    tbl.d[i].K = Ks[i]; tbl.d[i].Kp = Kps[i]; tbl.d[i].N = Ns[i]; tbl.d[i].mode = modes[i];
    if (modes[i] == 0)      { tbl.d[i].dhi = offs[i];              tbl.d[i].dlo = EA + offs[i]; }
    else if (modes[i] == 3) { long lo = offs[i] - offs[4];
                              tbl.d[i].dhi = FB + lo;              tbl.d[i].dlo = FB + EB + lo; }
    else                    { long lo = offs[i] - offs[8];
                              tbl.d[i].dhi = HB + lo;              tbl.d[i].dlo = 0; }
  }
  tbl.tot_work = woff;

  unsigned short* wswz = (unsigned short*)d_ws;
  const long WSHORTS = HB + (offs[11] - offs[8]) + (long)Kps[11] * Ns[11];
  const size_t XOFF = ((size_t)WSHORTS * 2 + 4095) & ~(size_t)4095;
  float* xstate = (float*)((char*)d_ws + XOFF);
  const size_t XF0 = XOFF + (2u << 20);
  int c = 64;
  {
    long cmax = ((long)ws_size - (long)XF0) >> 21;  // 2 MB per time-step (pair)
    if (cmax < c) c = (int)cmax;
    if (c < 1) c = 1;
  }
  unsigned short* xfh = (unsigned short*)((char*)d_ws + XF0);
  unsigned short* xfl = (unsigned short*)((char*)d_ws + XF0 + (size_t)c * 1048576);

  // kernel weight pointers
  const unsigned short* eW1h = wswz + offs[0];          const unsigned short* eW1l = wswz + EA + offs[0];
  const unsigned short* eW2h = wswz + offs[1];          const unsigned short* eW2l = wswz + EA + offs[1];
  const unsigned short* eW3h = wswz + offs[2];          const unsigned short* eW3l = wswz + EA + offs[2];
  const unsigned short* erWh = wswz + offs[3];          const unsigned short* erWl = wswz + EA + offs[3];
  const unsigned short* fW1h = wswz + FB + 0;           const unsigned short* fW1l = wswz + FB + EB + 0;
  const unsigned short* fW2h = wswz + FB + 40960;       const unsigned short* fW2l = wswz + FB + EB + 40960;
  const unsigned short* fW3h = wswz + FB + 106496;      const unsigned short* fW3l = wswz + FB + EB + 106496;
  const unsigned short* frWh = wswz + FB + 139264;      const unsigned short* frWl = wswz + FB + EB + 139264;
  const unsigned short* hW1 = wswz + HB + 0;
  const unsigned short* hW2 = wswz + HB + 32768;
  const unsigned short* hW3 = wswz + HB + 98304;
  const unsigned short* hrW = wswz + HB + 102400;

  swz_kernel<<<(int)((tbl.tot_work + 255) / 256), 256, 0, stream>>>(tbl, wswz);
  enc_kernel<<<256, 512, 0, stream>>>(upast, ypast,
                                      eW1h, eW1l, eW2h, eW2l, eW3h, eW3l, erWh, erWl,
                                      e_b1, e_b2, e_b3, e_rb, xstate);
  for (int t0 = 0; t0 < 256; t0 += c) {
    int len = 256 - t0; if (len > c) len = c;
    recur_kernel<<<256, 512, 0, stream>>>(ufut, fW1h, fW1l, fW2h, fW2l, fW3h, fW3l,
                                          frWh, frWl, f_b1, f_b2, f_b3, f_rb,
                                          xstate, xfh, xfl, t0, len);
    hnet_kernel<<<64 * len, 512, 0, stream>>>(xfh, xfl, hW1, hW2, hW3, hrW,
                                              h_b1, h_b2, h_b3, h_rb, out, t0, len);
  }
}

// Round 12
// 2912.272 us; speedup vs baseline: 1.5855x; 1.0028x over previous
//
#include <hip/hip_runtime.h>
#include <stdint.h>

// SUBNET_15290083574166: encoder MLP -> 256-step recurrent f MLP -> output h MLP
// B=4096, T=256, NX=128, NU=16, NY=16, NB=NA=32, H=256
//
// Precision (VERIFIED r4-r11, absmax 0.0625 vs thr 0.24): f16 hi/lo pairs
// (2^-22) on all recurrence operands, 2-accum (hi + lo*2^-11); encoder bf16
// pairs; hnet xf-pair x f16-single. DO NOT change the numerics.
//
// r12 (bit-identical, register-placement-neutral micro-pass):
//  - recur phase0: xf pack via 2 aligned b64 LDS reads instead of 8 scalar
//    ds_read_u16 + shifts (row stride 336B, col offset 8B-aligned; same bytes)
//  - hnet: #pragma unroll on the rt loops (stages A/B) so the scheduler can
//    overlap rt+1's xf/LDS loads with rt's MFMA+tanh
//  - everything else byte-identical to r11 (recur 577-582us, 6 restructure
//    attempts r5-r9 all demoted by the allocator; this is the stable basin)

typedef __attribute__((ext_vector_type(8))) short s8v;      // 8 bf16 bits
typedef __attribute__((ext_vector_type(8))) _Float16 h8v;   // 8 f16
typedef __attribute__((ext_vector_type(4))) float f4v;

__device__ __forceinline__ f4v mfma16(s8v a, s8v b, f4v c) {
  return __builtin_amdgcn_mfma_f32_16x16x32_bf16(a, b, c, 0, 0, 0);
}
__device__ __forceinline__ f4v mfmaH(h8v a, h8v b, f4v c) {
  return __builtin_amdgcn_mfma_f32_16x16x32_f16(a, b, c, 0, 0, 0);
}
__device__ __forceinline__ f4v zero4() { return (f4v){0.f, 0.f, 0.f, 0.f}; }

__device__ __forceinline__ unsigned short f2b(float x) {  // f32->bf16 RNE
  unsigned int u = __builtin_bit_cast(unsigned int, x);
  u += 0x7fffu + ((u >> 16) & 1u);
  return (unsigned short)(u >> 16);
}
__device__ __forceinline__ float b2f(unsigned short h) {
  return __builtin_bit_cast(float, (unsigned int)h << 16);
}
__device__ __forceinline__ unsigned short f2h(float x) {
  return __builtin_bit_cast(unsigned short, (_Float16)x);
}
__device__ __forceinline__ float h2f(unsigned short h) {
  return (float)__builtin_bit_cast(_Float16, h);
}

__device__ __forceinline__ float tanhf_fast(float x) {
  x = fminf(15.f, fmaxf(-15.f, x));
  float e = __expf(2.f * x);
  return (e - 1.f) / (e + 1.f);
}

// ---------------- weight swizzle: fp32 [K][N] -> fragment order ---------------
// frag: idx(nt,kk,lane,j) = ((nt*KK + kk)*64 + lane)*8 + j
//   holds W[kk*32 + (lane>>4)*8 + j][nt*16 + (lane&15)]  (zero-pad k>=K)
// mode 0: bf16 hi at dst[dhi+local], bf16 lo at dst[dlo+local]
// mode 3: f16 hi at dst[dhi+local], f16((v-hi)*2048) at dst[dlo+local]
// mode 1: f16 at dst[dhi+local]
struct SwzDesc { const float* src; long woff; long dhi; long dlo; int K; int Kp; int N; int mode; };
struct SwzTable { SwzDesc d[12]; long tot_work; };

__global__ void swz_kernel(SwzTable tbl, unsigned short* __restrict__ dst) {
  long gid = (long)blockIdx.x * 256 + threadIdx.x;
  if (gid >= tbl.tot_work) return;
  int i = 11;
  while (i > 0 && gid < tbl.d[i].woff) --i;
  const SwzDesc m = tbl.d[i];
  long local = gid - m.woff;
  int j = (int)(local & 7);
  int lane = (int)((local >> 3) & 63);
  long rem = local >> 9;
  int KK = m.Kp >> 5;
  int kk = (int)(rem % KK);
  int nt = (int)(rem / KK);
  int k = kk * 32 + (lane >> 4) * 8 + j;
  int n = nt * 16 + (lane & 15);
  float v = (k < m.K) ? m.src[(long)k * m.N + n] : 0.f;
  if (m.mode == 0) {
    unsigned short hi = f2b(v);
    dst[m.dhi + local] = hi;
    dst[m.dlo + local] = f2b(v - b2f(hi));
  } else if (m.mode == 3) {
    _Float16 hi = (_Float16)v;
    dst[m.dhi + local] = __builtin_bit_cast(unsigned short, hi);
    dst[m.dlo + local] = f2h((v - (float)hi) * 2048.f);
  } else {
    dst[m.dhi + local] = f2h(v);
  }
}

// ---------------- encoder (bf16 hi/lo 3-term, one-shot) ----------------------
__global__ __launch_bounds__(512, 2)
void enc_kernel(const float* __restrict__ upast, const float* __restrict__ ypast,
                const unsigned short* __restrict__ W1h, const unsigned short* __restrict__ W1l,
                const unsigned short* __restrict__ W2h, const unsigned short* __restrict__ W2l,
                const unsigned short* __restrict__ W3h, const unsigned short* __restrict__ W3l,
                const unsigned short* __restrict__ rWh, const unsigned short* __restrict__ rWl,
                const float* __restrict__ b1, const float* __restrict__ b2,
                const float* __restrict__ b3, const float* __restrict__ rb,
                float* __restrict__ xstate) {
  __shared__ __align__(16) unsigned short h1h[16][264], h1l[16][264];
  __shared__ __align__(16) unsigned short h2h[16][264], h2l[16][264];
  const int tid = threadIdx.x;
  const int w = tid >> 6, l = tid & 63;
  const int c = l & 15, g = l >> 4;
  const int b0 = blockIdx.x << 4;
  const long zrow = (long)(b0 + c) * 512;

  f4v a0 = zero4(), a1 = zero4();
  for (int kk = 0; kk < 32; ++kk) {
    const int cb = kk * 32 + g * 8;
    const float* zp = (cb < 512) ? (upast + zrow + cb) : (ypast + zrow + (cb - 512));
    float4 z0 = *(const float4*)zp;
    float4 z1 = *(const float4*)(zp + 4);
    float zz[8] = {z0.x, z0.y, z0.z, z0.w, z1.x, z1.y, z1.z, z1.w};
    s8v ah, al;
#pragma unroll
    for (int q = 0; q < 8; ++q) {
      unsigned short hi = f2b(zz[q]);
      ah[q] = (short)hi; al[q] = (short)f2b(zz[q] - b2f(hi));
    }
#pragma unroll
    for (int ct = 0; ct < 2; ++ct) {
      s8v bh = *(const s8v*)(W1h + (((long)(2 * w + ct) * 32 + kk) * 64 + l) * 8);
      s8v bl = *(const s8v*)(W1l + (((long)(2 * w + ct) * 32 + kk) * 64 + l) * 8);
      f4v& acc = ct ? a1 : a0;
      acc = mfma16(ah, bh, acc);
      acc = mfma16(al, bh, acc);
      acc = mfma16(ah, bl, acc);
    }
  }
  {
    const float bbA = b1[(2 * w + 0) * 16 + c], bbB = b1[(2 * w + 1) * 16 + c];
#pragma unroll
    for (int j = 0; j < 4; ++j) {
      float tA = tanhf_fast(a0[j] + bbA), tB = tanhf_fast(a1[j] + bbB);
      unsigned short hA = f2b(tA), hB = f2b(tB);
      h1h[g * 4 + j][(2 * w + 0) * 16 + c] = hA;
      h1l[g * 4 + j][(2 * w + 0) * 16 + c] = f2b(tA - b2f(hA));
      h1h[g * 4 + j][(2 * w + 1) * 16 + c] = hB;
      h1l[g * 4 + j][(2 * w + 1) * 16 + c] = f2b(tB - b2f(hB));
    }
  }
  __syncthreads();
  a0 = zero4(); a1 = zero4();
#pragma unroll
  for (int kk = 0; kk < 8; ++kk) {
    s8v ah = *(const s8v*)(&h1h[c][kk * 32 + g * 8]);
    s8v al = *(const s8v*)(&h1l[c][kk * 32 + g * 8]);
#pragma unroll
    for (int ct = 0; ct < 2; ++ct) {
      s8v bh = *(const s8v*)(W2h + (((long)(2 * w + ct) * 8 + kk) * 64 + l) * 8);
      s8v bl = *(const s8v*)(W2l + (((long)(2 * w + ct) * 8 + kk) * 64 + l) * 8);
      f4v& acc = ct ? a1 : a0;
      acc = mfma16(ah, bh, acc);
      acc = mfma16(al, bh, acc);
      acc = mfma16(ah, bl, acc);
    }
  }
  {
    const float bbA = b2[(2 * w + 0) * 16 + c], bbB = b2[(2 * w + 1) * 16 + c];
#pragma unroll
    for (int j = 0; j < 4; ++j) {
      float tA = tanhf_fast(a0[j] + bbA), tB = tanhf_fast(a1[j] + bbB);
      unsigned short hA = f2b(tA), hB = f2b(tB);
      h2h[g * 4 + j][(2 * w + 0) * 16 + c] = hA;
      h2l[g * 4 + j][(2 * w + 0) * 16 + c] = f2b(tA - b2f(hA));
      h2h[g * 4 + j][(2 * w + 1) * 16 + c] = hB;
      h2l[g * 4 + j][(2 * w + 1) * 16 + c] = f2b(tB - b2f(hB));
    }
  }
  __syncthreads();
  f4v ac = zero4();
#pragma unroll
  for (int kk = 0; kk < 8; ++kk) {
    s8v ah = *(const s8v*)(&h2h[c][kk * 32 + g * 8]);
    s8v al = *(const s8v*)(&h2l[c][kk * 32 + g * 8]);
    s8v bh = *(const s8v*)(W3h + (((long)w * 8 + kk) * 64 + l) * 8);
    s8v bl = *(const s8v*)(W3l + (((long)w * 8 + kk) * 64 + l) * 8);
    ac = mfma16(ah, bh, ac);
    ac = mfma16(al, bh, ac);
    ac = mfma16(ah, bl, ac);
  }
  for (int kk = 0; kk < 32; ++kk) {
    const int cb = kk * 32 + g * 8;
    const float* zp = (cb < 512) ? (upast + zrow + cb) : (ypast + zrow + (cb - 512));
    float4 z0 = *(const float4*)zp;
    float4 z1 = *(const float4*)(zp + 4);
    float zz[8] = {z0.x, z0.y, z0.z, z0.w, z1.x, z1.y, z1.z, z1.w};
    s8v ah, al;
#pragma unroll
    for (int q = 0; q < 8; ++q) {
      unsigned short hi = f2b(zz[q]);
      ah[q] = (short)hi; al[q] = (short)f2b(zz[q] - b2f(hi));
    }
    s8v bh = *(const s8v*)(rWh + (((long)w * 32 + kk) * 64 + l) * 8);
    s8v bl = *(const s8v*)(rWl + (((long)w * 32 + kk) * 64 + l) * 8);
    ac = mfma16(ah, bh, ac);
    ac = mfma16(al, bh, ac);
    ac = mfma16(ah, bl, ac);
  }
  {
    const float bias = b3[w * 16 + c] + rb[w * 16 + c];
#pragma unroll
    for (int j = 0; j < 4; ++j)
      xstate[(long)(b0 + g * 4 + j) * 128 + w * 16 + c] = ac[j] + bias;
  }
}

// ---------------- recurrence (f16 pairs, r4-stable placement) ----------------
// regs persistent (184): W1 pair 80, W2hi 64, rW pair 40. LDS: W3 pair 128KB +
// activations ~27KB. W2lo streamed from L2 (ct0 preload, ct1 in G1 tail).
__global__ __launch_bounds__(512, 2)
void recur_kernel(const float* __restrict__ ufut,
                  const unsigned short* __restrict__ W1h, const unsigned short* __restrict__ W1l,
                  const unsigned short* __restrict__ W2h, const unsigned short* __restrict__ W2l,
                  const unsigned short* __restrict__ W3h, const unsigned short* __restrict__ W3l,
                  const unsigned short* __restrict__ rWh, const unsigned short* __restrict__ rWl,
                  const float* __restrict__ b1, const float* __restrict__ b2,
                  const float* __restrict__ b3, const float* __restrict__ rb,
                  float* __restrict__ xstate,
                  unsigned short* __restrict__ xfh, unsigned short* __restrict__ xfl,
                  int t0, int len) {
  __shared__ __align__(16) unsigned short xu_h[16][168], xu_l[16][168];
  __shared__ __align__(16) unsigned short hh[16][264], hl[16][264];
  __shared__ __align__(16) unsigned short w3h_l[32768];   // W3 hi, full
  __shared__ __align__(16) unsigned short w3l_l[32768];   // W3 lo, full
  const int tid = threadIdx.x;
  const int w = tid >> 6, l = tid & 63;
  const int c = l & 15, g = l >> 4;
  const int b0 = blockIdx.x << 4;

  // persistent register fragments (f16)
  h8v w1h_r[2][5], w1l_r[2][5], w2h_r[2][8], rwh_r[5], rwl_r[5];
#pragma unroll
  for (int ct = 0; ct < 2; ++ct) {
#pragma unroll
    for (int kk = 0; kk < 5; ++kk) {
      w1h_r[ct][kk] = *(const h8v*)(W1h + (((long)(2 * w + ct) * 5 + kk) * 64 + l) * 8);
      w1l_r[ct][kk] = *(const h8v*)(W1l + (((long)(2 * w + ct) * 5 + kk) * 64 + l) * 8);
    }
#pragma unroll
    for (int kk = 0; kk < 8; ++kk)
      w2h_r[ct][kk] = *(const h8v*)(W2h + (((long)(2 * w + ct) * 8 + kk) * 64 + l) * 8);
  }
#pragma unroll
  for (int kk = 0; kk < 5; ++kk) {
    rwh_r[kk] = *(const h8v*)(rWh + (((long)w * 5 + kk) * 64 + l) * 8);
    rwl_r[kk] = *(const h8v*)(rWl + (((long)w * 5 + kk) * 64 + l) * 8);
  }
  // LDS: W3 pair (linear copy)
  for (int i = tid; i < 4096; i += 512) {
    ((h8v*)w3h_l)[i] = ((const h8v*)W3h)[i];
    ((h8v*)w3l_l)[i] = ((const h8v*)W3l)[i];
  }

  const float bbA = b1[(2 * w + 0) * 16 + c], bbB = b1[(2 * w + 1) * 16 + c];
  const float cbA = b2[(2 * w + 0) * 16 + c], cbB = b2[(2 * w + 1) * 16 + c];
  const float dB  = b3[w * 16 + c] + rb[w * 16 + c];

  // seed state f16 pair; zero k-pad cols 144..167
  for (int idx = tid; idx < 2048; idx += 512) {
    int r = idx >> 7, cc = idx & 127;
    float x = xstate[(long)(b0 + r) * 128 + cc];
    _Float16 hi = (_Float16)x;
    xu_h[r][cc] = __builtin_bit_cast(unsigned short, hi);
    xu_l[r][cc] = f2h((x - (float)hi) * 2048.f);
  }
  for (int idx = tid; idx < 16 * 24; idx += 512) {
    int r = idx / 24, cc = 144 + (idx % 24);
    xu_h[r][cc] = 0; xu_l[r][cc] = 0;
  }
  __syncthreads();

  for (int tc = 0; tc < len; ++tc) {
    const int t = t0 + tc;
    // rolling W2lo: preload ct0
    h8v w2s[8];
#pragma unroll
    for (int kk = 0; kk < 8; ++kk)
      w2s[kk] = *(const h8v*)(W2l + (((long)(2 * w + 0) * 8 + kk) * 64 + l) * 8);
    // phase 0: u_t pair into cols 128..143; xf store (pair) from cols 0..127
    if (tid < 256) {
      int r = tid >> 4, cc = tid & 15;
      float uv = ufut[((long)(b0 + r) * 256 + t) * 16 + cc];
      _Float16 hi = (_Float16)uv;
      xu_h[r][128 + cc] = __builtin_bit_cast(unsigned short, hi);
      xu_l[r][128 + cc] = f2h((uv - (float)hi) * 2048.f);
    }
    {
      int r = tid >> 5, cc0 = (tid & 31) * 4;
      long row = ((long)(b0 + r) * len + tc) * 128 + cc0;
      // b64 LDS reads (cols 0..127 only; disjoint from u-writes to 128..143;
      // row stride 336B and cc0*2B are 8B-aligned) — same bytes as before
      unsigned long long ph = *(const unsigned long long*)(&xu_h[r][cc0]);
      unsigned long long pl = *(const unsigned long long*)(&xu_l[r][cc0]);
      *(unsigned long long*)(xfh + row) = ph;
      *(unsigned long long*)(xfl + row) = pl;
    }
    __syncthreads();
    // GEMM1: xu pair x W1 pair -> h1 pair
    float v1s[2][4];
    {
      f4v t10 = zero4(), tl0 = zero4(), t11 = zero4(), tl1 = zero4();
#pragma unroll
      for (int kk = 0; kk < 5; ++kk) {
        h8v ah = *(const h8v*)(&xu_h[c][kk * 32 + g * 8]);
        h8v al = *(const h8v*)(&xu_l[c][kk * 32 + g * 8]);
        t10 = mfmaH(ah, w1h_r[0][kk], t10);
        tl0 = mfmaH(al, w1h_r[0][kk], tl0);
        tl0 = mfmaH(ah, w1l_r[0][kk], tl0);
        t11 = mfmaH(ah, w1h_r[1][kk], t11);
        tl1 = mfmaH(al, w1h_r[1][kk], tl1);
        tl1 = mfmaH(ah, w1l_r[1][kk], tl1);
      }
#pragma unroll
      for (int j = 0; j < 4; ++j) {
        v1s[0][j] = t10[j] + tl0[j] * 0x1p-11f + bbA;
        v1s[1][j] = t11[j] + tl1[j] * 0x1p-11f + bbB;
      }
    }
    // issue ct1's W2lo stream now (hidden under tanh + writes + barrier)
    h8v w2s1[8];
#pragma unroll
    for (int kk = 0; kk < 8; ++kk)
      w2s1[kk] = *(const h8v*)(W2l + (((long)(2 * w + 1) * 8 + kk) * 64 + l) * 8);
#pragma unroll
    for (int ct = 0; ct < 2; ++ct)
#pragma unroll
      for (int j = 0; j < 4; ++j) {
        float tv = tanhf_fast(v1s[ct][j]);
        _Float16 hi = (_Float16)tv;
        hh[g * 4 + j][(2 * w + ct) * 16 + c] = __builtin_bit_cast(unsigned short, hi);
        hl[g * 4 + j][(2 * w + ct) * 16 + c] = f2h((tv - (float)hi) * 2048.f);
      }
    __syncthreads();
    // GEMM2: h1 pair x W2 pair (ct-interleaved, A-frags read once)
    float v2s[2][4];
    {
      f4v t10 = zero4(), tl0 = zero4(), t11 = zero4(), tl1 = zero4();
#pragma unroll
      for (int kk = 0; kk < 8; ++kk) {
        h8v ah = *(const h8v*)(&hh[c][kk * 32 + g * 8]);
        h8v al = *(const h8v*)(&hl[c][kk * 32 + g * 8]);
        t10 = mfmaH(ah, w2h_r[0][kk], t10);
        tl0 = mfmaH(al, w2h_r[0][kk], tl0);
        tl0 = mfmaH(ah, w2s[kk], tl0);
        t11 = mfmaH(ah, w2h_r[1][kk], t11);
        tl1 = mfmaH(al, w2h_r[1][kk], tl1);
        tl1 = mfmaH(ah, w2s1[kk], tl1);
      }
#pragma unroll
      for (int j = 0; j < 4; ++j) {
        v2s[0][j] = t10[j] + tl0[j] * 0x1p-11f + cbA;
        v2s[1][j] = t11[j] + tl1[j] * 0x1p-11f + cbB;
      }
    }
    __syncthreads();  // drain h1 reads before overwriting hh/hl with h2
#pragma unroll
    for (int ct = 0; ct < 2; ++ct)
#pragma unroll
      for (int j = 0; j < 4; ++j) {
        float tv = tanhf_fast(v2s[ct][j]);
        _Float16 hi = (_Float16)tv;
        hh[g * 4 + j][(2 * w + ct) * 16 + c] = __builtin_bit_cast(unsigned short, hi);
        hl[g * 4 + j][(2 * w + ct) * 16 + c] = f2h((tv - (float)hi) * 2048.f);
      }
    __syncthreads();
    // GEMM3: h2 pair x W3 pair (LDS) + xu pair x rW pair (regs)
    {
      f4v t1 = zero4(), tl = zero4();
#pragma unroll
      for (int kk = 0; kk < 8; ++kk) {
        h8v ah = *(const h8v*)(&hh[c][kk * 32 + g * 8]);
        h8v al = *(const h8v*)(&hl[c][kk * 32 + g * 8]);
        h8v bh = *(const h8v*)(&w3h_l[((w * 8 + kk) * 64 + l) * 8]);
        h8v bl = *(const h8v*)(&w3l_l[((w * 8 + kk) * 64 + l) * 8]);
        t1 = mfmaH(ah, bh, t1);
        tl = mfmaH(al, bh, tl);
        tl = mfmaH(ah, bl, tl);
      }
#pragma unroll
      for (int kk = 0; kk < 5; ++kk) {
        h8v ah = *(const h8v*)(&xu_h[c][kk * 32 + g * 8]);
        h8v al = *(const h8v*)(&xu_l[c][kk * 32 + g * 8]);
        t1 = mfmaH(ah, rwh_r[kk], t1);
        tl = mfmaH(al, rwh_r[kk], tl);
        tl = mfmaH(ah, rwl_r[kk], tl);
      }
      __syncthreads();  // drain xu/hh reads before state overwrite
#pragma unroll
      for (int j = 0; j < 4; ++j) {
        float xn = t1[j] + tl[j] * 0x1p-11f + dB;
        _Float16 hi = (_Float16)xn;
        xu_h[g * 4 + j][w * 16 + c] = __builtin_bit_cast(unsigned short, hi);
        xu_l[g * 4 + j][w * 16 + c] = f2h((xn - (float)hi) * 2048.f);
      }
    }
    __syncthreads();
  }
  // chunk-final state writeback (fp32 = hi + lo*2^-11, exact)
  for (int idx = tid; idx < 2048; idx += 512) {
    int r = idx >> 7, cc = idx & 127;
    xstate[(long)(b0 + r) * 128 + cc] = h2f(xu_h[r][cc]) + h2f(xu_l[r][cc]) * 0x1p-11f;
  }
}

// ---------------- output network h (xf pair x f16-single weights) ------------
__global__ __launch_bounds__(512, 2)
void hnet_kernel(const unsigned short* __restrict__ xfh, const unsigned short* __restrict__ xfl,
                 const unsigned short* __restrict__ W1, const unsigned short* __restrict__ W2,
                 const unsigned short* __restrict__ W3, const unsigned short* __restrict__ rW,
                 const float* __restrict__ b1, const float* __restrict__ b2,
                 const float* __restrict__ b3, const float* __restrict__ rb,
                 float* __restrict__ out, int t0, int len) {
  __shared__ __align__(16) unsigned short h1[64][264];
  __shared__ __align__(16) unsigned short h2[64][264];
  __shared__ float part[4][16][16];
  const int tid = threadIdx.x;
  const int w = tid >> 6, l = tid & 63;
  const int c = l & 15, g = l >> 4;
  const long row0 = (long)blockIdx.x * 64;

  {  // stage A: h1 = tanh(xf(pair) @ W1 + b1)
    h8v w1f[2][4];
#pragma unroll
    for (int ct = 0; ct < 2; ++ct)
#pragma unroll
      for (int kk = 0; kk < 4; ++kk)
        w1f[ct][kk] = *(const h8v*)(W1 + (((long)(2 * w + ct) * 4 + kk) * 64 + l) * 8);
    const float bbA = b1[(2 * w + 0) * 16 + c], bbB = b1[(2 * w + 1) * 16 + c];
#pragma unroll
    for (int rt = 0; rt < 4; ++rt) {
      f4v t10 = zero4(), tl0 = zero4(), t11 = zero4(), tl1 = zero4();
#pragma unroll
      for (int kk = 0; kk < 4; ++kk) {
        h8v ah = *(const h8v*)(xfh + (row0 + rt * 16 + c) * 128 + kk * 32 + g * 8);
        h8v al = *(const h8v*)(xfl + (row0 + rt * 16 + c) * 128 + kk * 32 + g * 8);
        t10 = mfmaH(ah, w1f[0][kk], t10);
        tl0 = mfmaH(al, w1f[0][kk], tl0);
        t11 = mfmaH(ah, w1f[1][kk], t11);
        tl1 = mfmaH(al, w1f[1][kk], tl1);
      }
#pragma unroll
      for (int j = 0; j < 4; ++j) {
        h1[rt * 16 + g * 4 + j][(2 * w + 0) * 16 + c] =
            f2h(tanhf_fast(t10[j] + tl0[j] * 0x1p-11f + bbA));
        h1[rt * 16 + g * 4 + j][(2 * w + 1) * 16 + c] =
            f2h(tanhf_fast(t11[j] + tl1[j] * 0x1p-11f + bbB));
      }
    }
  }
  __syncthreads();
  {  // stage B: h2 = tanh(h1 @ W2 + b2), f16 single
    h8v w2f[2][8];
#pragma unroll
    for (int ct = 0; ct < 2; ++ct)
#pragma unroll
      for (int kk = 0; kk < 8; ++kk)
        w2f[ct][kk] = *(const h8v*)(W2 + (((long)(2 * w + ct) * 8 + kk) * 64 + l) * 8);
    const float bbA = b2[(2 * w + 0) * 16 + c], bbB = b2[(2 * w + 1) * 16 + c];
#pragma unroll
    for (int rt = 0; rt < 4; ++rt) {
      f4v a0 = zero4(), a1 = zero4();
#pragma unroll
      for (int kk = 0; kk < 8; ++kk) {
        h8v a = *(const h8v*)(&h1[rt * 16 + c][kk * 32 + g * 8]);
        a0 = mfmaH(a, w2f[0][kk], a0);
        a1 = mfmaH(a, w2f[1][kk], a1);
      }
#pragma unroll
      for (int j = 0; j < 4; ++j) {
        h2[rt * 16 + g * 4 + j][(2 * w + 0) * 16 + c] = f2h(tanhf_fast(a0[j] + bbA));
        h2[rt * 16 + g * 4 + j][(2 * w + 1) * 16 + c] = f2h(tanhf_fast(a1[j] + bbB));
      }
    }
  }
  __syncthreads();
  {  // stage C: y = h2 @ W3 + xf(pair) @ rW + b3 + rb
    const int rt = w & 3, kh = w >> 2;
    f4v t1 = zero4(), tl = zero4();
#pragma unroll
    for (int kk = 0; kk < 4; ++kk) {
      const int kkg = kh * 4 + kk;
      h8v a = *(const h8v*)(&h2[rt * 16 + c][kkg * 32 + g * 8]);
      h8v b = *(const h8v*)(W3 + ((long)(kkg * 64 + l)) * 8);
      t1 = mfmaH(a, b, t1);
    }
#pragma unroll
    for (int kk = 0; kk < 2; ++kk) {
      const int kkg = kh * 2 + kk;
      h8v ah = *(const h8v*)(xfh + (row0 + rt * 16 + c) * 128 + kkg * 32 + g * 8);
      h8v al = *(const h8v*)(xfl + (row0 + rt * 16 + c) * 128 + kkg * 32 + g * 8);
      h8v b = *(const h8v*)(rW + ((long)(kkg * 64 + l)) * 8);
      t1 = mfmaH(ah, b, t1);
      tl = mfmaH(al, b, tl);
    }
    float val[4];
#pragma unroll
    for (int j = 0; j < 4; ++j) val[j] = t1[j] + tl[j] * 0x1p-11f;
    if (w >= 4) {
#pragma unroll
      for (int j = 0; j < 4; ++j) part[rt][g * 4 + j][c] = val[j];
    }
    __syncthreads();
    if (w < 4) {
      const float bias = b3[c] + rb[c];
#pragma unroll
      for (int j = 0; j < 4; ++j) {
        const long grow = row0 + rt * 16 + g * 4 + j;
        const long bq = grow / len;
        const int tq = (int)(grow - bq * len);
        out[(bq * 256 + (t0 + tq)) * 16 + c] = val[j] + part[rt][g * 4 + j][c] + bias;
      }
    }
  }
}

// ---------------- host -------------------------------------------------------
extern "C" void kernel_launch(void* const* d_in, const int* in_sizes, int n_in,
                              void* d_out, int out_size, void* d_ws, size_t ws_size,
                              hipStream_t stream) {
  (void)in_sizes; (void)n_in; (void)out_size;
  const float* upast = (const float*)d_in[0];
  const float* ypast = (const float*)d_in[1];
  const float* ufut  = (const float*)d_in[2];
  const float* e_rW = (const float*)d_in[3];
  const float* e_rb = (const float*)d_in[4];
  const float* e_W1 = (const float*)d_in[5];
  const float* e_b1 = (const float*)d_in[6];
  const float* e_W2 = (const float*)d_in[7];
  const float* e_b2 = (const float*)d_in[8];
  const float* e_W3 = (const float*)d_in[9];
  const float* e_b3 = (const float*)d_in[10];
  const float* f_rW = (const float*)d_in[11];
  const float* f_rb = (const float*)d_in[12];
  const float* f_W1 = (const float*)d_in[13];
  const float* f_b1 = (const float*)d_in[14];
  const float* f_W2 = (const float*)d_in[15];
  const float* f_b2 = (const float*)d_in[16];
  const float* f_W3 = (const float*)d_in[17];
  const float* f_b3 = (const float*)d_in[18];
  const float* h_rW = (const float*)d_in[19];
  const float* h_rb = (const float*)d_in[20];
  const float* h_W1 = (const float*)d_in[21];
  const float* h_b1 = (const float*)d_in[22];
  const float* h_W2 = (const float*)d_in[23];
  const float* h_b2 = (const float*)d_in[24];
  const float* h_W3 = (const float*)d_in[25];
  const float* h_b3 = (const float*)d_in[26];
  float* out = (float*)d_out;

  // swizzle table: e_* bf16 pair (mode0), f_* f16 pair (mode3), h_* f16 (mode1)
  const float* srcs[12] = { e_W1, e_W2, e_W3, e_rW, f_W1, f_W2, f_W3, f_rW,
                            h_W1, h_W2, h_W3, h_rW };
  const int Ks [12] = {1024, 256, 256, 1024, 144, 256, 256, 144, 128, 256, 256, 128};
  const int Kps[12] = {1024, 256, 256, 1024, 160, 256, 256, 160, 128, 256, 256, 128};
  const int Ns [12] = { 256, 256, 128,  128, 256, 256, 128, 128, 256, 256,  16,  16};
  const int modes[12] = {0,0,0,0, 3,3,3,3, 1,1,1,1};

  SwzTable tbl;
  long woff = 0, offs[12];
  for (int i = 0; i < 12; ++i) { offs[i] = woff; woff += (long)Kps[i] * Ns[i]; }
  const long EA = offs[4];              // e-region elems
  const long FB = 2 * EA;
  const long EB = offs[8] - offs[4];    // f-region elems
  const long HB = FB + 2 * EB;
  for (int i = 0; i < 12; ++i) {
    tbl.d[i].src = srcs[i]; tbl.d[i].woff = offs[i];
    tbl.d[i].K = Ks[i]; tbl.d[i].Kp = Kps[i]; tbl.d[i].N = Ns[i]; tbl.d[i].mode = modes[i];
    if (modes[i] == 0)      { tbl.d[i].dhi = offs[i];              tbl.d[i].dlo = EA + offs[i]; }
    else if (modes[i] == 3) { long lo = offs[i] - offs[4];
                              tbl.d[i].dhi = FB + lo;              tbl.d[i].dlo = FB + EB + lo; }
    else                    { long lo = offs[i] - offs[8];
                              tbl.d[i].dhi = HB + lo;              tbl.d[i].dlo = 0; }
  }
  tbl.tot_work = woff;

  unsigned short* wswz = (unsigned short*)d_ws;
  const long WSHORTS = HB + (offs[11] - offs[8]) + (long)Kps[11] * Ns[11];
  const size_t XOFF = ((size_t)WSHORTS * 2 + 4095) & ~(size_t)4095;
  float* xstate = (float*)((char*)d_ws + XOFF);
  const size_t XF0 = XOFF + (2u << 20);
  int c = 64;
  {
    long cmax = ((long)ws_size - (long)XF0) >> 21;  // 2 MB per time-step (pair)
    if (cmax < c) c = (int)cmax;
    if (c < 1) c = 1;
  }
  unsigned short* xfh = (unsigned short*)((char*)d_ws + XF0);
  unsigned short* xfl = (unsigned short*)((char*)d_ws + XF0 + (size_t)c * 1048576);

  // kernel weight pointers
  const unsigned short* eW1h = wswz + offs[0];          const unsigned short* eW1l = wswz + EA + offs[0];
  const unsigned short* eW2h = wswz + offs[1];          const unsigned short* eW2l = wswz + EA + offs[1];
  const unsigned short* eW3h = wswz + offs[2];          const unsigned short* eW3l = wswz + EA + offs[2];
  const unsigned short* erWh = wswz + offs[3];          const unsigned short* erWl = wswz + EA + offs[3];
  const unsigned short* fW1h = wswz + FB + 0;           const unsigned short* fW1l = wswz + FB + EB + 0;
  const unsigned short* fW2h = wswz + FB + 40960;       const unsigned short* fW2l = wswz + FB + EB + 40960;
  const unsigned short* fW3h = wswz + FB + 106496;      const unsigned short* fW3l = wswz + FB + EB + 106496;
  const unsigned short* frWh = wswz + FB + 139264;      const unsigned short* frWl = wswz + FB + EB + 139264;
  const unsigned short* hW1 = wswz + HB + 0;
  const unsigned short* hW2 = wswz + HB + 32768;
  const unsigned short* hW3 = wswz + HB + 98304;
  const unsigned short* hrW = wswz + HB + 102400;

  swz_kernel<<<(int)((tbl.tot_work + 255) / 256), 256, 0, stream>>>(tbl, wswz);
  enc_kernel<<<256, 512, 0, stream>>>(upast, ypast,
                                      eW1h, eW1l, eW2h, eW2l, eW3h, eW3l, erWh, erWl,
                                      e_b1, e_b2, e_b3, e_rb, xstate);
  for (int t0 = 0; t0 < 256; t0 += c) {
    int len = 256 - t0; if (len > c) len = c;
    recur_kernel<<<256, 512, 0, stream>>>(ufut, fW1h, fW1l, fW2h, fW2l, fW3h, fW3l,
                                          frWh, frWl, f_b1, f_b2, f_b3, f_rb,
                                          xstate, xfh, xfl, t0, len);
    hnet_kernel<<<64 * len, 512, 0, stream>>>(xfh, xfl, hW1, hW2, hW3, hrW,
                                              h_b1, h_b2, h_b3, h_rb, out, t0, len);
  }
}

// Round 13
// 2860.308 us; speedup vs baseline: 1.6143x; 1.0182x over previous
//
#include <hip/hip_runtime.h>
#include <stdint.h>

// SUBNET_15290083574166: encoder MLP -> 256-step recurrent f MLP -> output h MLP
// B=4096, T=256, NX=128, NU=16, NY=16, NB=NA=32, H=256
//
// Precision (VERIFIED r4-r12, absmax 0.0625 vs thr 0.24): f16 hi/lo pairs
// (2^-22) on all recurrence operands, 2-accum (hi + lo*2^-11); encoder bf16
// pairs; hnet xf-pair x f16-single. DO NOT change the numerics.
//
// r13 (bit-identical; targets the two exposed global-latency segments in
// recur's phase0, which the pre-barrier vmcnt(0) drains serially):
//  - u(t+1) prefetched into regs right after barrier-1 (consumed next step);
//    phase0 keeps only convert+LDS-write (fast VALU+DS)
//  - xf store moved after barrier-1: issues concurrently with G1 MFMA, its
//    vmcnt drain lands on barrier-2 where compute hides it (xu stable till G3)
//  - everything else byte-identical to r12 (recur 575-578us stable basin;
//    r5-r9 proved placement changes get demoted at this shape)

typedef __attribute__((ext_vector_type(8))) short s8v;      // 8 bf16 bits
typedef __attribute__((ext_vector_type(8))) _Float16 h8v;   // 8 f16
typedef __attribute__((ext_vector_type(4))) float f4v;

__device__ __forceinline__ f4v mfma16(s8v a, s8v b, f4v c) {
  return __builtin_amdgcn_mfma_f32_16x16x32_bf16(a, b, c, 0, 0, 0);
}
__device__ __forceinline__ f4v mfmaH(h8v a, h8v b, f4v c) {
  return __builtin_amdgcn_mfma_f32_16x16x32_f16(a, b, c, 0, 0, 0);
}
__device__ __forceinline__ f4v zero4() { return (f4v){0.f, 0.f, 0.f, 0.f}; }

__device__ __forceinline__ unsigned short f2b(float x) {  // f32->bf16 RNE
  unsigned int u = __builtin_bit_cast(unsigned int, x);
  u += 0x7fffu + ((u >> 16) & 1u);
  return (unsigned short)(u >> 16);
}
__device__ __forceinline__ float b2f(unsigned short h) {
  return __builtin_bit_cast(float, (unsigned int)h << 16);
}
__device__ __forceinline__ unsigned short f2h(float x) {
  return __builtin_bit_cast(unsigned short, (_Float16)x);
}
__device__ __forceinline__ float h2f(unsigned short h) {
  return (float)__builtin_bit_cast(_Float16, h);
}

__device__ __forceinline__ float tanhf_fast(float x) {
  x = fminf(15.f, fmaxf(-15.f, x));
  float e = __expf(2.f * x);
  return (e - 1.f) / (e + 1.f);
}

// ---------------- weight swizzle: fp32 [K][N] -> fragment order ---------------
// frag: idx(nt,kk,lane,j) = ((nt*KK + kk)*64 + lane)*8 + j
//   holds W[kk*32 + (lane>>4)*8 + j][nt*16 + (lane&15)]  (zero-pad k>=K)
// mode 0: bf16 hi at dst[dhi+local], bf16 lo at dst[dlo+local]
// mode 3: f16 hi at dst[dhi+local], f16((v-hi)*2048) at dst[dlo+local]
// mode 1: f16 at dst[dhi+local]
struct SwzDesc { const float* src; long woff; long dhi; long dlo; int K; int Kp; int N; int mode; };
struct SwzTable { SwzDesc d[12]; long tot_work; };

__global__ void swz_kernel(SwzTable tbl, unsigned short* __restrict__ dst) {
  long gid = (long)blockIdx.x * 256 + threadIdx.x;
  if (gid >= tbl.tot_work) return;
  int i = 11;
  while (i > 0 && gid < tbl.d[i].woff) --i;
  const SwzDesc m = tbl.d[i];
  long local = gid - m.woff;
  int j = (int)(local & 7);
  int lane = (int)((local >> 3) & 63);
  long rem = local >> 9;
  int KK = m.Kp >> 5;
  int kk = (int)(rem % KK);
  int nt = (int)(rem / KK);
  int k = kk * 32 + (lane >> 4) * 8 + j;
  int n = nt * 16 + (lane & 15);
  float v = (k < m.K) ? m.src[(long)k * m.N + n] : 0.f;
  if (m.mode == 0) {
    unsigned short hi = f2b(v);
    dst[m.dhi + local] = hi;
    dst[m.dlo + local] = f2b(v - b2f(hi));
  } else if (m.mode == 3) {
    _Float16 hi = (_Float16)v;
    dst[m.dhi + local] = __builtin_bit_cast(unsigned short, hi);
    dst[m.dlo + local] = f2h((v - (float)hi) * 2048.f);
  } else {
    dst[m.dhi + local] = f2h(v);
  }
}

// ---------------- encoder (bf16 hi/lo 3-term, one-shot) ----------------------
__global__ __launch_bounds__(512, 2)
void enc_kernel(const float* __restrict__ upast, const float* __restrict__ ypast,
                const unsigned short* __restrict__ W1h, const unsigned short* __restrict__ W1l,
                const unsigned short* __restrict__ W2h, const unsigned short* __restrict__ W2l,
                const unsigned short* __restrict__ W3h, const unsigned short* __restrict__ W3l,
                const unsigned short* __restrict__ rWh, const unsigned short* __restrict__ rWl,
                const float* __restrict__ b1, const float* __restrict__ b2,
                const float* __restrict__ b3, const float* __restrict__ rb,
                float* __restrict__ xstate) {
  __shared__ __align__(16) unsigned short h1h[16][264], h1l[16][264];
  __shared__ __align__(16) unsigned short h2h[16][264], h2l[16][264];
  const int tid = threadIdx.x;
  const int w = tid >> 6, l = tid & 63;
  const int c = l & 15, g = l >> 4;
  const int b0 = blockIdx.x << 4;
  const long zrow = (long)(b0 + c) * 512;

  f4v a0 = zero4(), a1 = zero4();
  for (int kk = 0; kk < 32; ++kk) {
    const int cb = kk * 32 + g * 8;
    const float* zp = (cb < 512) ? (upast + zrow + cb) : (ypast + zrow + (cb - 512));
    float4 z0 = *(const float4*)zp;
    float4 z1 = *(const float4*)(zp + 4);
    float zz[8] = {z0.x, z0.y, z0.z, z0.w, z1.x, z1.y, z1.z, z1.w};
    s8v ah, al;
#pragma unroll
    for (int q = 0; q < 8; ++q) {
      unsigned short hi = f2b(zz[q]);
      ah[q] = (short)hi; al[q] = (short)f2b(zz[q] - b2f(hi));
    }
#pragma unroll
    for (int ct = 0; ct < 2; ++ct) {
      s8v bh = *(const s8v*)(W1h + (((long)(2 * w + ct) * 32 + kk) * 64 + l) * 8);
      s8v bl = *(const s8v*)(W1l + (((long)(2 * w + ct) * 32 + kk) * 64 + l) * 8);
      f4v& acc = ct ? a1 : a0;
      acc = mfma16(ah, bh, acc);
      acc = mfma16(al, bh, acc);
      acc = mfma16(ah, bl, acc);
    }
  }
  {
    const float bbA = b1[(2 * w + 0) * 16 + c], bbB = b1[(2 * w + 1) * 16 + c];
#pragma unroll
    for (int j = 0; j < 4; ++j) {
      float tA = tanhf_fast(a0[j] + bbA), tB = tanhf_fast(a1[j] + bbB);
      unsigned short hA = f2b(tA), hB = f2b(tB);
      h1h[g * 4 + j][(2 * w + 0) * 16 + c] = hA;
      h1l[g * 4 + j][(2 * w + 0) * 16 + c] = f2b(tA - b2f(hA));
      h1h[g * 4 + j][(2 * w + 1) * 16 + c] = hB;
      h1l[g * 4 + j][(2 * w + 1) * 16 + c] = f2b(tB - b2f(hB));
    }
  }
  __syncthreads();
  a0 = zero4(); a1 = zero4();
#pragma unroll
  for (int kk = 0; kk < 8; ++kk) {
    s8v ah = *(const s8v*)(&h1h[c][kk * 32 + g * 8]);
    s8v al = *(const s8v*)(&h1l[c][kk * 32 + g * 8]);
#pragma unroll
    for (int ct = 0; ct < 2; ++ct) {
      s8v bh = *(const s8v*)(W2h + (((long)(2 * w + ct) * 8 + kk) * 64 + l) * 8);
      s8v bl = *(const s8v*)(W2l + (((long)(2 * w + ct) * 8 + kk) * 64 + l) * 8);
      f4v& acc = ct ? a1 : a0;
      acc = mfma16(ah, bh, acc);
      acc = mfma16(al, bh, acc);
      acc = mfma16(ah, bl, acc);
    }
  }
  {
    const float bbA = b2[(2 * w + 0) * 16 + c], bbB = b2[(2 * w + 1) * 16 + c];
#pragma unroll
    for (int j = 0; j < 4; ++j) {
      float tA = tanhf_fast(a0[j] + bbA), tB = tanhf_fast(a1[j] + bbB);
      unsigned short hA = f2b(tA), hB = f2b(tB);
      h2h[g * 4 + j][(2 * w + 0) * 16 + c] = hA;
      h2l[g * 4 + j][(2 * w + 0) * 16 + c] = f2b(tA - b2f(hA));
      h2h[g * 4 + j][(2 * w + 1) * 16 + c] = hB;
      h2l[g * 4 + j][(2 * w + 1) * 16 + c] = f2b(tB - b2f(hB));
    }
  }
  __syncthreads();
  f4v ac = zero4();
#pragma unroll
  for (int kk = 0; kk < 8; ++kk) {
    s8v ah = *(const s8v*)(&h2h[c][kk * 32 + g * 8]);
    s8v al = *(const s8v*)(&h2l[c][kk * 32 + g * 8]);
    s8v bh = *(const s8v*)(W3h + (((long)w * 8 + kk) * 64 + l) * 8);
    s8v bl = *(const s8v*)(W3l + (((long)w * 8 + kk) * 64 + l) * 8);
    ac = mfma16(ah, bh, ac);
    ac = mfma16(al, bh, ac);
    ac = mfma16(ah, bl, ac);
  }
  for (int kk = 0; kk < 32; ++kk) {
    const int cb = kk * 32 + g * 8;
    const float* zp = (cb < 512) ? (upast + zrow + cb) : (ypast + zrow + (cb - 512));
    float4 z0 = *(const float4*)zp;
    float4 z1 = *(const float4*)(zp + 4);
    float zz[8] = {z0.x, z0.y, z0.z, z0.w, z1.x, z1.y, z1.z, z1.w};
    s8v ah, al;
#pragma unroll
    for (int q = 0; q < 8; ++q) {
      unsigned short hi = f2b(zz[q]);
      ah[q] = (short)hi; al[q] = (short)f2b(zz[q] - b2f(hi));
    }
    s8v bh = *(const s8v*)(rWh + (((long)w * 32 + kk) * 64 + l) * 8);
    s8v bl = *(const s8v*)(rWl + (((long)w * 32 + kk) * 64 + l) * 8);
    ac = mfma16(ah, bh, ac);
    ac = mfma16(al, bh, ac);
    ac = mfma16(ah, bl, ac);
  }
  {
    const float bias = b3[w * 16 + c] + rb[w * 16 + c];
#pragma unroll
    for (int j = 0; j < 4; ++j)
      xstate[(long)(b0 + g * 4 + j) * 128 + w * 16 + c] = ac[j] + bias;
  }
}

// ---------------- recurrence (f16 pairs, u-prefetch + deferred xf store) -----
// regs persistent (184): W1 pair 80, W2hi 64, rW pair 40. LDS: W3 pair 128KB +
// activations ~27KB. W2lo streamed from L2 (ct0 preload, ct1 in G1 tail).
__global__ __launch_bounds__(512, 2)
void recur_kernel(const float* __restrict__ ufut,
                  const unsigned short* __restrict__ W1h, const unsigned short* __restrict__ W1l,
                  const unsigned short* __restrict__ W2h, const unsigned short* __restrict__ W2l,
                  const unsigned short* __restrict__ W3h, const unsigned short* __restrict__ W3l,
                  const unsigned short* __restrict__ rWh, const unsigned short* __restrict__ rWl,
                  const float* __restrict__ b1, const float* __restrict__ b2,
                  const float* __restrict__ b3, const float* __restrict__ rb,
                  float* __restrict__ xstate,
                  unsigned short* __restrict__ xfh, unsigned short* __restrict__ xfl,
                  int t0, int len) {
  __shared__ __align__(16) unsigned short xu_h[16][168], xu_l[16][168];
  __shared__ __align__(16) unsigned short hh[16][264], hl[16][264];
  __shared__ __align__(16) unsigned short w3h_l[32768];   // W3 hi, full
  __shared__ __align__(16) unsigned short w3l_l[32768];   // W3 lo, full
  const int tid = threadIdx.x;
  const int w = tid >> 6, l = tid & 63;
  const int c = l & 15, g = l >> 4;
  const int b0 = blockIdx.x << 4;

  // persistent register fragments (f16)
  h8v w1h_r[2][5], w1l_r[2][5], w2h_r[2][8], rwh_r[5], rwl_r[5];
#pragma unroll
  for (int ct = 0; ct < 2; ++ct) {
#pragma unroll
    for (int kk = 0; kk < 5; ++kk) {
      w1h_r[ct][kk] = *(const h8v*)(W1h + (((long)(2 * w + ct) * 5 + kk) * 64 + l) * 8);
      w1l_r[ct][kk] = *(const h8v*)(W1l + (((long)(2 * w + ct) * 5 + kk) * 64 + l) * 8);
    }
#pragma unroll
    for (int kk = 0; kk < 8; ++kk)
      w2h_r[ct][kk] = *(const h8v*)(W2h + (((long)(2 * w + ct) * 8 + kk) * 64 + l) * 8);
  }
#pragma unroll
  for (int kk = 0; kk < 5; ++kk) {
    rwh_r[kk] = *(const h8v*)(rWh + (((long)w * 5 + kk) * 64 + l) * 8);
    rwl_r[kk] = *(const h8v*)(rWl + (((long)w * 5 + kk) * 64 + l) * 8);
  }
  // LDS: W3 pair (linear copy)
  for (int i = tid; i < 4096; i += 512) {
    ((h8v*)w3h_l)[i] = ((const h8v*)W3h)[i];
    ((h8v*)w3l_l)[i] = ((const h8v*)W3l)[i];
  }

  const float bbA = b1[(2 * w + 0) * 16 + c], bbB = b1[(2 * w + 1) * 16 + c];
  const float cbA = b2[(2 * w + 0) * 16 + c], cbB = b2[(2 * w + 1) * 16 + c];
  const float dB  = b3[w * 16 + c] + rb[w * 16 + c];

  // seed state f16 pair; zero k-pad cols 144..167
  for (int idx = tid; idx < 2048; idx += 512) {
    int r = idx >> 7, cc = idx & 127;
    float x = xstate[(long)(b0 + r) * 128 + cc];
    _Float16 hi = (_Float16)x;
    xu_h[r][cc] = __builtin_bit_cast(unsigned short, hi);
    xu_l[r][cc] = f2h((x - (float)hi) * 2048.f);
  }
  for (int idx = tid; idx < 16 * 24; idx += 512) {
    int r = idx / 24, cc = 144 + (idx % 24);
    xu_h[r][cc] = 0; xu_l[r][cc] = 0;
  }
  // u-prefetch: load u(t0) into regs (tid<256: 1 value each)
  const int ur = tid >> 4, uc = tid & 15;
  float uval = 0.f;
  if (tid < 256) uval = ufut[((long)(b0 + ur) * 256 + t0) * 16 + uc];
  __syncthreads();

  for (int tc = 0; tc < len; ++tc) {
    const int t = t0 + tc;
    // rolling W2lo: preload ct0
    h8v w2s[8];
#pragma unroll
    for (int kk = 0; kk < 8; ++kk)
      w2s[kk] = *(const h8v*)(W2l + (((long)(2 * w + 0) * 8 + kk) * 64 + l) * 8);
    // phase 0 (short): u_t pair from prefetched reg into cols 128..143
    if (tid < 256) {
      _Float16 hi = (_Float16)uval;
      xu_h[ur][128 + uc] = __builtin_bit_cast(unsigned short, hi);
      xu_l[ur][128 + uc] = f2h((uval - (float)hi) * 2048.f);
    }
    __syncthreads();  // barrier 1: xu complete for this step
    // prefetch u(t+1) (consumed next step; ~full step of slack to land)
    if (tid < 256) {
      const int tt = (tc + 1 < len) ? (t + 1) : t;
      uval = ufut[((long)(b0 + ur) * 256 + tt) * 16 + uc];
    }
    // xf store — issued here so it overlaps G1 compute; xu stable until G3-end
    {
      int r = tid >> 5, cc0 = (tid & 31) * 4;
      long row = ((long)(b0 + r) * len + tc) * 128 + cc0;
      unsigned long long ph = *(const unsigned long long*)(&xu_h[r][cc0]);
      unsigned long long pl = *(const unsigned long long*)(&xu_l[r][cc0]);
      *(unsigned long long*)(xfh + row) = ph;
      *(unsigned long long*)(xfl + row) = pl;
    }
    // GEMM1: xu pair x W1 pair -> h1 pair
    float v1s[2][4];
    {
      f4v t10 = zero4(), tl0 = zero4(), t11 = zero4(), tl1 = zero4();
#pragma unroll
      for (int kk = 0; kk < 5; ++kk) {
        h8v ah = *(const h8v*)(&xu_h[c][kk * 32 + g * 8]);
        h8v al = *(const h8v*)(&xu_l[c][kk * 32 + g * 8]);
        t10 = mfmaH(ah, w1h_r[0][kk], t10);
        tl0 = mfmaH(al, w1h_r[0][kk], tl0);
        tl0 = mfmaH(ah, w1l_r[0][kk], tl0);
        t11 = mfmaH(ah, w1h_r[1][kk], t11);
        tl1 = mfmaH(al, w1h_r[1][kk], tl1);
        tl1 = mfmaH(ah, w1l_r[1][kk], tl1);
      }
#pragma unroll
      for (int j = 0; j < 4; ++j) {
        v1s[0][j] = t10[j] + tl0[j] * 0x1p-11f + bbA;
        v1s[1][j] = t11[j] + tl1[j] * 0x1p-11f + bbB;
      }
    }
    // issue ct1's W2lo stream now (hidden under tanh + writes + barrier)
    h8v w2s1[8];
#pragma unroll
    for (int kk = 0; kk < 8; ++kk)
      w2s1[kk] = *(const h8v*)(W2l + (((long)(2 * w + 1) * 8 + kk) * 64 + l) * 8);
#pragma unroll
    for (int ct = 0; ct < 2; ++ct)
#pragma unroll
      for (int j = 0; j < 4; ++j) {
        float tv = tanhf_fast(v1s[ct][j]);
        _Float16 hi = (_Float16)tv;
        hh[g * 4 + j][(2 * w + ct) * 16 + c] = __builtin_bit_cast(unsigned short, hi);
        hl[g * 4 + j][(2 * w + ct) * 16 + c] = f2h((tv - (float)hi) * 2048.f);
      }
    __syncthreads();  // barrier 2: h1 ready (also drains xf store under G1 work)
    // GEMM2: h1 pair x W2 pair (ct-interleaved, A-frags read once)
    float v2s[2][4];
    {
      f4v t10 = zero4(), tl0 = zero4(), t11 = zero4(), tl1 = zero4();
#pragma unroll
      for (int kk = 0; kk < 8; ++kk) {
        h8v ah = *(const h8v*)(&hh[c][kk * 32 + g * 8]);
        h8v al = *(const h8v*)(&hl[c][kk * 32 + g * 8]);
        t10 = mfmaH(ah, w2h_r[0][kk], t10);
        tl0 = mfmaH(al, w2h_r[0][kk], tl0);
        tl0 = mfmaH(ah, w2s[kk], tl0);
        t11 = mfmaH(ah, w2h_r[1][kk], t11);
        tl1 = mfmaH(al, w2h_r[1][kk], tl1);
        tl1 = mfmaH(ah, w2s1[kk], tl1);
      }
#pragma unroll
      for (int j = 0; j < 4; ++j) {
        v2s[0][j] = t10[j] + tl0[j] * 0x1p-11f + cbA;
        v2s[1][j] = t11[j] + tl1[j] * 0x1p-11f + cbB;
      }
    }
    __syncthreads();  // barrier 3: drain h1 reads before overwriting hh/hl
#pragma unroll
    for (int ct = 0; ct < 2; ++ct)
#pragma unroll
      for (int j = 0; j < 4; ++j) {
        float tv = tanhf_fast(v2s[ct][j]);
        _Float16 hi = (_Float16)tv;
        hh[g * 4 + j][(2 * w + ct) * 16 + c] = __builtin_bit_cast(unsigned short, hi);
        hl[g * 4 + j][(2 * w + ct) * 16 + c] = f2h((tv - (float)hi) * 2048.f);
      }
    __syncthreads();  // barrier 4: h2 ready
    // GEMM3: h2 pair x W3 pair (LDS) + xu pair x rW pair (regs)
    {
      f4v t1 = zero4(), tl = zero4();
#pragma unroll
      for (int kk = 0; kk < 8; ++kk) {
        h8v ah = *(const h8v*)(&hh[c][kk * 32 + g * 8]);
        h8v al = *(const h8v*)(&hl[c][kk * 32 + g * 8]);
        h8v bh = *(const h8v*)(&w3h_l[((w * 8 + kk) * 64 + l) * 8]);
        h8v bl = *(const h8v*)(&w3l_l[((w * 8 + kk) * 64 + l) * 8]);
        t1 = mfmaH(ah, bh, t1);
        tl = mfmaH(al, bh, tl);
        tl = mfmaH(ah, bl, tl);
      }
#pragma unroll
      for (int kk = 0; kk < 5; ++kk) {
        h8v ah = *(const h8v*)(&xu_h[c][kk * 32 + g * 8]);
        h8v al = *(const h8v*)(&xu_l[c][kk * 32 + g * 8]);
        t1 = mfmaH(ah, rwh_r[kk], t1);
        tl = mfmaH(al, rwh_r[kk], tl);
        tl = mfmaH(ah, rwl_r[kk], tl);
      }
      __syncthreads();  // barrier 5: drain xu/hh reads before state overwrite
#pragma unroll
      for (int j = 0; j < 4; ++j) {
        float xn = t1[j] + tl[j] * 0x1p-11f + dB;
        _Float16 hi = (_Float16)xn;
        xu_h[g * 4 + j][w * 16 + c] = __builtin_bit_cast(unsigned short, hi);
        xu_l[g * 4 + j][w * 16 + c] = f2h((xn - (float)hi) * 2048.f);
      }
    }
    __syncthreads();  // barrier 6: state ready
  }
  // chunk-final state writeback (fp32 = hi + lo*2^-11, exact)
  for (int idx = tid; idx < 2048; idx += 512) {
    int r = idx >> 7, cc = idx & 127;
    xstate[(long)(b0 + r) * 128 + cc] = h2f(xu_h[r][cc]) + h2f(xu_l[r][cc]) * 0x1p-11f;
  }
}

// ---------------- output network h (xf pair x f16-single weights) ------------
__global__ __launch_bounds__(512, 2)
void hnet_kernel(const unsigned short* __restrict__ xfh, const unsigned short* __restrict__ xfl,
                 const unsigned short* __restrict__ W1, const unsigned short* __restrict__ W2,
                 const unsigned short* __restrict__ W3, const unsigned short* __restrict__ rW,
                 const float* __restrict__ b1, const float* __restrict__ b2,
                 const float* __restrict__ b3, const float* __restrict__ rb,
                 float* __restrict__ out, int t0, int len) {
  __shared__ __align__(16) unsigned short h1[64][264];
  __shared__ __align__(16) unsigned short h2[64][264];
  __shared__ float part[4][16][16];
  const int tid = threadIdx.x;
  const int w = tid >> 6, l = tid & 63;
  const int c = l & 15, g = l >> 4;
  const long row0 = (long)blockIdx.x * 64;

  {  // stage A: h1 = tanh(xf(pair) @ W1 + b1)
    h8v w1f[2][4];
#pragma unroll
    for (int ct = 0; ct < 2; ++ct)
#pragma unroll
      for (int kk = 0; kk < 4; ++kk)
        w1f[ct][kk] = *(const h8v*)(W1 + (((long)(2 * w + ct) * 4 + kk) * 64 + l) * 8);
    const float bbA = b1[(2 * w + 0) * 16 + c], bbB = b1[(2 * w + 1) * 16 + c];
#pragma unroll
    for (int rt = 0; rt < 4; ++rt) {
      f4v t10 = zero4(), tl0 = zero4(), t11 = zero4(), tl1 = zero4();
#pragma unroll
      for (int kk = 0; kk < 4; ++kk) {
        h8v ah = *(const h8v*)(xfh + (row0 + rt * 16 + c) * 128 + kk * 32 + g * 8);
        h8v al = *(const h8v*)(xfl + (row0 + rt * 16 + c) * 128 + kk * 32 + g * 8);
        t10 = mfmaH(ah, w1f[0][kk], t10);
        tl0 = mfmaH(al, w1f[0][kk], tl0);
        t11 = mfmaH(ah, w1f[1][kk], t11);
        tl1 = mfmaH(al, w1f[1][kk], tl1);
      }
#pragma unroll
      for (int j = 0; j < 4; ++j) {
        h1[rt * 16 + g * 4 + j][(2 * w + 0) * 16 + c] =
            f2h(tanhf_fast(t10[j] + tl0[j] * 0x1p-11f + bbA));
        h1[rt * 16 + g * 4 + j][(2 * w + 1) * 16 + c] =
            f2h(tanhf_fast(t11[j] + tl1[j] * 0x1p-11f + bbB));
      }
    }
  }
  __syncthreads();
  {  // stage B: h2 = tanh(h1 @ W2 + b2), f16 single
    h8v w2f[2][8];
#pragma unroll
    for (int ct = 0; ct < 2; ++ct)
#pragma unroll
      for (int kk = 0; kk < 8; ++kk)
        w2f[ct][kk] = *(const h8v*)(W2 + (((long)(2 * w + ct) * 8 + kk) * 64 + l) * 8);
    const float bbA = b2[(2 * w + 0) * 16 + c], bbB = b2[(2 * w + 1) * 16 + c];
#pragma unroll
    for (int rt = 0; rt < 4; ++rt) {
      f4v a0 = zero4(), a1 = zero4();
#pragma unroll
      for (int kk = 0; kk < 8; ++kk) {
        h8v a = *(const h8v*)(&h1[rt * 16 + c][kk * 32 + g * 8]);
        a0 = mfmaH(a, w2f[0][kk], a0);
        a1 = mfmaH(a, w2f[1][kk], a1);
      }
#pragma unroll
      for (int j = 0; j < 4; ++j) {
        h2[rt * 16 + g * 4 + j][(2 * w + 0) * 16 + c] = f2h(tanhf_fast(a0[j] + bbA));
        h2[rt * 16 + g * 4 + j][(2 * w + 1) * 16 + c] = f2h(tanhf_fast(a1[j] + bbB));
      }
    }
  }
  __syncthreads();
  {  // stage C: y = h2 @ W3 + xf(pair) @ rW + b3 + rb
    const int rt = w & 3, kh = w >> 2;
    f4v t1 = zero4(), tl = zero4();
#pragma unroll
    for (int kk = 0; kk < 4; ++kk) {
      const int kkg = kh * 4 + kk;
      h8v a = *(const h8v*)(&h2[rt * 16 + c][kkg * 32 + g * 8]);
      h8v b = *(const h8v*)(W3 + ((long)(kkg * 64 + l)) * 8);
      t1 = mfmaH(a, b, t1);
    }
#pragma unroll
    for (int kk = 0; kk < 2; ++kk) {
      const int kkg = kh * 2 + kk;
      h8v ah = *(const h8v*)(xfh + (row0 + rt * 16 + c) * 128 + kkg * 32 + g * 8);
      h8v al = *(const h8v*)(xfl + (row0 + rt * 16 + c) * 128 + kkg * 32 + g * 8);
      h8v b = *(const h8v*)(rW + ((long)(kkg * 64 + l)) * 8);
      t1 = mfmaH(ah, b, t1);
      tl = mfmaH(al, b, tl);
    }
    float val[4];
#pragma unroll
    for (int j = 0; j < 4; ++j) val[j] = t1[j] + tl[j] * 0x1p-11f;
    if (w >= 4) {
#pragma unroll
      for (int j = 0; j < 4; ++j) part[rt][g * 4 + j][c] = val[j];
    }
    __syncthreads();
    if (w < 4) {
      const float bias = b3[c] + rb[c];
#pragma unroll
      for (int j = 0; j < 4; ++j) {
        const long grow = row0 + rt * 16 + g * 4 + j;
        const long bq = grow / len;
        const int tq = (int)(grow - bq * len);
        out[(bq * 256 + (t0 + tq)) * 16 + c] = val[j] + part[rt][g * 4 + j][c] + bias;
      }
    }
  }
}

// ---------------- host -------------------------------------------------------
extern "C" void kernel_launch(void* const* d_in, const int* in_sizes, int n_in,
                              void* d_out, int out_size, void* d_ws, size_t ws_size,
                              hipStream_t stream) {
  (void)in_sizes; (void)n_in; (void)out_size;
  const float* upast = (const float*)d_in[0];
  const float* ypast = (const float*)d_in[1];
  const float* ufut  = (const float*)d_in[2];
  const float* e_rW = (const float*)d_in[3];
  const float* e_rb = (const float*)d_in[4];
  const float* e_W1 = (const float*)d_in[5];
  const float* e_b1 = (const float*)d_in[6];
  const float* e_W2 = (const float*)d_in[7];
  const float* e_b2 = (const float*)d_in[8];
  const float* e_W3 = (const float*)d_in[9];
  const float* e_b3 = (const float*)d_in[10];
  const float* f_rW = (const float*)d_in[11];
  const float* f_rb = (const float*)d_in[12];
  const float* f_W1 = (const float*)d_in[13];
  const float* f_b1 = (const float*)d_in[14];
  const float* f_W2 = (const float*)d_in[15];
  const float* f_b2 = (const float*)d_in[16];
  const float* f_W3 = (const float*)d_in[17];
  const float* f_b3 = (const float*)d_in[18];
  const float* h_rW = (const float*)d_in[19];
  const float* h_rb = (const float*)d_in[20];
  const float* h_W1 = (const float*)d_in[21];
  const float* h_b1 = (const float*)d_in[22];
  const float* h_W2 = (const float*)d_in[23];
  const float* h_b2 = (const float*)d_in[24];
  const float* h_W3 = (const float*)d_in[25];
  const float* h_b3 = (const float*)d_in[26];
  float* out = (float*)d_out;

  // swizzle table: e_* bf16 pair (mode0), f_* f16 pair (mode3), h_* f16 (mode1)
  const float* srcs[12] = { e_W1, e_W2, e_W3, e_rW, f_W1, f_W2, f_W3, f_rW,
                            h_W1, h_W2, h_W3, h_rW };
  const int Ks [12] = {1024, 256, 256, 1024, 144, 256, 256, 144, 128, 256, 256, 128};
  const int Kps[12] = {1024, 256, 256, 1024, 160, 256, 256, 160, 128, 256, 256, 128};
  const int Ns [12] = { 256, 256, 128,  128, 256, 256, 128, 128, 256, 256,  16,  16};
  const int modes[12] = {0,0,0,0, 3,3,3,3, 1,1,1,1};

  SwzTable tbl;
  long woff = 0, offs[12];
  for (int i = 0; i < 12; ++i) { offs[i] = woff; woff += (long)Kps[i] * Ns[i]; }
  const long EA = offs[4];              // e-region elems
  const long FB = 2 * EA;
  const long EB = offs[8] - offs[4];    // f-region elems
  const long HB = FB + 2 * EB;
  for (int i = 0; i < 12; ++i) {
    tbl.d[i].src = srcs[i]; tbl.d[i].woff = offs[i];
    tbl.d[i].K = Ks[i]; tbl.d[i].Kp = Kps[i]; tbl.d[i].N = Ns[i]; tbl.d[i].mode = modes[i];
    if (modes[i] == 0)      { tbl.d[i].dhi = offs[i];              tbl.d[i].dlo = EA + offs[i]; }
    else if (modes[i] == 3) { long lo = offs[i] - offs[4];
                              tbl.d[i].dhi = FB + lo;              tbl.d[i].dlo = FB + EB + lo; }
    else                    { long lo = offs[i] - offs[8];
                              tbl.d[i].dhi = HB + lo;              tbl.d[i].dlo = 0; }
  }
  tbl.tot_work = woff;

  unsigned short* wswz = (unsigned short*)d_ws;
  const long WSHORTS = HB + (offs[11] - offs[8]) + (long)Kps[11] * Ns[11];
  const size_t XOFF = ((size_t)WSHORTS * 2 + 4095) & ~(size_t)4095;
  float* xstate = (float*)((char*)d_ws + XOFF);
  const size_t XF0 = XOFF + (2u << 20);
  int c = 64;
  {
    long cmax = ((long)ws_size - (long)XF0) >> 21;  // 2 MB per time-step (pair)
    if (cmax < c) c = (int)cmax;
    if (c < 1) c = 1;
  }
  unsigned short* xfh = (unsigned short*)((char*)d_ws + XF0);
  unsigned short* xfl = (unsigned short*)((char*)d_ws + XF0 + (size_t)c * 1048576);

  // kernel weight pointers
  const unsigned short* eW1h = wswz + offs[0];          const unsigned short* eW1l = wswz + EA + offs[0];
  const unsigned short* eW2h = wswz + offs[1];          const unsigned short* eW2l = wswz + EA + offs[1];
  const unsigned short* eW3h = wswz + offs[2];          const unsigned short* eW3l = wswz + EA + offs[2];
  const unsigned short* erWh = wswz + offs[3];          const unsigned short* erWl = wswz + EA + offs[3];
  const unsigned short* fW1h = wswz + FB + 0;           const unsigned short* fW1l = wswz + FB + EB + 0;
  const unsigned short* fW2h = wswz + FB + 40960;       const unsigned short* fW2l = wswz + FB + EB + 40960;
  const unsigned short* fW3h = wswz + FB + 106496;      const unsigned short* fW3l = wswz + FB + EB + 106496;
  const unsigned short* frWh = wswz + FB + 139264;      const unsigned short* frWl = wswz + FB + EB + 139264;
  const unsigned short* hW1 = wswz + HB + 0;
  const unsigned short* hW2 = wswz + HB + 32768;
  const unsigned short* hW3 = wswz + HB + 98304;
  const unsigned short* hrW = wswz + HB + 102400;

  swz_kernel<<<(int)((tbl.tot_work + 255) / 256), 256, 0, stream>>>(tbl, wswz);
  enc_kernel<<<256, 512, 0, stream>>>(upast, ypast,
                                      eW1h, eW1l, eW2h, eW2l, eW3h, eW3l, erWh, erWl,
                                      e_b1, e_b2, e_b3, e_rb, xstate);
  for (int t0 = 0; t0 < 256; t0 += c) {
    int len = 256 - t0; if (len > c) len = c;
    recur_kernel<<<256, 512, 0, stream>>>(ufut, fW1h, fW1l, fW2h, fW2l, fW3h, fW3l,
                                          frWh, frWl, f_b1, f_b2, f_b3, f_rb,
                                          xstate, xfh, xfl, t0, len);
    hnet_kernel<<<64 * len, 512, 0, stream>>>(xfh, xfl, hW1, hW2, hW3, hrW,
                                              h_b1, h_b2, h_b3, h_rb, out, t0, len);
  }
}